// Round 4
// baseline (1041.301 us; speedup 1.0000x reference)
//
#include <hip/hip_runtime.h>
#include <math.h>

#define NN 50000
#define EE 800000
#define GG 500
#define CC 6
#define BN_EPS 1e-5f

// ---------------- degree / norm ----------------
__global__ __launch_bounds__(256) void k_deg_init(float* __restrict__ deg) {
  int i = blockIdx.x * 256 + threadIdx.x;
  if (i < NN) deg[i] = 1.0f;  // self-loop contributes 1 to every node
}

__global__ __launch_bounds__(256) void k_deg_count(const int* __restrict__ dst,
                                                   float* __restrict__ deg) {
  int e = blockIdx.x * 256 + threadIdx.x;
  if (e < EE) atomicAdd(&deg[dst[e]], 1.0f);
}

__global__ __launch_bounds__(256) void k_deg_rsqrt(float* __restrict__ deg) {
  int i = blockIdx.x * 256 + threadIdx.x;
  if (i < NN) deg[i] = rsqrtf(deg[i]);
}

// ---------------- GEMM: out[N,64] = A[N,64] @ W[64,64] ----------------
__global__ __launch_bounds__(256) void k_gemm64(const float* __restrict__ A,
                                                const float* __restrict__ W,
                                                float* __restrict__ out) {
  __shared__ float Ws[64][64];
  int tid = threadIdx.x;
#pragma unroll
  for (int i = 0; i < 16; ++i) {
    int idx = tid + i * 256;
    Ws[idx >> 6][idx & 63] = W[idx];
  }
  __syncthreads();
  int c = tid & 63;        // output channel (lane)
  int r4 = tid >> 6;       // wave id 0..3
  int base = blockIdx.x * 32;
  for (int rr = r4; rr < 32; rr += 4) {
    int n = base + rr;
    if (n < NN) {
      const float* a = A + (size_t)n * 64;
      float acc = 0.f;
#pragma unroll
      for (int k = 0; k < 64; ++k) acc = fmaf(a[k], Ws[k][c], acc);
      out[(size_t)n * 64 + c] = acc;
    }
  }
}

// ---------------- scatter-aggregate (edges + self-loops) ----------------
__global__ __launch_bounds__(256) void k_scatter(const int* __restrict__ src,
                                                 const int* __restrict__ dst,
                                                 const float* __restrict__ dinv,
                                                 const float* __restrict__ t,
                                                 float* __restrict__ a) {
  int idx = blockIdx.x * 4 + (threadIdx.x >> 6);
  int c = threadIdx.x & 63;
  if (idx >= EE + NN) return;
  int s, d;
  float w;
  if (idx < EE) {
    s = src[idx];
    d = dst[idx];
    w = dinv[s] * dinv[d];
  } else {
    s = d = idx - EE;
    float dv = dinv[s];
    w = dv * dv;
  }
  atomicAdd(&a[(size_t)d * 64 + c], w * t[(size_t)s * 64 + c]);
}

// ---------------- BatchNorm stats (sum, sumsq per channel) ----------------
__global__ __launch_bounds__(256) void k_bn_stats(const float* __restrict__ h,
                                                  double* __restrict__ sums) {
  int c = threadIdx.x & 63, r = threadIdx.x >> 6;
  int base = blockIdx.x * 256;
  float s = 0.f, sq = 0.f;
  for (int rr = r; rr < 256; rr += 4) {
    int n = base + rr;
    if (n < NN) {
      float v = h[(size_t)n * 64 + c];
      s += v;
      sq = fmaf(v, v, sq);
    }
  }
  __shared__ float ls[4][64], lq[4][64];
  ls[r][c] = s;
  lq[r][c] = sq;
  __syncthreads();
  if (r == 0) {
    float S = ls[0][c] + ls[1][c] + ls[2][c] + ls[3][c];
    float Q = lq[0][c] + lq[1][c] + lq[2][c] + lq[3][c];
    atomicAdd(&sums[c], (double)S);
    atomicAdd(&sums[64 + c], (double)Q);
  }
}

__global__ void k_bn_finalize(const double* __restrict__ sums,
                              const float* __restrict__ g,
                              const float* __restrict__ be,
                              float* __restrict__ scale,
                              float* __restrict__ shift) {
  int c = threadIdx.x;  // 64 threads
  double mu = sums[c] / (double)NN;
  double var = sums[64 + c] / (double)NN - mu * mu;
  float rstd = (float)(1.0 / sqrt(var + (double)BN_EPS));
  float sc = g[c] * rstd;
  scale[c] = sc;
  shift[c] = be[c] - (float)mu * sc;
}

// ---------------- BN apply + ReLU (in place, float4) ----------------
__global__ __launch_bounds__(256) void k_bn_apply(float* __restrict__ h,
                                                  const float* __restrict__ scale,
                                                  const float* __restrict__ shift) {
  int i = blockIdx.x * 256 + threadIdx.x;  // over N*16 float4s
  if (i >= NN * 16) return;
  float4 v = ((float4*)h)[i];
  int c0 = (i * 4) & 63;
  v.x = fmaxf(fmaf(v.x, scale[c0 + 0], shift[c0 + 0]), 0.f);
  v.y = fmaxf(fmaf(v.y, scale[c0 + 1], shift[c0 + 1]), 0.f);
  v.z = fmaxf(fmaf(v.z, scale[c0 + 2], shift[c0 + 2]), 0.f);
  v.w = fmaxf(fmaf(v.w, scale[c0 + 3], shift[c0 + 3]), 0.f);
  ((float4*)h)[i] = v;
}

// ---------------- global mean pool (scatter by graph id) ----------------
__global__ __launch_bounds__(256) void k_pool(const int* __restrict__ batch,
                                              const float* __restrict__ h,
                                              float* __restrict__ pooled,
                                              float* __restrict__ cnt) {
  int idx = blockIdx.x * 4 + (threadIdx.x >> 6);
  int c = threadIdx.x & 63;
  if (idx >= NN) return;
  int g = batch[idx];
  atomicAdd(&pooled[(size_t)g * 64 + c], h[(size_t)idx * 64 + c]);
  if (c == 0) atomicAdd(&cnt[g], 1.0f);
}

// ---------------- final FC: out[G,C] = (pooled/cnt) @ fcW + fcb ----------------
__global__ __launch_bounds__(256) void k_final(const float* __restrict__ pooled,
                                               const float* __restrict__ cnt,
                                               const float* __restrict__ fcW,
                                               const float* __restrict__ fcb,
                                               float* __restrict__ out) {
  int i = blockIdx.x * 256 + threadIdx.x;
  if (i >= GG * CC) return;
  int g = i / CC, j = i % CC;
  float inv = 1.0f / fmaxf(cnt[g], 1.0f);
  float acc = 0.f;
#pragma unroll
  for (int k = 0; k < 64; ++k) acc = fmaf(pooled[(size_t)g * 64 + k], fcW[k * CC + j], acc);
  out[i] = acc * inv + fcb[j];
}

extern "C" void kernel_launch(void* const* d_in, const int* in_sizes, int n_in,
                              void* d_out, int out_size, void* d_ws, size_t ws_size,
                              hipStream_t stream) {
  const float* x = (const float*)d_in[0];
  const int* eidx = (const int*)d_in[1];
  const int* batch = (const int*)d_in[2];
  const float* W[3] = {(const float*)d_in[3], (const float*)d_in[7], (const float*)d_in[11]};
  const float* gam[3] = {(const float*)d_in[5], (const float*)d_in[9], (const float*)d_in[13]};
  const float* bet[3] = {(const float*)d_in[6], (const float*)d_in[10], (const float*)d_in[14]};
  const float* fcW = (const float*)d_in[15];
  const float* fcb = (const float*)d_in[16];
  float* out = (float*)d_out;

  char* ws = (char*)d_ws;
  size_t off = 0;
  auto alloc = [&](size_t b) -> void* {
    void* p = ws + off;
    off = (off + b + 255) & ~(size_t)255;
    return p;
  };
  float* dinv = (float*)alloc((size_t)NN * 4);
  float* bufA = (float*)alloc((size_t)NN * 64 * 4);
  float* bufB = (float*)alloc((size_t)NN * 64 * 4);
  double* sums = (double*)alloc(128 * 8);
  float* scale = (float*)alloc(64 * 4);
  float* shift = (float*)alloc(64 * 4);
  float* pooled = (float*)alloc((size_t)GG * 64 * 4);
  float* cnt = (float*)alloc((size_t)GG * 4);

  const int* src = eidx;       // edge_index[0]
  const int* dst = eidx + EE;  // edge_index[1]

  k_deg_init<<<(NN + 255) / 256, 256, 0, stream>>>(dinv);
  k_deg_count<<<(EE + 255) / 256, 256, 0, stream>>>(dst, dinv);
  k_deg_rsqrt<<<(NN + 255) / 256, 256, 0, stream>>>(dinv);

  const float* h = x;
  for (int l = 0; l < 3; ++l) {
    k_gemm64<<<(NN + 31) / 32, 256, 0, stream>>>(h, W[l], bufB);
    hipMemsetAsync(bufA, 0, (size_t)NN * 64 * 4, stream);
    k_scatter<<<(EE + NN + 3) / 4, 256, 0, stream>>>(src, dst, dinv, bufB, bufA);
    hipMemsetAsync(sums, 0, 128 * 8, stream);
    k_bn_stats<<<(NN + 255) / 256, 256, 0, stream>>>(bufA, sums);
    k_bn_finalize<<<1, 64, 0, stream>>>(sums, gam[l], bet[l], scale, shift);
    k_bn_apply<<<(NN * 16 + 255) / 256, 256, 0, stream>>>(bufA, scale, shift);
    h = bufA;
  }

  hipMemsetAsync(pooled, 0, (size_t)GG * 64 * 4, stream);
  hipMemsetAsync(cnt, 0, (size_t)GG * 4, stream);
  k_pool<<<(NN + 3) / 4, 256, 0, stream>>>(batch, bufA, pooled, cnt);
  k_final<<<(GG * CC + 255) / 256, 256, 0, stream>>>(pooled, cnt, fcW, fcb, out);
}

// Round 5
// 662.409 us; speedup vs baseline: 1.5720x; 1.5720x over previous
//
#include <hip/hip_runtime.h>
#include <math.h>

#define NN 50000
#define EE 800000
#define GG 500
#define CC 6
#define BN_EPS 1e-5f
#define NB_SCAN 49  // ceil(50000/1024)

// ---------------- degree count (int) ----------------
__global__ __launch_bounds__(256) void k_count(const int* __restrict__ dst,
                                               int* __restrict__ icnt) {
  int e = blockIdx.x * 256 + threadIdx.x;
  if (e < EE) atomicAdd(&icnt[dst[e]], 1);
}

__global__ __launch_bounds__(256) void k_dinv(const int* __restrict__ icnt,
                                              float* __restrict__ dinv) {
  int i = blockIdx.x * 256 + threadIdx.x;
  if (i < NN) dinv[i] = rsqrtf((float)(icnt[i] + 1));  // +1 self-loop
}

// ---------------- prefix sum (3-phase) ----------------
// phase 1: each block scans 1024 elements (4/thread), writes per-elem exclusive
// prefix (within block) and the block total.
__global__ __launch_bounds__(256) void k_scan1(const int* __restrict__ icnt,
                                               int* __restrict__ pre,
                                               int* __restrict__ bsum) {
  __shared__ int ls[256];
  int base = blockIdx.x * 1024;
  int t = threadIdx.x;
  int v[4], s = 0;
#pragma unroll
  for (int j = 0; j < 4; ++j) {
    int idx = base + t * 4 + j;
    v[j] = (idx < NN) ? icnt[idx] : 0;
    s += v[j];
  }
  ls[t] = s;
  __syncthreads();
  for (int ofs = 1; ofs < 256; ofs <<= 1) {
    int y = (t >= ofs) ? ls[t - ofs] : 0;
    __syncthreads();
    ls[t] += y;
    __syncthreads();
  }
  int excl = ls[t] - s;  // exclusive prefix of this thread's chunk
#pragma unroll
  for (int j = 0; j < 4; ++j) {
    int idx = base + t * 4 + j;
    if (idx < NN) pre[idx] = excl;
    excl += v[j];
  }
  if (t == 255) bsum[blockIdx.x] = ls[255];
}

// phase 2: serial scan of the 49 block sums (tiny); also writes rowptr[NN].
__global__ void k_scan2(int* __restrict__ bsum, int* __restrict__ rowptr) {
  if (threadIdx.x == 0) {
    int run = 0;
    for (int b = 0; b < NB_SCAN; ++b) {
      int x = bsum[b];
      bsum[b] = run;
      run += x;
    }
    rowptr[NN] = EE;
  }
}

// phase 3: rowptr[i] = pre[i] + bsum[block(i)]
__global__ __launch_bounds__(256) void k_scan3(const int* __restrict__ pre,
                                               const int* __restrict__ bsum,
                                               int* __restrict__ rowptr) {
  int i = blockIdx.x * 256 + threadIdx.x;
  if (i < NN) rowptr[i] = pre[i] + bsum[i >> 10];
}

// ---------------- fill CSR: packed (src, weight) per edge ----------------
__global__ __launch_bounds__(256) void k_fill(const int* __restrict__ src,
                                              const int* __restrict__ dst,
                                              const float* __restrict__ dinv,
                                              const int* __restrict__ rowptr,
                                              int* __restrict__ fill,
                                              uint2* __restrict__ ep) {
  int e = blockIdx.x * 256 + threadIdx.x;
  if (e >= EE) return;
  int d = dst[e], s = src[e];
  int pos = rowptr[d] + atomicAdd(&fill[d], 1);
  uint2 p;
  p.x = (unsigned)s;
  p.y = __float_as_uint(dinv[s] * dinv[d]);
  ep[pos] = p;
}

// ---------------- GEMM with optional fused BN+ReLU on input ----------------
// out[N,64] = f(A)[N,64] @ W[64,64],  f = BN(scale,shift)+ReLU if useBN
__global__ __launch_bounds__(256) void k_gemm64f(const float* __restrict__ A,
                                                 const float* __restrict__ scale,
                                                 const float* __restrict__ shift,
                                                 const float* __restrict__ W,
                                                 float* __restrict__ out,
                                                 int useBN) {
  __shared__ float Ws[64][64];
  __shared__ float sc[64], sh[64];
  int tid = threadIdx.x;
#pragma unroll
  for (int i = 0; i < 16; ++i) {
    int idx = tid + i * 256;
    Ws[idx >> 6][idx & 63] = W[idx];
  }
  if (tid < 64) {
    sc[tid] = useBN ? scale[tid] : 1.0f;
    sh[tid] = useBN ? shift[tid] : 0.0f;
  }
  __syncthreads();
  int c = tid & 63;
  int r4 = tid >> 6;
  int base = blockIdx.x * 32;
  for (int rr = r4; rr < 32; rr += 4) {
    int n = base + rr;
    if (n < NN) {
      const float* a = A + (size_t)n * 64;
      float acc = 0.f;
      if (useBN) {
#pragma unroll
        for (int k = 0; k < 64; ++k) {
          float v = fmaxf(fmaf(a[k], sc[k], sh[k]), 0.f);
          acc = fmaf(v, Ws[k][c], acc);
        }
      } else {
#pragma unroll
        for (int k = 0; k < 64; ++k) acc = fmaf(a[k], Ws[k][c], acc);
      }
      out[(size_t)n * 64 + c] = acc;
    }
  }
}

// ---------------- gather-aggregate: one wave per dst node ----------------
__global__ __launch_bounds__(256) void k_gather(const int* __restrict__ rowptr,
                                                const uint2* __restrict__ ep,
                                                const float* __restrict__ dinv,
                                                const float* __restrict__ t,
                                                float* __restrict__ outp) {
  int d = blockIdx.x * 4 + (threadIdx.x >> 6);
  int c = threadIdx.x & 63;
  if (d >= NN) return;
  float dv = dinv[d];
  float acc = dv * dv * t[(size_t)d * 64 + c];  // self-loop
  int e = rowptr[d], e1 = rowptr[d + 1];
  for (; e + 1 < e1; e += 2) {
    uint2 p0 = ep[e], p1 = ep[e + 1];
    float t0 = t[(size_t)p0.x * 64 + c];
    float t1 = t[(size_t)p1.x * 64 + c];
    acc = fmaf(__uint_as_float(p0.y), t0, acc);
    acc = fmaf(__uint_as_float(p1.y), t1, acc);
  }
  if (e < e1) {
    uint2 p = ep[e];
    acc = fmaf(__uint_as_float(p.y), t[(size_t)p.x * 64 + c], acc);
  }
  outp[(size_t)d * 64 + c] = acc;
}

// ---------------- BatchNorm stats ----------------
__global__ __launch_bounds__(256) void k_bn_stats(const float* __restrict__ h,
                                                  double* __restrict__ sums) {
  int c = threadIdx.x & 63, r = threadIdx.x >> 6;
  int base = blockIdx.x * 256;
  float s = 0.f, sq = 0.f;
  for (int rr = r; rr < 256; rr += 4) {
    int n = base + rr;
    if (n < NN) {
      float v = h[(size_t)n * 64 + c];
      s += v;
      sq = fmaf(v, v, sq);
    }
  }
  __shared__ float ls[4][64], lq[4][64];
  ls[r][c] = s;
  lq[r][c] = sq;
  __syncthreads();
  if (r == 0) {
    float S = ls[0][c] + ls[1][c] + ls[2][c] + ls[3][c];
    float Q = lq[0][c] + lq[1][c] + lq[2][c] + lq[3][c];
    atomicAdd(&sums[c], (double)S);
    atomicAdd(&sums[64 + c], (double)Q);
  }
}

__global__ void k_bn_finalize(const double* __restrict__ sums,
                              const float* __restrict__ g,
                              const float* __restrict__ be,
                              float* __restrict__ scale,
                              float* __restrict__ shift) {
  int c = threadIdx.x;  // 64 threads
  double mu = sums[c] / (double)NN;
  double var = sums[64 + c] / (double)NN - mu * mu;
  float rstd = (float)(1.0 / sqrt(var + (double)BN_EPS));
  float scv = g[c] * rstd;
  scale[c] = scv;
  shift[c] = be[c] - (float)mu * scv;
}

// ---------------- pool with fused BN+ReLU on read ----------------
__global__ __launch_bounds__(256) void k_pool(const int* __restrict__ batch,
                                              const float* __restrict__ h,
                                              const float* __restrict__ scale,
                                              const float* __restrict__ shift,
                                              float* __restrict__ pooled,
                                              float* __restrict__ cnt) {
  int idx = blockIdx.x * 4 + (threadIdx.x >> 6);
  int c = threadIdx.x & 63;
  if (idx >= NN) return;
  int g = batch[idx];
  float v = fmaxf(fmaf(h[(size_t)idx * 64 + c], scale[c], shift[c]), 0.f);
  atomicAdd(&pooled[(size_t)g * 64 + c], v);
  if (c == 0) atomicAdd(&cnt[g], 1.0f);
}

// ---------------- final FC ----------------
__global__ __launch_bounds__(256) void k_final(const float* __restrict__ pooled,
                                               const float* __restrict__ cnt,
                                               const float* __restrict__ fcW,
                                               const float* __restrict__ fcb,
                                               float* __restrict__ out) {
  int i = blockIdx.x * 256 + threadIdx.x;
  if (i >= GG * CC) return;
  int g = i / CC, j = i % CC;
  float inv = 1.0f / fmaxf(cnt[g], 1.0f);
  float acc = 0.f;
#pragma unroll
  for (int k = 0; k < 64; ++k) acc = fmaf(pooled[(size_t)g * 64 + k], fcW[k * CC + j], acc);
  out[i] = acc * inv + fcb[j];
}

extern "C" void kernel_launch(void* const* d_in, const int* in_sizes, int n_in,
                              void* d_out, int out_size, void* d_ws, size_t ws_size,
                              hipStream_t stream) {
  const float* x = (const float*)d_in[0];
  const int* eidx = (const int*)d_in[1];
  const int* batch = (const int*)d_in[2];
  const float* W[3] = {(const float*)d_in[3], (const float*)d_in[7], (const float*)d_in[11]};
  const float* gam[3] = {(const float*)d_in[5], (const float*)d_in[9], (const float*)d_in[13]};
  const float* bet[3] = {(const float*)d_in[6], (const float*)d_in[10], (const float*)d_in[14]};
  const float* fcW = (const float*)d_in[15];
  const float* fcb = (const float*)d_in[16];
  float* out = (float*)d_out;

  char* ws = (char*)d_ws;
  size_t off = 0;
  auto alloc = [&](size_t b) -> void* {
    void* p = ws + off;
    off = (off + b + 255) & ~(size_t)255;
    return p;
  };
  float* dinv = (float*)alloc((size_t)NN * 4);
  int* icnt = (int*)alloc((size_t)NN * 4);
  int* pre = (int*)alloc((size_t)NN * 4);
  int* bsum = (int*)alloc((size_t)NB_SCAN * 4);
  int* rowptr = (int*)alloc((size_t)(NN + 1) * 4);
  int* fill = (int*)alloc((size_t)NN * 4);
  uint2* ep = (uint2*)alloc((size_t)EE * 8);
  float* bufA = (float*)alloc((size_t)NN * 64 * 4);
  float* bufB = (float*)alloc((size_t)NN * 64 * 4);
  double* sums = (double*)alloc(128 * 8);
  float* scale = (float*)alloc(64 * 4);
  float* shift = (float*)alloc(64 * 4);
  float* pooled = (float*)alloc((size_t)GG * 64 * 4);
  float* cnt = (float*)alloc((size_t)GG * 4);

  const int* src = eidx;       // edge_index[0]
  const int* dst = eidx + EE;  // edge_index[1]

  // --- preprocessing: CSR by dst ---
  hipMemsetAsync(icnt, 0, (size_t)NN * 4, stream);
  hipMemsetAsync(fill, 0, (size_t)NN * 4, stream);
  k_count<<<(EE + 255) / 256, 256, 0, stream>>>(dst, icnt);
  k_dinv<<<(NN + 255) / 256, 256, 0, stream>>>(icnt, dinv);
  k_scan1<<<NB_SCAN, 256, 0, stream>>>(icnt, pre, bsum);
  k_scan2<<<1, 64, 0, stream>>>(bsum, rowptr);
  k_scan3<<<(NN + 255) / 256, 256, 0, stream>>>(pre, bsum, rowptr);
  k_fill<<<(EE + 255) / 256, 256, 0, stream>>>(src, dst, dinv, rowptr, fill, ep);

  // --- 3 GCN layers ---
  const float* h = x;
  for (int l = 0; l < 3; ++l) {
    k_gemm64f<<<(NN + 31) / 32, 256, 0, stream>>>(h, scale, shift, W[l], bufB, l > 0);
    k_gather<<<(NN + 3) / 4, 256, 0, stream>>>(rowptr, ep, dinv, bufB, bufA);
    hipMemsetAsync(sums, 0, 128 * 8, stream);
    k_bn_stats<<<(NN + 255) / 256, 256, 0, stream>>>(bufA, sums);
    k_bn_finalize<<<1, 64, 0, stream>>>(sums, gam[l], bet[l], scale, shift);
    h = bufA;
  }

  // --- pool (fused BN+ReLU of layer 2) + FC ---
  hipMemsetAsync(pooled, 0, (size_t)GG * 64 * 4, stream);
  hipMemsetAsync(cnt, 0, (size_t)GG * 4, stream);
  k_pool<<<(NN + 3) / 4, 256, 0, stream>>>(batch, bufA, scale, shift, pooled, cnt);
  k_final<<<(GG * CC + 255) / 256, 256, 0, stream>>>(pooled, cnt, fcW, fcb, out);
}

// Round 6
// 569.907 us; speedup vs baseline: 1.8271x; 1.1623x over previous
//
#include <hip/hip_runtime.h>
#include <math.h>

#define NN 50000
#define EE 800000
#define GG 500
#define CC 6
#define BN_EPS 1e-5f
#define NB_SCAN 49  // ceil(50000/1024)

// ---------------- degree count (int) ----------------
__global__ __launch_bounds__(256) void k_count(const int* __restrict__ dst,
                                               int* __restrict__ icnt) {
  int e = blockIdx.x * 256 + threadIdx.x;
  if (e < EE) atomicAdd(&icnt[dst[e]], 1);
}

__global__ __launch_bounds__(256) void k_dinv(const int* __restrict__ icnt,
                                              float* __restrict__ dinv) {
  int i = blockIdx.x * 256 + threadIdx.x;
  if (i < NN) dinv[i] = rsqrtf((float)(icnt[i] + 1));  // +1 self-loop
}

// ---------------- prefix sum (3-phase) ----------------
__global__ __launch_bounds__(256) void k_scan1(const int* __restrict__ icnt,
                                               int* __restrict__ pre,
                                               int* __restrict__ bsum) {
  __shared__ int ls[256];
  int base = blockIdx.x * 1024;
  int t = threadIdx.x;
  int v[4], s = 0;
#pragma unroll
  for (int j = 0; j < 4; ++j) {
    int idx = base + t * 4 + j;
    v[j] = (idx < NN) ? icnt[idx] : 0;
    s += v[j];
  }
  ls[t] = s;
  __syncthreads();
  for (int ofs = 1; ofs < 256; ofs <<= 1) {
    int y = (t >= ofs) ? ls[t - ofs] : 0;
    __syncthreads();
    ls[t] += y;
    __syncthreads();
  }
  int excl = ls[t] - s;
#pragma unroll
  for (int j = 0; j < 4; ++j) {
    int idx = base + t * 4 + j;
    if (idx < NN) pre[idx] = excl;
    excl += v[j];
  }
  if (t == 255) bsum[blockIdx.x] = ls[255];
}

__global__ void k_scan2(int* __restrict__ bsum, int* __restrict__ rowptr) {
  if (threadIdx.x == 0) {
    int run = 0;
    for (int b = 0; b < NB_SCAN; ++b) {
      int x = bsum[b];
      bsum[b] = run;
      run += x;
    }
    rowptr[NN] = EE;
  }
}

__global__ __launch_bounds__(256) void k_scan3(const int* __restrict__ pre,
                                               const int* __restrict__ bsum,
                                               int* __restrict__ rowptr) {
  int i = blockIdx.x * 256 + threadIdx.x;
  if (i < NN) rowptr[i] = pre[i] + bsum[i >> 10];
}

// ---------------- fill CSR: packed (src, weight) per edge ----------------
__global__ __launch_bounds__(256) void k_fill(const int* __restrict__ src,
                                              const int* __restrict__ dst,
                                              const float* __restrict__ dinv,
                                              const int* __restrict__ rowptr,
                                              int* __restrict__ fill,
                                              uint2* __restrict__ ep) {
  int e = blockIdx.x * 256 + threadIdx.x;
  if (e >= EE) return;
  int d = dst[e], s = src[e];
  int pos = rowptr[d] + atomicAdd(&fill[d], 1);
  uint2 p;
  p.x = (unsigned)s;
  p.y = __float_as_uint(dinv[s] * dinv[d]);
  ep[pos] = p;
}

// ---------------- GEMM with optional fused BN+ReLU on input ----------------
__global__ __launch_bounds__(256) void k_gemm64f(const float* __restrict__ A,
                                                 const float* __restrict__ scale,
                                                 const float* __restrict__ shift,
                                                 const float* __restrict__ W,
                                                 float* __restrict__ out,
                                                 int useBN) {
  __shared__ float Ws[64][64];
  __shared__ float sc[64], sh[64];
  int tid = threadIdx.x;
#pragma unroll
  for (int i = 0; i < 16; ++i) {
    int idx = tid + i * 256;
    Ws[idx >> 6][idx & 63] = W[idx];
  }
  if (tid < 64) {
    sc[tid] = useBN ? scale[tid] : 1.0f;
    sh[tid] = useBN ? shift[tid] : 0.0f;
  }
  __syncthreads();
  int c = tid & 63;
  int r4 = tid >> 6;
  int base = blockIdx.x * 32;
  for (int rr = r4; rr < 32; rr += 4) {
    int n = base + rr;
    if (n < NN) {
      const float* a = A + (size_t)n * 64;
      float acc = 0.f;
      if (useBN) {
#pragma unroll
        for (int k = 0; k < 64; ++k) {
          float v = fmaxf(fmaf(a[k], sc[k], sh[k]), 0.f);
          acc = fmaf(v, Ws[k][c], acc);
        }
      } else {
#pragma unroll
        for (int k = 0; k < 64; ++k) acc = fmaf(a[k], Ws[k][c], acc);
      }
      out[(size_t)n * 64 + c] = acc;
    }
  }
}

// ---------------- gather-aggregate: one wave per dst node, 4-edge unroll ----------------
__global__ __launch_bounds__(256) void k_gather(const int* __restrict__ rowptr,
                                                const uint2* __restrict__ ep,
                                                const float* __restrict__ dinv,
                                                const float* __restrict__ t,
                                                float* __restrict__ outp) {
  int d = blockIdx.x * 4 + (threadIdx.x >> 6);
  int c = threadIdx.x & 63;
  if (d >= NN) return;
  float dv = dinv[d];
  float acc = dv * dv * t[(size_t)d * 64 + c];  // self-loop
  int e = rowptr[d], e1 = rowptr[d + 1];
  for (; e + 3 < e1; e += 4) {
    uint2 p0 = ep[e], p1 = ep[e + 1], p2 = ep[e + 2], p3 = ep[e + 3];
    float t0 = t[(size_t)p0.x * 64 + c];
    float t1 = t[(size_t)p1.x * 64 + c];
    float t2 = t[(size_t)p2.x * 64 + c];
    float t3 = t[(size_t)p3.x * 64 + c];
    acc = fmaf(__uint_as_float(p0.y), t0, acc);
    acc = fmaf(__uint_as_float(p1.y), t1, acc);
    acc = fmaf(__uint_as_float(p2.y), t2, acc);
    acc = fmaf(__uint_as_float(p3.y), t3, acc);
  }
  for (; e < e1; ++e) {
    uint2 p = ep[e];
    acc = fmaf(__uint_as_float(p.y), t[(size_t)p.x * 64 + c], acc);
  }
  outp[(size_t)d * 64 + c] = acc;
}

// ---------------- BatchNorm stats ----------------
__global__ __launch_bounds__(256) void k_bn_stats(const float* __restrict__ h,
                                                  double* __restrict__ sums) {
  int c = threadIdx.x & 63, r = threadIdx.x >> 6;
  int base = blockIdx.x * 256;
  float s = 0.f, sq = 0.f;
  for (int rr = r; rr < 256; rr += 4) {
    int n = base + rr;
    if (n < NN) {
      float v = h[(size_t)n * 64 + c];
      s += v;
      sq = fmaf(v, v, sq);
    }
  }
  __shared__ float ls[4][64], lq[4][64];
  ls[r][c] = s;
  lq[r][c] = sq;
  __syncthreads();
  if (r == 0) {
    float S = ls[0][c] + ls[1][c] + ls[2][c] + ls[3][c];
    float Q = lq[0][c] + lq[1][c] + lq[2][c] + lq[3][c];
    atomicAdd(&sums[c], (double)S);
    atomicAdd(&sums[64 + c], (double)Q);
  }
}

__global__ void k_bn_finalize(const double* __restrict__ sums,
                              const float* __restrict__ g,
                              const float* __restrict__ be,
                              float* __restrict__ scale,
                              float* __restrict__ shift) {
  int c = threadIdx.x;  // 64 threads
  double mu = sums[c] / (double)NN;
  double var = sums[64 + c] / (double)NN - mu * mu;
  float rstd = (float)(1.0 / sqrt(var + (double)BN_EPS));
  float scv = g[c] * rstd;
  scale[c] = scv;
  shift[c] = be[c] - (float)mu * scv;
}

// ---------------- graph boundaries in sorted batch ----------------
__global__ __launch_bounds__(256) void k_bounds(const int* __restrict__ batch,
                                                int* __restrict__ gstart) {
  int i = blockIdx.x * 256 + threadIdx.x;
  if (i >= NN) return;
  int b = batch[i];
  if (i == 0) {
    for (int g = 0; g <= b; ++g) gstart[g] = 0;
  } else {
    int pb = batch[i - 1];
    for (int g = pb + 1; g <= b; ++g) gstart[g] = i;
  }
  if (i == NN - 1) {
    for (int g = b + 1; g <= GG; ++g) gstart[g] = NN;
  }
}

// ---------------- segmented mean-pool: one wave per graph, zero atomics ----------------
__global__ __launch_bounds__(256) void k_pool2(const int* __restrict__ gstart,
                                               const float* __restrict__ h,
                                               const float* __restrict__ scale,
                                               const float* __restrict__ shift,
                                               float* __restrict__ pooled) {
  int g = blockIdx.x * 4 + (threadIdx.x >> 6);
  int c = threadIdx.x & 63;
  if (g >= GG) return;
  int s = gstart[g], e = gstart[g + 1];
  float sc = scale[c], sh = shift[c];
  float acc = 0.f;
  for (int i = s; i < e; ++i)
    acc += fmaxf(fmaf(h[(size_t)i * 64 + c], sc, sh), 0.f);
  float inv = 1.0f / fmaxf((float)(e - s), 1.0f);
  pooled[(size_t)g * 64 + c] = acc * inv;
}

// ---------------- final FC ----------------
__global__ __launch_bounds__(256) void k_final(const float* __restrict__ pooled,
                                               const float* __restrict__ fcW,
                                               const float* __restrict__ fcb,
                                               float* __restrict__ out) {
  int i = blockIdx.x * 256 + threadIdx.x;
  if (i >= GG * CC) return;
  int g = i / CC, j = i % CC;
  float acc = 0.f;
#pragma unroll
  for (int k = 0; k < 64; ++k) acc = fmaf(pooled[(size_t)g * 64 + k], fcW[k * CC + j], acc);
  out[i] = acc + fcb[j];
}

extern "C" void kernel_launch(void* const* d_in, const int* in_sizes, int n_in,
                              void* d_out, int out_size, void* d_ws, size_t ws_size,
                              hipStream_t stream) {
  const float* x = (const float*)d_in[0];
  const int* eidx = (const int*)d_in[1];
  const int* batch = (const int*)d_in[2];
  const float* W[3] = {(const float*)d_in[3], (const float*)d_in[7], (const float*)d_in[11]};
  const float* gam[3] = {(const float*)d_in[5], (const float*)d_in[9], (const float*)d_in[13]};
  const float* bet[3] = {(const float*)d_in[6], (const float*)d_in[10], (const float*)d_in[14]};
  const float* fcW = (const float*)d_in[15];
  const float* fcb = (const float*)d_in[16];
  float* out = (float*)d_out;

  char* ws = (char*)d_ws;
  size_t off = 0;
  auto alloc = [&](size_t b) -> void* {
    void* p = ws + off;
    off = (off + b + 255) & ~(size_t)255;
    return p;
  };
  float* dinv = (float*)alloc((size_t)NN * 4);
  int* icnt = (int*)alloc((size_t)NN * 4);
  int* pre = (int*)alloc((size_t)NN * 4);
  int* bsum = (int*)alloc((size_t)NB_SCAN * 4);
  int* rowptr = (int*)alloc((size_t)(NN + 1) * 4);
  int* fill = (int*)alloc((size_t)NN * 4);
  int* gstart = (int*)alloc((size_t)(GG + 1) * 4);
  uint2* ep = (uint2*)alloc((size_t)EE * 8);
  float* bufA = (float*)alloc((size_t)NN * 64 * 4);
  float* bufB = (float*)alloc((size_t)NN * 64 * 4);
  double* sums = (double*)alloc(128 * 8);
  float* scale = (float*)alloc(64 * 4);
  float* shift = (float*)alloc(64 * 4);
  float* pooled = (float*)alloc((size_t)GG * 64 * 4);

  const int* src = eidx;       // edge_index[0]
  const int* dst = eidx + EE;  // edge_index[1]

  // --- preprocessing: CSR by dst + graph boundaries ---
  hipMemsetAsync(icnt, 0, (size_t)NN * 4, stream);
  hipMemsetAsync(fill, 0, (size_t)NN * 4, stream);
  k_count<<<(EE + 255) / 256, 256, 0, stream>>>(dst, icnt);
  k_dinv<<<(NN + 255) / 256, 256, 0, stream>>>(icnt, dinv);
  k_scan1<<<NB_SCAN, 256, 0, stream>>>(icnt, pre, bsum);
  k_scan2<<<1, 64, 0, stream>>>(bsum, rowptr);
  k_scan3<<<(NN + 255) / 256, 256, 0, stream>>>(pre, bsum, rowptr);
  k_fill<<<(EE + 255) / 256, 256, 0, stream>>>(src, dst, dinv, rowptr, fill, ep);
  k_bounds<<<(NN + 255) / 256, 256, 0, stream>>>(batch, gstart);

  // --- 3 GCN layers ---
  const float* h = x;
  for (int l = 0; l < 3; ++l) {
    k_gemm64f<<<(NN + 31) / 32, 256, 0, stream>>>(h, scale, shift, W[l], bufB, l > 0);
    k_gather<<<(NN + 3) / 4, 256, 0, stream>>>(rowptr, ep, dinv, bufB, bufA);
    hipMemsetAsync(sums, 0, 128 * 8, stream);
    k_bn_stats<<<(NN + 255) / 256, 256, 0, stream>>>(bufA, sums);
    k_bn_finalize<<<1, 64, 0, stream>>>(sums, gam[l], bet[l], scale, shift);
    h = bufA;
  }

  // --- pool (fused BN+ReLU of layer 2, zero atomics) + FC ---
  k_pool2<<<(GG + 3) / 4, 256, 0, stream>>>(gstart, bufA, scale, shift, pooled);
  k_final<<<(GG * CC + 255) / 256, 256, 0, stream>>>(pooled, fcW, fcb, out);
}

// Round 7
// 505.030 us; speedup vs baseline: 2.0619x; 1.1285x over previous
//
#include <hip/hip_runtime.h>
#include <math.h>

#define NN 50000
#define EE 800000
#define GG 500
#define CC 6
#define BN_EPS 1e-5f
#define NB_SCAN 49  // ceil(50000/1024)

// ---------------- degree count (int) ----------------
__global__ __launch_bounds__(256) void k_count(const int* __restrict__ dst,
                                               int* __restrict__ icnt) {
  int e = blockIdx.x * 256 + threadIdx.x;
  if (e < EE) atomicAdd(&icnt[dst[e]], 1);
}

__global__ __launch_bounds__(256) void k_dinv(const int* __restrict__ icnt,
                                              float* __restrict__ dinv) {
  int i = blockIdx.x * 256 + threadIdx.x;
  if (i < NN) dinv[i] = rsqrtf((float)(icnt[i] + 1));  // +1 self-loop
}

// ---------------- prefix sum (3-phase) ----------------
__global__ __launch_bounds__(256) void k_scan1(const int* __restrict__ icnt,
                                               int* __restrict__ pre,
                                               int* __restrict__ bsum) {
  __shared__ int ls[256];
  int base = blockIdx.x * 1024;
  int t = threadIdx.x;
  int v[4], s = 0;
#pragma unroll
  for (int j = 0; j < 4; ++j) {
    int idx = base + t * 4 + j;
    v[j] = (idx < NN) ? icnt[idx] : 0;
    s += v[j];
  }
  ls[t] = s;
  __syncthreads();
  for (int ofs = 1; ofs < 256; ofs <<= 1) {
    int y = (t >= ofs) ? ls[t - ofs] : 0;
    __syncthreads();
    ls[t] += y;
    __syncthreads();
  }
  int excl = ls[t] - s;
#pragma unroll
  for (int j = 0; j < 4; ++j) {
    int idx = base + t * 4 + j;
    if (idx < NN) pre[idx] = excl;
    excl += v[j];
  }
  if (t == 255) bsum[blockIdx.x] = ls[255];
}

__global__ void k_scan2(int* __restrict__ bsum, int* __restrict__ rowptr) {
  if (threadIdx.x == 0) {
    int run = 0;
    for (int b = 0; b < NB_SCAN; ++b) {
      int x = bsum[b];
      bsum[b] = run;
      run += x;
    }
    rowptr[NN] = EE;
  }
}

__global__ __launch_bounds__(256) void k_scan3(const int* __restrict__ pre,
                                               const int* __restrict__ bsum,
                                               int* __restrict__ rowptr) {
  int i = blockIdx.x * 256 + threadIdx.x;
  if (i < NN) rowptr[i] = pre[i] + bsum[i >> 10];
}

// ---------------- fill CSR: packed (src, weight) per edge ----------------
__global__ __launch_bounds__(256) void k_fill(const int* __restrict__ src,
                                              const int* __restrict__ dst,
                                              const float* __restrict__ dinv,
                                              const int* __restrict__ rowptr,
                                              int* __restrict__ fill,
                                              uint2* __restrict__ ep) {
  int e = blockIdx.x * 256 + threadIdx.x;
  if (e >= EE) return;
  int d = dst[e], s = src[e];
  int pos = rowptr[d] + atomicAdd(&fill[d], 1);
  uint2 p;
  p.x = (unsigned)s;
  p.y = __float_as_uint(dinv[s] * dinv[d]);
  ep[pos] = p;
}

// ---------------- tiled GEMM, BN+ReLU fused into A staging ----------------
// out[N,64] = f(A)[N,64] @ W[64,64]; f = BN(scale,shift)+ReLU if useBN.
// Block: 256 thr, 32-row tile. A-tile + W in LDS; inner loop pure FMA.
__global__ __launch_bounds__(256) void k_gemm64f(const float* __restrict__ A,
                                                 const float* __restrict__ scale,
                                                 const float* __restrict__ shift,
                                                 const float* __restrict__ W,
                                                 float* __restrict__ out,
                                                 int useBN) {
  __shared__ float Ws[64][64];
  __shared__ float As[32][64];
  int tid = threadIdx.x;
  // W: 4096 floats = 1024 float4; 4 per thread, coalesced
  const float4* W4 = (const float4*)W;
  float4* Ws4 = (float4*)&Ws[0][0];
#pragma unroll
  for (int i = 0; i < 4; ++i) Ws4[tid + 256 * i] = W4[tid + 256 * i];
  // A tile: 32 rows x 64 = 512 float4; 2 per thread; BN+ReLU on the fly
  int base = blockIdx.x * 32;
  int remain = NN - base;
  const float4* A4 = (const float4*)(A + (size_t)base * 64);
  float4* As4 = (float4*)&As[0][0];
#pragma unroll
  for (int i = 0; i < 2; ++i) {
    int idx = tid + 256 * i;      // float4 index in tile
    int r = idx >> 4;             // 16 float4 per row
    if (r < remain) {
      float4 v = A4[idx];
      if (useBN) {
        float4 scv = ((const float4*)scale)[idx & 15];
        float4 shv = ((const float4*)shift)[idx & 15];
        v.x = fmaxf(fmaf(v.x, scv.x, shv.x), 0.f);
        v.y = fmaxf(fmaf(v.y, scv.y, shv.y), 0.f);
        v.z = fmaxf(fmaf(v.z, scv.z, shv.z), 0.f);
        v.w = fmaxf(fmaf(v.w, scv.w, shv.w), 0.f);
      }
      As4[idx] = v;
    }
  }
  __syncthreads();
  int c = tid & 63;   // output channel (lane) -> Ws[k][c] conflict-free
  int w = tid >> 6;   // wave id; rows w*8 .. w*8+7
#pragma unroll
  for (int rg = 0; rg < 8; rg += 4) {
    int r0 = w * 8 + rg;
    float a0 = 0.f, a1 = 0.f, a2 = 0.f, a3 = 0.f;
#pragma unroll
    for (int k = 0; k < 64; ++k) {
      float wv = Ws[k][c];
      a0 = fmaf(As[r0 + 0][k], wv, a0);
      a1 = fmaf(As[r0 + 1][k], wv, a1);
      a2 = fmaf(As[r0 + 2][k], wv, a2);
      a3 = fmaf(As[r0 + 3][k], wv, a3);
    }
    int n = base + r0;
    if (n + 0 < NN) out[(size_t)(n + 0) * 64 + c] = a0;
    if (n + 1 < NN) out[(size_t)(n + 1) * 64 + c] = a1;
    if (n + 2 < NN) out[(size_t)(n + 2) * 64 + c] = a2;
    if (n + 3 < NN) out[(size_t)(n + 3) * 64 + c] = a3;
  }
}

// ---------------- gather-aggregate: one wave per dst node, 4-edge unroll ----------------
__global__ __launch_bounds__(256) void k_gather(const int* __restrict__ rowptr,
                                                const uint2* __restrict__ ep,
                                                const float* __restrict__ dinv,
                                                const float* __restrict__ t,
                                                float* __restrict__ outp) {
  int d = blockIdx.x * 4 + (threadIdx.x >> 6);
  int c = threadIdx.x & 63;
  if (d >= NN) return;
  float dv = dinv[d];
  float acc = dv * dv * t[(size_t)d * 64 + c];  // self-loop
  int e = rowptr[d], e1 = rowptr[d + 1];
  for (; e + 3 < e1; e += 4) {
    uint2 p0 = ep[e], p1 = ep[e + 1], p2 = ep[e + 2], p3 = ep[e + 3];
    float t0 = t[(size_t)p0.x * 64 + c];
    float t1 = t[(size_t)p1.x * 64 + c];
    float t2 = t[(size_t)p2.x * 64 + c];
    float t3 = t[(size_t)p3.x * 64 + c];
    acc = fmaf(__uint_as_float(p0.y), t0, acc);
    acc = fmaf(__uint_as_float(p1.y), t1, acc);
    acc = fmaf(__uint_as_float(p2.y), t2, acc);
    acc = fmaf(__uint_as_float(p3.y), t3, acc);
  }
  for (; e < e1; ++e) {
    uint2 p = ep[e];
    acc = fmaf(__uint_as_float(p.y), t[(size_t)p.x * 64 + c], acc);
  }
  outp[(size_t)d * 64 + c] = acc;
}

// ---------------- BatchNorm stats ----------------
__global__ __launch_bounds__(256) void k_bn_stats(const float* __restrict__ h,
                                                  double* __restrict__ sums) {
  int c = threadIdx.x & 63, r = threadIdx.x >> 6;
  int base = blockIdx.x * 256;
  float s = 0.f, sq = 0.f;
  for (int rr = r; rr < 256; rr += 4) {
    int n = base + rr;
    if (n < NN) {
      float v = h[(size_t)n * 64 + c];
      s += v;
      sq = fmaf(v, v, sq);
    }
  }
  __shared__ float ls[4][64], lq[4][64];
  ls[r][c] = s;
  lq[r][c] = sq;
  __syncthreads();
  if (r == 0) {
    float S = ls[0][c] + ls[1][c] + ls[2][c] + ls[3][c];
    float Q = lq[0][c] + lq[1][c] + lq[2][c] + lq[3][c];
    atomicAdd(&sums[c], (double)S);
    atomicAdd(&sums[64 + c], (double)Q);
  }
}

__global__ void k_bn_finalize(const double* __restrict__ sums,
                              const float* __restrict__ g,
                              const float* __restrict__ be,
                              float* __restrict__ scale,
                              float* __restrict__ shift) {
  int c = threadIdx.x;  // 64 threads
  double mu = sums[c] / (double)NN;
  double var = sums[64 + c] / (double)NN - mu * mu;
  float rstd = (float)(1.0 / sqrt(var + (double)BN_EPS));
  float scv = g[c] * rstd;
  scale[c] = scv;
  shift[c] = be[c] - (float)mu * scv;
}

// ---------------- graph boundaries in sorted batch ----------------
__global__ __launch_bounds__(256) void k_bounds(const int* __restrict__ batch,
                                                int* __restrict__ gstart) {
  int i = blockIdx.x * 256 + threadIdx.x;
  if (i >= NN) return;
  int b = batch[i];
  if (i == 0) {
    for (int g = 0; g <= b; ++g) gstart[g] = 0;
  } else {
    int pb = batch[i - 1];
    for (int g = pb + 1; g <= b; ++g) gstart[g] = i;
  }
  if (i == NN - 1) {
    for (int g = b + 1; g <= GG; ++g) gstart[g] = NN;
  }
}

// ---------------- segmented mean-pool: one wave per graph, zero atomics ----------------
__global__ __launch_bounds__(256) void k_pool2(const int* __restrict__ gstart,
                                               const float* __restrict__ h,
                                               const float* __restrict__ scale,
                                               const float* __restrict__ shift,
                                               float* __restrict__ pooled) {
  int g = blockIdx.x * 4 + (threadIdx.x >> 6);
  int c = threadIdx.x & 63;
  if (g >= GG) return;
  int s = gstart[g], e = gstart[g + 1];
  float sc = scale[c], sh = shift[c];
  float acc = 0.f;
  for (int i = s; i < e; ++i)
    acc += fmaxf(fmaf(h[(size_t)i * 64 + c], sc, sh), 0.f);
  float inv = 1.0f / fmaxf((float)(e - s), 1.0f);
  pooled[(size_t)g * 64 + c] = acc * inv;
}

// ---------------- final FC ----------------
__global__ __launch_bounds__(256) void k_final(const float* __restrict__ pooled,
                                               const float* __restrict__ fcW,
                                               const float* __restrict__ fcb,
                                               float* __restrict__ out) {
  int i = blockIdx.x * 256 + threadIdx.x;
  if (i >= GG * CC) return;
  int g = i / CC, j = i % CC;
  float acc = 0.f;
#pragma unroll
  for (int k = 0; k < 64; ++k) acc = fmaf(pooled[(size_t)g * 64 + k], fcW[k * CC + j], acc);
  out[i] = acc + fcb[j];
}

extern "C" void kernel_launch(void* const* d_in, const int* in_sizes, int n_in,
                              void* d_out, int out_size, void* d_ws, size_t ws_size,
                              hipStream_t stream) {
  const float* x = (const float*)d_in[0];
  const int* eidx = (const int*)d_in[1];
  const int* batch = (const int*)d_in[2];
  const float* W[3] = {(const float*)d_in[3], (const float*)d_in[7], (const float*)d_in[11]};
  const float* gam[3] = {(const float*)d_in[5], (const float*)d_in[9], (const float*)d_in[13]};
  const float* bet[3] = {(const float*)d_in[6], (const float*)d_in[10], (const float*)d_in[14]};
  const float* fcW = (const float*)d_in[15];
  const float* fcb = (const float*)d_in[16];
  float* out = (float*)d_out;

  char* ws = (char*)d_ws;
  size_t off = 0;
  auto alloc = [&](size_t b) -> void* {
    void* p = ws + off;
    off = (off + b + 255) & ~(size_t)255;
    return p;
  };
  float* dinv = (float*)alloc((size_t)NN * 4);
  int* icnt = (int*)alloc((size_t)NN * 4);
  int* pre = (int*)alloc((size_t)NN * 4);
  int* bsum = (int*)alloc((size_t)NB_SCAN * 4);
  int* rowptr = (int*)alloc((size_t)(NN + 1) * 4);
  int* fill = (int*)alloc((size_t)NN * 4);
  int* gstart = (int*)alloc((size_t)(GG + 1) * 4);
  uint2* ep = (uint2*)alloc((size_t)EE * 8);
  float* bufA = (float*)alloc((size_t)NN * 64 * 4);
  float* bufB = (float*)alloc((size_t)NN * 64 * 4);
  double* sums = (double*)alloc(128 * 8);
  float* scale = (float*)alloc(64 * 4);
  float* shift = (float*)alloc(64 * 4);
  float* pooled = (float*)alloc((size_t)GG * 64 * 4);

  const int* src = eidx;       // edge_index[0]
  const int* dst = eidx + EE;  // edge_index[1]

  // --- preprocessing: CSR by dst + graph boundaries ---
  hipMemsetAsync(icnt, 0, (size_t)NN * 4, stream);
  hipMemsetAsync(fill, 0, (size_t)NN * 4, stream);
  k_count<<<(EE + 255) / 256, 256, 0, stream>>>(dst, icnt);
  k_dinv<<<(NN + 255) / 256, 256, 0, stream>>>(icnt, dinv);
  k_scan1<<<NB_SCAN, 256, 0, stream>>>(icnt, pre, bsum);
  k_scan2<<<1, 64, 0, stream>>>(bsum, rowptr);
  k_scan3<<<(NN + 255) / 256, 256, 0, stream>>>(pre, bsum, rowptr);
  k_fill<<<(EE + 255) / 256, 256, 0, stream>>>(src, dst, dinv, rowptr, fill, ep);
  k_bounds<<<(NN + 255) / 256, 256, 0, stream>>>(batch, gstart);

  // --- 3 GCN layers ---
  const float* h = x;
  for (int l = 0; l < 3; ++l) {
    k_gemm64f<<<(NN + 31) / 32, 256, 0, stream>>>(h, scale, shift, W[l], bufB, l > 0);
    k_gather<<<(NN + 3) / 4, 256, 0, stream>>>(rowptr, ep, dinv, bufB, bufA);
    hipMemsetAsync(sums, 0, 128 * 8, stream);
    k_bn_stats<<<(NN + 255) / 256, 256, 0, stream>>>(bufA, sums);
    k_bn_finalize<<<1, 64, 0, stream>>>(sums, gam[l], bet[l], scale, shift);
    h = bufA;
  }

  // --- pool (fused BN+ReLU of layer 2, zero atomics) + FC ---
  k_pool2<<<(GG + 3) / 4, 256, 0, stream>>>(gstart, bufA, scale, shift, pooled);
  k_final<<<(GG * CC + 255) / 256, 256, 0, stream>>>(pooled, fcW, fcb, out);
}

// Round 8
// 418.250 us; speedup vs baseline: 2.4897x; 1.2075x over previous
//
#include <hip/hip_runtime.h>
#include <math.h>

#define NN 50000
#define EE 800000
#define GG 500
#define CC 6
#define BN_EPS 1e-5f
#define NB_SCAN 49     // ceil(50000/1024)
#define NB_CNT 3125    // ceil(800000/256)
#define NB_BND 196     // ceil(50000/256)
#define NB_GEMM 1563   // ceil(50000/32)

// ---------------- count (edges) + graph bounds (nodes), one dispatch ----------------
__global__ __launch_bounds__(256) void k_cb(const int* __restrict__ dst,
                                            int* __restrict__ icnt,
                                            const int* __restrict__ batch,
                                            int* __restrict__ gstart) {
  int b = blockIdx.x;
  if (b < NB_CNT) {
    int e = b * 256 + threadIdx.x;
    if (e < EE) atomicAdd(&icnt[dst[e]], 1);
  } else {
    int i = (b - NB_CNT) * 256 + threadIdx.x;
    if (i >= NN) return;
    int bb = batch[i];
    if (i == 0) {
      for (int g = 0; g <= bb; ++g) gstart[g] = 0;
    } else {
      int pb = batch[i - 1];
      for (int g = pb + 1; g <= bb; ++g) gstart[g] = i;
    }
    if (i == NN - 1) {
      for (int g = bb + 1; g <= GG; ++g) gstart[g] = NN;
    }
  }
}

// ---------------- prefix sum phase 1 (+ dinv fused) ----------------
__global__ __launch_bounds__(256) void k_scan1(const int* __restrict__ icnt,
                                               int* __restrict__ pre,
                                               int* __restrict__ bsum,
                                               float* __restrict__ dinv) {
  __shared__ int ls[256];
  int base = blockIdx.x * 1024;
  int t = threadIdx.x;
  int v[4], s = 0;
#pragma unroll
  for (int j = 0; j < 4; ++j) {
    int idx = base + t * 4 + j;
    v[j] = (idx < NN) ? icnt[idx] : 0;
    if (idx < NN) dinv[idx] = rsqrtf((float)(v[j] + 1));  // +1 self-loop
    s += v[j];
  }
  ls[t] = s;
  __syncthreads();
  for (int ofs = 1; ofs < 256; ofs <<= 1) {
    int y = (t >= ofs) ? ls[t - ofs] : 0;
    __syncthreads();
    ls[t] += y;
    __syncthreads();
  }
  int excl = ls[t] - s;
#pragma unroll
  for (int j = 0; j < 4; ++j) {
    int idx = base + t * 4 + j;
    if (idx < NN) pre[idx] = excl;
    excl += v[j];
  }
  if (t == 255) bsum[blockIdx.x] = ls[255];
}

// phase 2: serial scan of 49 block sums; also zero the 8-bank BN sums.
__global__ void k_scan2(int* __restrict__ bsum, int* __restrict__ rowptr,
                        double* __restrict__ sums8) {
  int t = threadIdx.x;  // 64 threads
  for (int k = t; k < 1024; k += 64) sums8[k] = 0.0;
  if (t == 0) {
    int run = 0;
    for (int b = 0; b < NB_SCAN; ++b) {
      int x = bsum[b];
      bsum[b] = run;
      run += x;
    }
    rowptr[NN] = EE;
  }
}

__global__ __launch_bounds__(256) void k_scan3(const int* __restrict__ pre,
                                               const int* __restrict__ bsum,
                                               int* __restrict__ rowptr) {
  int i = blockIdx.x * 256 + threadIdx.x;
  if (i < NN) rowptr[i] = pre[i] + bsum[i >> 10];
}

// ---------------- CSR fill + layer-0 GEMM in one dispatch ----------------
// blocks [0, NB_GEMM): out[N,64] = x @ W0 (tiled, LDS)
// blocks [NB_GEMM, NB_GEMM+NB_CNT): scatter packed (src,weight) into ep
__global__ __launch_bounds__(256) void k_fill_gemm0(const int* __restrict__ src,
                                                    const int* __restrict__ dst,
                                                    const float* __restrict__ dinv,
                                                    const int* __restrict__ rowptr,
                                                    int* __restrict__ fill,
                                                    uint2* __restrict__ ep,
                                                    const float* __restrict__ x,
                                                    const float* __restrict__ W0,
                                                    float* __restrict__ outB) {
  __shared__ float Ws[64][64];
  __shared__ float As[32][64];
  int tid = threadIdx.x;
  if (blockIdx.x >= NB_GEMM) {
    int e = (blockIdx.x - NB_GEMM) * 256 + tid;
    if (e >= EE) return;
    int d = dst[e], s = src[e];
    int pos = rowptr[d] + atomicAdd(&fill[d], 1);
    uint2 p;
    p.x = (unsigned)s;
    p.y = __float_as_uint(dinv[s] * dinv[d]);
    ep[pos] = p;
    return;
  }
  const float4* W4 = (const float4*)W0;
  float4* Ws4 = (float4*)&Ws[0][0];
#pragma unroll
  for (int i = 0; i < 4; ++i) Ws4[tid + 256 * i] = W4[tid + 256 * i];
  int base = blockIdx.x * 32;
  int remain = NN - base;
  const float4* A4 = (const float4*)(x + (size_t)base * 64);
  float4* As4 = (float4*)&As[0][0];
#pragma unroll
  for (int i = 0; i < 2; ++i) {
    int idx = tid + 256 * i;
    if ((idx >> 4) < remain) As4[idx] = A4[idx];
  }
  __syncthreads();
  int c = tid & 63;
  int w = tid >> 6;
#pragma unroll
  for (int rg = 0; rg < 8; rg += 4) {
    int r0 = w * 8 + rg;
    float a0 = 0.f, a1 = 0.f, a2 = 0.f, a3 = 0.f;
#pragma unroll
    for (int k = 0; k < 64; ++k) {
      float wv = Ws[k][c];
      a0 = fmaf(As[r0 + 0][k], wv, a0);
      a1 = fmaf(As[r0 + 1][k], wv, a1);
      a2 = fmaf(As[r0 + 2][k], wv, a2);
      a3 = fmaf(As[r0 + 3][k], wv, a3);
    }
    int n = base + r0;
    if (n + 0 < NN) outB[(size_t)(n + 0) * 64 + c] = a0;
    if (n + 1 < NN) outB[(size_t)(n + 1) * 64 + c] = a1;
    if (n + 2 < NN) outB[(size_t)(n + 2) * 64 + c] = a2;
    if (n + 3 < NN) outB[(size_t)(n + 3) * 64 + c] = a3;
  }
}

// ---------------- tiled GEMM with fused BN+ReLU on input ----------------
__global__ __launch_bounds__(256) void k_gemm64f(const float* __restrict__ A,
                                                 const float* __restrict__ scale,
                                                 const float* __restrict__ shift,
                                                 const float* __restrict__ W,
                                                 float* __restrict__ out) {
  __shared__ float Ws[64][64];
  __shared__ float As[32][64];
  int tid = threadIdx.x;
  const float4* W4 = (const float4*)W;
  float4* Ws4 = (float4*)&Ws[0][0];
#pragma unroll
  for (int i = 0; i < 4; ++i) Ws4[tid + 256 * i] = W4[tid + 256 * i];
  int base = blockIdx.x * 32;
  int remain = NN - base;
  const float4* A4 = (const float4*)(A + (size_t)base * 64);
  float4* As4 = (float4*)&As[0][0];
#pragma unroll
  for (int i = 0; i < 2; ++i) {
    int idx = tid + 256 * i;
    if ((idx >> 4) < remain) {
      float4 v = A4[idx];
      float4 scv = ((const float4*)scale)[idx & 15];
      float4 shv = ((const float4*)shift)[idx & 15];
      v.x = fmaxf(fmaf(v.x, scv.x, shv.x), 0.f);
      v.y = fmaxf(fmaf(v.y, scv.y, shv.y), 0.f);
      v.z = fmaxf(fmaf(v.z, scv.z, shv.z), 0.f);
      v.w = fmaxf(fmaf(v.w, scv.w, shv.w), 0.f);
      As4[idx] = v;
    }
  }
  __syncthreads();
  int c = tid & 63;
  int w = tid >> 6;
#pragma unroll
  for (int rg = 0; rg < 8; rg += 4) {
    int r0 = w * 8 + rg;
    float a0 = 0.f, a1 = 0.f, a2 = 0.f, a3 = 0.f;
#pragma unroll
    for (int k = 0; k < 64; ++k) {
      float wv = Ws[k][c];
      a0 = fmaf(As[r0 + 0][k], wv, a0);
      a1 = fmaf(As[r0 + 1][k], wv, a1);
      a2 = fmaf(As[r0 + 2][k], wv, a2);
      a3 = fmaf(As[r0 + 3][k], wv, a3);
    }
    int n = base + r0;
    if (n + 0 < NN) out[(size_t)(n + 0) * 64 + c] = a0;
    if (n + 1 < NN) out[(size_t)(n + 1) * 64 + c] = a1;
    if (n + 2 < NN) out[(size_t)(n + 2) * 64 + c] = a2;
    if (n + 3 < NN) out[(size_t)(n + 3) * 64 + c] = a3;
  }
}

// ---------------- gather-aggregate + fused BN stats ----------------
// wave = 8 nodes (sequential), lane = channel. Block = 32 nodes.
// Per-block stats reduced in LDS, then f64 atomics into 8 contention banks.
__global__ __launch_bounds__(256) void k_gather_stats(const int* __restrict__ rowptr,
                                                      const uint2* __restrict__ ep,
                                                      const float* __restrict__ dinv,
                                                      const float* __restrict__ t,
                                                      float* __restrict__ outp,
                                                      double* __restrict__ sums8) {
  int w = threadIdx.x >> 6;
  int c = threadIdx.x & 63;
  int nodeBase = blockIdx.x * 32 + w * 8;
  float s = 0.f, sq = 0.f;
#pragma unroll 1
  for (int j = 0; j < 8; ++j) {
    int d = nodeBase + j;
    if (d >= NN) break;
    float dv = dinv[d];
    float acc = dv * dv * t[(size_t)d * 64 + c];  // self-loop
    int e = rowptr[d], e1 = rowptr[d + 1];
    for (; e + 3 < e1; e += 4) {
      uint2 p0 = ep[e], p1 = ep[e + 1], p2 = ep[e + 2], p3 = ep[e + 3];
      float t0 = t[(size_t)p0.x * 64 + c];
      float t1 = t[(size_t)p1.x * 64 + c];
      float t2 = t[(size_t)p2.x * 64 + c];
      float t3 = t[(size_t)p3.x * 64 + c];
      acc = fmaf(__uint_as_float(p0.y), t0, acc);
      acc = fmaf(__uint_as_float(p1.y), t1, acc);
      acc = fmaf(__uint_as_float(p2.y), t2, acc);
      acc = fmaf(__uint_as_float(p3.y), t3, acc);
    }
    for (; e < e1; ++e) {
      uint2 p = ep[e];
      acc = fmaf(__uint_as_float(p.y), t[(size_t)p.x * 64 + c], acc);
    }
    outp[(size_t)d * 64 + c] = acc;
    s += acc;
    sq = fmaf(acc, acc, sq);
  }
  __shared__ float ls[4][64], lq[4][64];
  ls[w][c] = s;
  lq[w][c] = sq;
  __syncthreads();
  if (w == 0) {
    float S = ls[0][c] + ls[1][c] + ls[2][c] + ls[3][c];
    float Q = lq[0][c] + lq[1][c] + lq[2][c] + lq[3][c];
    double* bank = sums8 + (size_t)(blockIdx.x & 7) * 128;
    atomicAdd(&bank[c], (double)S);
    atomicAdd(&bank[64 + c], (double)Q);
  }
}

// ---------------- BN finalize: fold 8 banks, emit scale/shift, re-zero banks ----------------
__global__ void k_bn_finalize(double* __restrict__ sums8,
                              const float* __restrict__ g,
                              const float* __restrict__ be,
                              float* __restrict__ scale,
                              float* __restrict__ shift) {
  int c = threadIdx.x;  // 64 threads
  double S = 0.0, Q = 0.0;
  for (int k = 0; k < 8; ++k) {
    S += sums8[k * 128 + c];
    Q += sums8[k * 128 + 64 + c];
  }
  double mu = S / (double)NN;
  double var = Q / (double)NN - mu * mu;
  float rstd = (float)(1.0 / sqrt(var + (double)BN_EPS));
  float scv = g[c] * rstd;
  scale[c] = scv;
  shift[c] = be[c] - (float)mu * scv;
  __syncthreads();
  for (int k = 0; k < 8; ++k) {
    sums8[k * 128 + c] = 0.0;
    sums8[k * 128 + 64 + c] = 0.0;
  }
}

// ---------------- segmented mean-pool + final FC, one dispatch ----------------
__global__ __launch_bounds__(256) void k_pool_final(const int* __restrict__ gstart,
                                                    const float* __restrict__ h,
                                                    const float* __restrict__ scale,
                                                    const float* __restrict__ shift,
                                                    const float* __restrict__ fcW,
                                                    const float* __restrict__ fcb,
                                                    float* __restrict__ out) {
  int w = threadIdx.x >> 6;
  int c = threadIdx.x & 63;
  int g = blockIdx.x * 4 + w;
  __shared__ float pl[4][64];
  float p = 0.f;
  if (g < GG) {
    int s = gstart[g], e = gstart[g + 1];
    float sc = scale[c], sh = shift[c], acc = 0.f;
    for (int i = s; i < e; ++i)
      acc += fmaxf(fmaf(h[(size_t)i * 64 + c], sc, sh), 0.f);
    p = acc / fmaxf((float)(e - s), 1.0f);
  }
  pl[w][c] = p;
  __syncthreads();
  int t = threadIdx.x;
  if (t < 4 * CC) {
    int gw = t / CC, j = t % CC;
    int gg = blockIdx.x * 4 + gw;
    if (gg < GG) {
      float acc = 0.f;
#pragma unroll
      for (int k = 0; k < 64; ++k) acc = fmaf(pl[gw][k], fcW[k * CC + j], acc);
      out[gg * CC + j] = acc + fcb[j];
    }
  }
}

extern "C" void kernel_launch(void* const* d_in, const int* in_sizes, int n_in,
                              void* d_out, int out_size, void* d_ws, size_t ws_size,
                              hipStream_t stream) {
  const float* x = (const float*)d_in[0];
  const int* eidx = (const int*)d_in[1];
  const int* batch = (const int*)d_in[2];
  const float* W[3] = {(const float*)d_in[3], (const float*)d_in[7], (const float*)d_in[11]};
  const float* gam[3] = {(const float*)d_in[5], (const float*)d_in[9], (const float*)d_in[13]};
  const float* bet[3] = {(const float*)d_in[6], (const float*)d_in[10], (const float*)d_in[14]};
  const float* fcW = (const float*)d_in[15];
  const float* fcb = (const float*)d_in[16];
  float* out = (float*)d_out;

  char* ws = (char*)d_ws;
  size_t off = 0;
  auto alloc = [&](size_t b) -> void* {
    void* p = ws + off;
    off = (off + b + 255) & ~(size_t)255;
    return p;
  };
  int* icnt_fill = (int*)alloc((size_t)2 * NN * 4);  // icnt | fill, one memset
  int* icnt = icnt_fill;
  int* fill = icnt_fill + NN;
  float* dinv = (float*)alloc((size_t)NN * 4);
  int* pre = (int*)alloc((size_t)NN * 4);
  int* bsum = (int*)alloc((size_t)NB_SCAN * 4);
  int* rowptr = (int*)alloc((size_t)(NN + 1) * 4);
  int* gstart = (int*)alloc((size_t)(GG + 1) * 4);
  uint2* ep = (uint2*)alloc((size_t)EE * 8);
  float* bufA = (float*)alloc((size_t)NN * 64 * 4);
  float* bufB = (float*)alloc((size_t)NN * 64 * 4);
  double* sums8 = (double*)alloc(8 * 128 * 8);
  float* scale = (float*)alloc(64 * 4);
  float* shift = (float*)alloc(64 * 4);

  const int* src = eidx;       // edge_index[0]
  const int* dst = eidx + EE;  // edge_index[1]

  // --- preprocessing ---
  hipMemsetAsync(icnt_fill, 0, (size_t)2 * NN * 4, stream);
  k_cb<<<NB_CNT + NB_BND, 256, 0, stream>>>(dst, icnt, batch, gstart);
  k_scan1<<<NB_SCAN, 256, 0, stream>>>(icnt, pre, bsum, dinv);
  k_scan2<<<1, 64, 0, stream>>>(bsum, rowptr, sums8);
  k_scan3<<<(NN + 255) / 256, 256, 0, stream>>>(pre, bsum, rowptr);

  // --- CSR fill + layer-0 GEMM (one dispatch), then layers ---
  k_fill_gemm0<<<NB_GEMM + NB_CNT, 256, 0, stream>>>(src, dst, dinv, rowptr, fill,
                                                     ep, x, W[0], bufB);
  k_gather_stats<<<(NN + 31) / 32, 256, 0, stream>>>(rowptr, ep, dinv, bufB, bufA, sums8);
  k_bn_finalize<<<1, 64, 0, stream>>>(sums8, gam[0], bet[0], scale, shift);

  for (int l = 1; l < 3; ++l) {
    k_gemm64f<<<NB_GEMM, 256, 0, stream>>>(bufA, scale, shift, W[l], bufB);
    k_gather_stats<<<(NN + 31) / 32, 256, 0, stream>>>(rowptr, ep, dinv, bufB, bufA, sums8);
    k_bn_finalize<<<1, 64, 0, stream>>>(sums8, gam[l], bet[l], scale, shift);
  }

  // --- pool (fused BN+ReLU) + FC, one dispatch ---
  k_pool_final<<<(GG + 3) / 4, 256, 0, stream>>>(gstart, bufA, scale, shift, fcW, fcb, out);
}

// Round 9
// 362.605 us; speedup vs baseline: 2.8717x; 1.1535x over previous
//
#include <hip/hip_runtime.h>
#include <hip/hip_fp16.h>
#include <math.h>

#define NN 50000
#define EE 800000
#define GG 500
#define CC 6
#define BN_EPS 1e-5f
#define NB_SCAN 49     // ceil(50000/1024)
#define NB_CNT 3125    // ceil(800000/256)
#define NB_BND 196     // ceil(50000/256)
#define NB_GEMM 1563   // ceil(50000/32)

// ---------------- count (edges) + graph bounds (nodes), one dispatch ----------------
__global__ __launch_bounds__(256) void k_cb(const int* __restrict__ dst,
                                            int* __restrict__ icnt,
                                            const int* __restrict__ batch,
                                            int* __restrict__ gstart) {
  int b = blockIdx.x;
  if (b < NB_CNT) {
    int e = b * 256 + threadIdx.x;
    if (e < EE) atomicAdd(&icnt[dst[e]], 1);
  } else {
    int i = (b - NB_CNT) * 256 + threadIdx.x;
    if (i >= NN) return;
    int bb = batch[i];
    if (i == 0) {
      for (int g = 0; g <= bb; ++g) gstart[g] = 0;
    } else {
      int pb = batch[i - 1];
      for (int g = pb + 1; g <= bb; ++g) gstart[g] = i;
    }
    if (i == NN - 1) {
      for (int g = bb + 1; g <= GG; ++g) gstart[g] = NN;
    }
  }
}

// ---------------- prefix sum phase 1 (+ dinv fused) ----------------
__global__ __launch_bounds__(256) void k_scan1(const int* __restrict__ icnt,
                                               int* __restrict__ pre,
                                               int* __restrict__ bsum,
                                               float* __restrict__ dinv) {
  __shared__ int ls[256];
  int base = blockIdx.x * 1024;
  int t = threadIdx.x;
  int v[4], s = 0;
#pragma unroll
  for (int j = 0; j < 4; ++j) {
    int idx = base + t * 4 + j;
    v[j] = (idx < NN) ? icnt[idx] : 0;
    if (idx < NN) dinv[idx] = rsqrtf((float)(v[j] + 1));  // +1 self-loop
    s += v[j];
  }
  ls[t] = s;
  __syncthreads();
  for (int ofs = 1; ofs < 256; ofs <<= 1) {
    int y = (t >= ofs) ? ls[t - ofs] : 0;
    __syncthreads();
    ls[t] += y;
    __syncthreads();
  }
  int excl = ls[t] - s;
#pragma unroll
  for (int j = 0; j < 4; ++j) {
    int idx = base + t * 4 + j;
    if (idx < NN) pre[idx] = excl;
    excl += v[j];
  }
  if (t == 255) bsum[blockIdx.x] = ls[255];
}

// phase 2: serial scan of 49 block sums; also zero the 8-bank BN sums.
__global__ void k_scan2(int* __restrict__ bsum, int* __restrict__ rowptr,
                        double* __restrict__ sums8) {
  int t = threadIdx.x;  // 64 threads
  for (int k = t; k < 1024; k += 64) sums8[k] = 0.0;
  if (t == 0) {
    int run = 0;
    for (int b = 0; b < NB_SCAN; ++b) {
      int x = bsum[b];
      bsum[b] = run;
      run += x;
    }
    rowptr[NN] = EE;
  }
}

__global__ __launch_bounds__(256) void k_scan3(const int* __restrict__ pre,
                                               const int* __restrict__ bsum,
                                               int* __restrict__ rowptr) {
  int i = blockIdx.x * 256 + threadIdx.x;
  if (i < NN) rowptr[i] = pre[i] + bsum[i >> 10];
}

// ---------------- shared GEMM tile body (channel-pair lanes, fp16 out) ----------------
// 32-row tile: out[n, 2c..2c+1] (half2). Lane c2=tid&31 channel pair, slot=tid>>5 rows 4.
__device__ __forceinline__ void gemm_tile(int blockId,
                                          const float* __restrict__ A,
                                          const float* __restrict__ scale,
                                          const float* __restrict__ shift,
                                          const float* __restrict__ W,
                                          __half* __restrict__ out,
                                          bool useBN) {
  __shared__ float Ws[64][64];
  __shared__ float As[32][64];
  int tid = threadIdx.x;
  const float4* W4 = (const float4*)W;
  float4* Ws4 = (float4*)&Ws[0][0];
#pragma unroll
  for (int i = 0; i < 4; ++i) Ws4[tid + 256 * i] = W4[tid + 256 * i];
  int base = blockId * 32;
  int remain = NN - base;
  const float4* A4 = (const float4*)(A + (size_t)base * 64);
  float4* As4 = (float4*)&As[0][0];
#pragma unroll
  for (int i = 0; i < 2; ++i) {
    int idx = tid + 256 * i;
    if ((idx >> 4) < remain) {
      float4 v = A4[idx];
      if (useBN) {
        float4 scv = ((const float4*)scale)[idx & 15];
        float4 shv = ((const float4*)shift)[idx & 15];
        v.x = fmaxf(fmaf(v.x, scv.x, shv.x), 0.f);
        v.y = fmaxf(fmaf(v.y, scv.y, shv.y), 0.f);
        v.z = fmaxf(fmaf(v.z, scv.z, shv.z), 0.f);
        v.w = fmaxf(fmaf(v.w, scv.w, shv.w), 0.f);
      }
      As4[idx] = v;
    }
  }
  __syncthreads();
  int c2 = tid & 31;
  int r0 = (tid >> 5) * 4;
  float a00 = 0.f, a01 = 0.f, a10 = 0.f, a11 = 0.f;
  float a20 = 0.f, a21 = 0.f, a30 = 0.f, a31 = 0.f;
#pragma unroll
  for (int k = 0; k < 64; k += 4) {
    float4 v0 = *(const float4*)&As[r0 + 0][k];
    float4 v1 = *(const float4*)&As[r0 + 1][k];
    float4 v2 = *(const float4*)&As[r0 + 2][k];
    float4 v3 = *(const float4*)&As[r0 + 3][k];
#pragma unroll
    for (int kk = 0; kk < 4; ++kk) {
      float2 wv = *(const float2*)&Ws[k + kk][c2 * 2];
      float e0 = (kk == 0) ? v0.x : (kk == 1) ? v0.y : (kk == 2) ? v0.z : v0.w;
      float e1 = (kk == 0) ? v1.x : (kk == 1) ? v1.y : (kk == 2) ? v1.z : v1.w;
      float e2 = (kk == 0) ? v2.x : (kk == 1) ? v2.y : (kk == 2) ? v2.z : v2.w;
      float e3 = (kk == 0) ? v3.x : (kk == 1) ? v3.y : (kk == 2) ? v3.z : v3.w;
      a00 = fmaf(e0, wv.x, a00); a01 = fmaf(e0, wv.y, a01);
      a10 = fmaf(e1, wv.x, a10); a11 = fmaf(e1, wv.y, a11);
      a20 = fmaf(e2, wv.x, a20); a21 = fmaf(e2, wv.y, a21);
      a30 = fmaf(e3, wv.x, a30); a31 = fmaf(e3, wv.y, a31);
    }
  }
  int n = base + r0;
  if (n + 0 < NN) ((__half2*)(out + (size_t)(n + 0) * 64))[c2] = __floats2half2_rn(a00, a01);
  if (n + 1 < NN) ((__half2*)(out + (size_t)(n + 1) * 64))[c2] = __floats2half2_rn(a10, a11);
  if (n + 2 < NN) ((__half2*)(out + (size_t)(n + 2) * 64))[c2] = __floats2half2_rn(a20, a21);
  if (n + 3 < NN) ((__half2*)(out + (size_t)(n + 3) * 64))[c2] = __floats2half2_rn(a30, a31);
}

// ---------------- CSR fill + layer-0 GEMM in one dispatch ----------------
__global__ __launch_bounds__(256) void k_fill_gemm0(const int* __restrict__ src,
                                                    const int* __restrict__ dst,
                                                    const float* __restrict__ dinv,
                                                    const int* __restrict__ rowptr,
                                                    int* __restrict__ fill,
                                                    uint2* __restrict__ ep,
                                                    const float* __restrict__ x,
                                                    const float* __restrict__ W0,
                                                    __half* __restrict__ outB) {
  if (blockIdx.x >= NB_GEMM) {
    int e = (blockIdx.x - NB_GEMM) * 256 + threadIdx.x;
    if (e >= EE) return;
    int d = dst[e], s = src[e];
    int pos = rowptr[d] + atomicAdd(&fill[d], 1);
    uint2 p;
    p.x = (unsigned)s;
    p.y = __float_as_uint(dinv[s] * dinv[d]);
    ep[pos] = p;
    return;
  }
  gemm_tile(blockIdx.x, x, nullptr, nullptr, W0, outB, false);
}

// ---------------- tiled GEMM with fused BN+ReLU on input ----------------
__global__ __launch_bounds__(256) void k_gemm64f(const float* __restrict__ A,
                                                 const float* __restrict__ scale,
                                                 const float* __restrict__ shift,
                                                 const float* __restrict__ W,
                                                 __half* __restrict__ out) {
  gemm_tile(blockIdx.x, A, scale, shift, W, out, true);
}

// ---------------- gather-aggregate (fp16 source) + fused BN stats ----------------
// wave = 2 nodes concurrent (half-waves) x 4 sequential pairs = 8 nodes.
// lane: c2 = lane&31 -> channels 2c2,2c2+1 (half2); h = lane>>5 -> node parity.
__global__ __launch_bounds__(256) void k_gather_stats(const int* __restrict__ rowptr,
                                                      const uint2* __restrict__ ep,
                                                      const float* __restrict__ dinv,
                                                      const __half* __restrict__ t,
                                                      float* __restrict__ outp,
                                                      double* __restrict__ sums8) {
  int w = threadIdx.x >> 6;
  int lane = threadIdx.x & 63;
  int h = lane >> 5;
  int c2 = lane & 31;
  int nodeBase = blockIdx.x * 32 + w * 8;
  float2 s = {0.f, 0.f}, sq = {0.f, 0.f};
  for (int j = 0; j < 4; ++j) {
    int d = nodeBase + j * 2 + h;
    if (d < NN) {
      float dv = dinv[d];
      float2 self = __half22float2(((const __half2*)(t + (size_t)d * 64))[c2]);
      float2 acc;
      acc.x = dv * dv * self.x;
      acc.y = dv * dv * self.y;
      int e = rowptr[d], e1 = rowptr[d + 1];
      for (; e + 3 < e1; e += 4) {
        uint2 p0 = ep[e], p1 = ep[e + 1], p2 = ep[e + 2], p3 = ep[e + 3];
        float2 t0 = __half22float2(((const __half2*)(t + (size_t)p0.x * 64))[c2]);
        float2 t1 = __half22float2(((const __half2*)(t + (size_t)p1.x * 64))[c2]);
        float2 t2 = __half22float2(((const __half2*)(t + (size_t)p2.x * 64))[c2]);
        float2 t3 = __half22float2(((const __half2*)(t + (size_t)p3.x * 64))[c2]);
        float w0 = __uint_as_float(p0.y), w1 = __uint_as_float(p1.y);
        float w2 = __uint_as_float(p2.y), w3 = __uint_as_float(p3.y);
        acc.x = fmaf(w0, t0.x, acc.x); acc.y = fmaf(w0, t0.y, acc.y);
        acc.x = fmaf(w1, t1.x, acc.x); acc.y = fmaf(w1, t1.y, acc.y);
        acc.x = fmaf(w2, t2.x, acc.x); acc.y = fmaf(w2, t2.y, acc.y);
        acc.x = fmaf(w3, t3.x, acc.x); acc.y = fmaf(w3, t3.y, acc.y);
      }
      for (; e < e1; ++e) {
        uint2 p = ep[e];
        float2 tv = __half22float2(((const __half2*)(t + (size_t)p.x * 64))[c2]);
        float wv = __uint_as_float(p.y);
        acc.x = fmaf(wv, tv.x, acc.x);
        acc.y = fmaf(wv, tv.y, acc.y);
      }
      ((float2*)(outp + (size_t)d * 64))[c2] = acc;
      s.x += acc.x;
      s.y += acc.y;
      sq.x = fmaf(acc.x, acc.x, sq.x);
      sq.y = fmaf(acc.y, acc.y, sq.y);
    }
  }
  __shared__ float2 ls[4][2][32], lq[4][2][32];
  ls[w][h][c2] = s;
  lq[w][h][c2] = sq;
  __syncthreads();
  if (threadIdx.x < 64) {
    int c = threadIdx.x;
    int cc = c >> 1, comp = c & 1;
    float S = 0.f, Q = 0.f;
#pragma unroll
    for (int ww = 0; ww < 4; ++ww)
#pragma unroll
      for (int hh = 0; hh < 2; ++hh) {
        float2 v = ls[ww][hh][cc];
        float2 q = lq[ww][hh][cc];
        S += comp ? v.y : v.x;
        Q += comp ? q.y : q.x;
      }
    double* bank = sums8 + (size_t)(blockIdx.x & 7) * 128;
    atomicAdd(&bank[c], (double)S);
    atomicAdd(&bank[64 + c], (double)Q);
  }
}

// ---------------- BN finalize: fold 8 banks, emit scale/shift, re-zero banks ----------------
__global__ void k_bn_finalize(double* __restrict__ sums8,
                              const float* __restrict__ g,
                              const float* __restrict__ be,
                              float* __restrict__ scale,
                              float* __restrict__ shift) {
  int c = threadIdx.x;  // 64 threads
  double S = 0.0, Q = 0.0;
  for (int k = 0; k < 8; ++k) {
    S += sums8[k * 128 + c];
    Q += sums8[k * 128 + 64 + c];
  }
  double mu = S / (double)NN;
  double var = Q / (double)NN - mu * mu;
  float rstd = (float)(1.0 / sqrt(var + (double)BN_EPS));
  float scv = g[c] * rstd;
  scale[c] = scv;
  shift[c] = be[c] - (float)mu * scv;
  __syncthreads();
  for (int k = 0; k < 8; ++k) {
    sums8[k * 128 + c] = 0.0;
    sums8[k * 128 + 64 + c] = 0.0;
  }
}

// ---------------- segmented mean-pool + final FC, one dispatch ----------------
__global__ __launch_bounds__(256) void k_pool_final(const int* __restrict__ gstart,
                                                    const float* __restrict__ h,
                                                    const float* __restrict__ scale,
                                                    const float* __restrict__ shift,
                                                    const float* __restrict__ fcW,
                                                    const float* __restrict__ fcb,
                                                    float* __restrict__ out) {
  int w = threadIdx.x >> 6;
  int c = threadIdx.x & 63;
  int g = blockIdx.x * 4 + w;
  __shared__ float pl[4][64];
  float p = 0.f;
  if (g < GG) {
    int s = gstart[g], e = gstart[g + 1];
    float sc = scale[c], sh = shift[c], acc = 0.f;
    for (int i = s; i < e; ++i)
      acc += fmaxf(fmaf(h[(size_t)i * 64 + c], sc, sh), 0.f);
    p = acc / fmaxf((float)(e - s), 1.0f);
  }
  pl[w][c] = p;
  __syncthreads();
  int t = threadIdx.x;
  if (t < 4 * CC) {
    int gw = t / CC, j = t % CC;
    int gg = blockIdx.x * 4 + gw;
    if (gg < GG) {
      float acc = 0.f;
#pragma unroll
      for (int k = 0; k < 64; ++k) acc = fmaf(pl[gw][k], fcW[k * CC + j], acc);
      out[gg * CC + j] = acc + fcb[j];
    }
  }
}

extern "C" void kernel_launch(void* const* d_in, const int* in_sizes, int n_in,
                              void* d_out, int out_size, void* d_ws, size_t ws_size,
                              hipStream_t stream) {
  const float* x = (const float*)d_in[0];
  const int* eidx = (const int*)d_in[1];
  const int* batch = (const int*)d_in[2];
  const float* W[3] = {(const float*)d_in[3], (const float*)d_in[7], (const float*)d_in[11]};
  const float* gam[3] = {(const float*)d_in[5], (const float*)d_in[9], (const float*)d_in[13]};
  const float* bet[3] = {(const float*)d_in[6], (const float*)d_in[10], (const float*)d_in[14]};
  const float* fcW = (const float*)d_in[15];
  const float* fcb = (const float*)d_in[16];
  float* out = (float*)d_out;

  char* ws = (char*)d_ws;
  size_t off = 0;
  auto alloc = [&](size_t b) -> void* {
    void* p = ws + off;
    off = (off + b + 255) & ~(size_t)255;
    return p;
  };
  int* icnt_fill = (int*)alloc((size_t)2 * NN * 4);  // icnt | fill, one memset
  int* icnt = icnt_fill;
  int* fill = icnt_fill + NN;
  float* dinv = (float*)alloc((size_t)NN * 4);
  int* pre = (int*)alloc((size_t)NN * 4);
  int* bsum = (int*)alloc((size_t)NB_SCAN * 4);
  int* rowptr = (int*)alloc((size_t)(NN + 1) * 4);
  int* gstart = (int*)alloc((size_t)(GG + 1) * 4);
  uint2* ep = (uint2*)alloc((size_t)EE * 8);
  float* bufA = (float*)alloc((size_t)NN * 64 * 4);
  __half* bufB = (__half*)alloc((size_t)NN * 64 * 2);
  double* sums8 = (double*)alloc(8 * 128 * 8);
  float* scale = (float*)alloc(64 * 4);
  float* shift = (float*)alloc(64 * 4);

  const int* src = eidx;       // edge_index[0]
  const int* dst = eidx + EE;  // edge_index[1]

  // --- preprocessing ---
  hipMemsetAsync(icnt_fill, 0, (size_t)2 * NN * 4, stream);
  k_cb<<<NB_CNT + NB_BND, 256, 0, stream>>>(dst, icnt, batch, gstart);
  k_scan1<<<NB_SCAN, 256, 0, stream>>>(icnt, pre, bsum, dinv);
  k_scan2<<<1, 64, 0, stream>>>(bsum, rowptr, sums8);
  k_scan3<<<(NN + 255) / 256, 256, 0, stream>>>(pre, bsum, rowptr);

  // --- CSR fill + layer-0 GEMM (one dispatch), then layers ---
  k_fill_gemm0<<<NB_GEMM + NB_CNT, 256, 0, stream>>>(src, dst, dinv, rowptr, fill,
                                                     ep, x, W[0], bufB);
  k_gather_stats<<<(NN + 31) / 32, 256, 0, stream>>>(rowptr, ep, dinv, bufB, bufA, sums8);
  k_bn_finalize<<<1, 64, 0, stream>>>(sums8, gam[0], bet[0], scale, shift);

  for (int l = 1; l < 3; ++l) {
    k_gemm64f<<<NB_GEMM, 256, 0, stream>>>(bufA, scale, shift, W[l], bufB);
    k_gather_stats<<<(NN + 31) / 32, 256, 0, stream>>>(rowptr, ep, dinv, bufB, bufA, sums8);
    k_bn_finalize<<<1, 64, 0, stream>>>(sums8, gam[l], bet[l], scale, shift);
  }

  // --- pool (fused BN+ReLU) + FC, one dispatch ---
  k_pool_final<<<(GG + 3) / 4, 256, 0, stream>>>(gstart, bufA, scale, shift, fcW, fcb, out);
}

// Round 10
// 360.852 us; speedup vs baseline: 2.8857x; 1.0049x over previous
//
#include <hip/hip_runtime.h>
#include <hip/hip_fp16.h>
#include <math.h>

#define NN 50000
#define EE 800000
#define GG 500
#define CC 6
#define BN_EPS 1e-5f
#define NB_SCAN 49     // ceil(50000/1024)
#define NB_CNT 3125    // ceil(800000/256)
#define NB_BND 196     // ceil(50000/256)
#define NB_GEMM 1563   // ceil(50000/32)

// ---------------- count (edges) + graph bounds (nodes), one dispatch ----------------
__global__ __launch_bounds__(256) void k_cb(const int* __restrict__ dst,
                                            int* __restrict__ icnt,
                                            const int* __restrict__ batch,
                                            int* __restrict__ gstart) {
  int b = blockIdx.x;
  if (b < NB_CNT) {
    int e = b * 256 + threadIdx.x;
    if (e < EE) atomicAdd(&icnt[dst[e]], 1);
  } else {
    int i = (b - NB_CNT) * 256 + threadIdx.x;
    if (i >= NN) return;
    int bb = batch[i];
    if (i == 0) {
      for (int g = 0; g <= bb; ++g) gstart[g] = 0;
    } else {
      int pb = batch[i - 1];
      for (int g = pb + 1; g <= bb; ++g) gstart[g] = i;
    }
    if (i == NN - 1) {
      for (int g = bb + 1; g <= GG; ++g) gstart[g] = NN;
    }
  }
}

// ---------------- prefix sum phase 1 over CEIL4(deg) (+ dinv fused) ----------------
__global__ __launch_bounds__(256) void k_scan1(const int* __restrict__ icnt,
                                               int* __restrict__ pre,
                                               int* __restrict__ bsum,
                                               float* __restrict__ dinv) {
  __shared__ int ls[256];
  int base = blockIdx.x * 1024;
  int t = threadIdx.x;
  int v[4], s = 0;
#pragma unroll
  for (int j = 0; j < 4; ++j) {
    int idx = base + t * 4 + j;
    int raw = (idx < NN) ? icnt[idx] : 0;
    if (idx < NN) dinv[idx] = rsqrtf((float)(raw + 1));  // +1 self-loop
    v[j] = (raw + 3) & ~3;  // padded length (keeps row starts 4-aligned)
    s += v[j];
  }
  ls[t] = s;
  __syncthreads();
  for (int ofs = 1; ofs < 256; ofs <<= 1) {
    int y = (t >= ofs) ? ls[t - ofs] : 0;
    __syncthreads();
    ls[t] += y;
    __syncthreads();
  }
  int excl = ls[t] - s;
#pragma unroll
  for (int j = 0; j < 4; ++j) {
    int idx = base + t * 4 + j;
    if (idx < NN) pre[idx] = excl;
    excl += v[j];
  }
  if (t == 255) bsum[blockIdx.x] = ls[255];
}

// phase 2: serial scan of 49 block sums; also zero the 3 per-layer BN stat regions.
__global__ void k_scan2(int* __restrict__ bsum, int* __restrict__ rowptr,
                        double* __restrict__ sums24) {
  int t = threadIdx.x;  // 64 threads
  for (int k = t; k < 3 * 1024; k += 64) sums24[k] = 0.0;
  if (t == 0) {
    int run = 0;
    for (int b = 0; b < NB_SCAN; ++b) {
      int x = bsum[b];
      bsum[b] = run;
      run += x;
    }
    rowptr[NN] = run;
  }
}

__global__ __launch_bounds__(256) void k_scan3(const int* __restrict__ pre,
                                               const int* __restrict__ bsum,
                                               int* __restrict__ rowptr) {
  int i = blockIdx.x * 256 + threadIdx.x;
  if (i < NN) rowptr[i] = pre[i] + bsum[i >> 10];
}

// ---------------- shared GEMM tile body ----------------
// out[n, :] = dinv[n] * f(A[n]) @ W  as half2 lanes; f = BN+ReLU (stats inlined) if sums!=null.
__device__ __forceinline__ void gemm_tile(int blockId,
                                          const float* __restrict__ A,
                                          const double* __restrict__ sums,
                                          const float* __restrict__ gamma,
                                          const float* __restrict__ beta,
                                          const float* __restrict__ W,
                                          const float* __restrict__ dinv,
                                          __half* __restrict__ out,
                                          bool useBN) {
  __shared__ float Ws[64][64];
  __shared__ float As[32][64];
  __shared__ float sc[64], sh[64];
  int tid = threadIdx.x;
  if (useBN && tid < 64) {
    double S = 0.0, Q = 0.0;
#pragma unroll
    for (int k = 0; k < 8; ++k) {
      S += sums[k * 128 + tid];
      Q += sums[k * 128 + 64 + tid];
    }
    double mu = S / (double)NN;
    double var = Q / (double)NN - mu * mu;
    float rstd = (float)(1.0 / sqrt(var + (double)BN_EPS));
    float scv = gamma[tid] * rstd;
    sc[tid] = scv;
    sh[tid] = beta[tid] - (float)mu * scv;
  }
  const float4* W4 = (const float4*)W;
  float4* Ws4 = (float4*)&Ws[0][0];
#pragma unroll
  for (int i = 0; i < 4; ++i) Ws4[tid + 256 * i] = W4[tid + 256 * i];
  if (useBN) __syncthreads();  // sc/sh ready before A staging
  int base = blockId * 32;
  int remain = NN - base;
  const float4* A4 = (const float4*)(A + (size_t)base * 64);
  float4* As4 = (float4*)&As[0][0];
#pragma unroll
  for (int i = 0; i < 2; ++i) {
    int idx = tid + 256 * i;
    if ((idx >> 4) < remain) {
      float4 v = A4[idx];
      if (useBN) {
        float4 scv = *(const float4*)&sc[(idx & 15) * 4];
        float4 shv = *(const float4*)&sh[(idx & 15) * 4];
        v.x = fmaxf(fmaf(v.x, scv.x, shv.x), 0.f);
        v.y = fmaxf(fmaf(v.y, scv.y, shv.y), 0.f);
        v.z = fmaxf(fmaf(v.z, scv.z, shv.z), 0.f);
        v.w = fmaxf(fmaf(v.w, scv.w, shv.w), 0.f);
      }
      As4[idx] = v;
    }
  }
  __syncthreads();
  int c2 = tid & 31;
  int r0 = (tid >> 5) * 4;
  float a00 = 0.f, a01 = 0.f, a10 = 0.f, a11 = 0.f;
  float a20 = 0.f, a21 = 0.f, a30 = 0.f, a31 = 0.f;
#pragma unroll
  for (int k = 0; k < 64; k += 4) {
    float4 v0 = *(const float4*)&As[r0 + 0][k];
    float4 v1 = *(const float4*)&As[r0 + 1][k];
    float4 v2 = *(const float4*)&As[r0 + 2][k];
    float4 v3 = *(const float4*)&As[r0 + 3][k];
#pragma unroll
    for (int kk = 0; kk < 4; ++kk) {
      float2 wv = *(const float2*)&Ws[k + kk][c2 * 2];
      float e0 = (kk == 0) ? v0.x : (kk == 1) ? v0.y : (kk == 2) ? v0.z : v0.w;
      float e1 = (kk == 0) ? v1.x : (kk == 1) ? v1.y : (kk == 2) ? v1.z : v1.w;
      float e2 = (kk == 0) ? v2.x : (kk == 1) ? v2.y : (kk == 2) ? v2.z : v2.w;
      float e3 = (kk == 0) ? v3.x : (kk == 1) ? v3.y : (kk == 2) ? v3.z : v3.w;
      a00 = fmaf(e0, wv.x, a00); a01 = fmaf(e0, wv.y, a01);
      a10 = fmaf(e1, wv.x, a10); a11 = fmaf(e1, wv.y, a11);
      a20 = fmaf(e2, wv.x, a20); a21 = fmaf(e2, wv.y, a21);
      a30 = fmaf(e3, wv.x, a30); a31 = fmaf(e3, wv.y, a31);
    }
  }
  int n = base + r0;
  if (n + 0 < NN) { float dv = dinv[n + 0]; ((__half2*)(out + (size_t)(n + 0) * 64))[c2] = __floats2half2_rn(a00 * dv, a01 * dv); }
  if (n + 1 < NN) { float dv = dinv[n + 1]; ((__half2*)(out + (size_t)(n + 1) * 64))[c2] = __floats2half2_rn(a10 * dv, a11 * dv); }
  if (n + 2 < NN) { float dv = dinv[n + 2]; ((__half2*)(out + (size_t)(n + 2) * 64))[c2] = __floats2half2_rn(a20 * dv, a21 * dv); }
  if (n + 3 < NN) { float dv = dinv[n + 3]; ((__half2*)(out + (size_t)(n + 3) * 64))[c2] = __floats2half2_rn(a30 * dv, a31 * dv); }
}

// ---------------- CSR fill (ushort src only) + layer-0 GEMM in one dispatch ----------------
__global__ __launch_bounds__(256) void k_fill_gemm0(const int* __restrict__ src,
                                                    const int* __restrict__ dst,
                                                    const float* __restrict__ dinv,
                                                    const int* __restrict__ rowptr,
                                                    int* __restrict__ fill,
                                                    unsigned short* __restrict__ ep,
                                                    const float* __restrict__ x,
                                                    const float* __restrict__ W0,
                                                    __half* __restrict__ outB) {
  if (blockIdx.x >= NB_GEMM) {
    int e = (blockIdx.x - NB_GEMM) * 256 + threadIdx.x;
    if (e >= EE) return;
    int d = dst[e];
    int pos = rowptr[d] + atomicAdd(&fill[d], 1);
    ep[pos] = (unsigned short)src[e];
    return;
  }
  gemm_tile(blockIdx.x, x, nullptr, nullptr, nullptr, W0, dinv, outB, false);
}

// ---------------- tiled GEMM with inlined BN-finalize + fused BN+ReLU ----------------
__global__ __launch_bounds__(256) void k_gemm64f(const float* __restrict__ A,
                                                 const double* __restrict__ sums,
                                                 const float* __restrict__ gamma,
                                                 const float* __restrict__ beta,
                                                 const float* __restrict__ W,
                                                 const float* __restrict__ dinv,
                                                 __half* __restrict__ out) {
  gemm_tile(blockIdx.x, A, sums, gamma, beta, W, dinv, out, true);
}

// ---------------- gather-aggregate (weight-free, fp16 rows) + fused BN stats ----------------
// out[d] = dinv[d] * (t'[d] + sum_{s in N(d)} t'[s]);  t' rows already dinv-prescaled.
__global__ __launch_bounds__(256) void k_gather_stats(const int* __restrict__ rowptr,
                                                      const int* __restrict__ icnt,
                                                      const unsigned short* __restrict__ ep,
                                                      const float* __restrict__ dinv,
                                                      const __half* __restrict__ t,
                                                      float* __restrict__ outp,
                                                      double* __restrict__ sums8) {
  int w = threadIdx.x >> 6;
  int lane = threadIdx.x & 63;
  int h = lane >> 5;
  int c2 = lane & 31;
  int nodeBase = blockIdx.x * 32 + w * 8;
  float2 s = {0.f, 0.f}, sq = {0.f, 0.f};
  for (int j = 0; j < 4; ++j) {
    int d = nodeBase + j * 2 + h;
    if (d < NN) {
      float2 acc = __half22float2(((const __half2*)(t + (size_t)d * 64))[c2]);  // self t'[d]
      int e0 = rowptr[d], cnt = icnt[d];
      int k = 0;
      for (; k + 3 < cnt; k += 4) {
        ushort4 q = *(const ushort4*)&ep[e0 + k];  // e0 is 4-aligned by construction
        float2 t0 = __half22float2(((const __half2*)(t + (size_t)q.x * 64))[c2]);
        float2 t1 = __half22float2(((const __half2*)(t + (size_t)q.y * 64))[c2]);
        float2 t2 = __half22float2(((const __half2*)(t + (size_t)q.z * 64))[c2]);
        float2 t3 = __half22float2(((const __half2*)(t + (size_t)q.w * 64))[c2]);
        acc.x += t0.x + t1.x + t2.x + t3.x;
        acc.y += t0.y + t1.y + t2.y + t3.y;
      }
      for (; k < cnt; ++k) {
        float2 tv = __half22float2(((const __half2*)(t + (size_t)ep[e0 + k] * 64))[c2]);
        acc.x += tv.x;
        acc.y += tv.y;
      }
      float dv = dinv[d];
      acc.x *= dv;
      acc.y *= dv;
      ((float2*)(outp + (size_t)d * 64))[c2] = acc;
      s.x += acc.x;
      s.y += acc.y;
      sq.x = fmaf(acc.x, acc.x, sq.x);
      sq.y = fmaf(acc.y, acc.y, sq.y);
    }
  }
  __shared__ float2 ls[4][2][32], lq[4][2][32];
  ls[w][h][c2] = s;
  lq[w][h][c2] = sq;
  __syncthreads();
  if (threadIdx.x < 64) {
    int c = threadIdx.x;
    int cc = c >> 1, comp = c & 1;
    float S = 0.f, Q = 0.f;
#pragma unroll
    for (int ww = 0; ww < 4; ++ww)
#pragma unroll
      for (int hh = 0; hh < 2; ++hh) {
        float2 v = ls[ww][hh][cc];
        float2 q = lq[ww][hh][cc];
        S += comp ? v.y : v.x;
        Q += comp ? q.y : q.x;
      }
    double* bank = sums8 + (size_t)(blockIdx.x & 7) * 128;
    atomicAdd(&bank[c], (double)S);
    atomicAdd(&bank[64 + c], (double)Q);
  }
}

// ---------------- segmented mean-pool (inlined BN) + final FC, one dispatch ----------------
__global__ __launch_bounds__(256) void k_pool_final(const int* __restrict__ gstart,
                                                    const float* __restrict__ h,
                                                    const double* __restrict__ sums,
                                                    const float* __restrict__ gamma,
                                                    const float* __restrict__ beta,
                                                    const float* __restrict__ fcW,
                                                    const float* __restrict__ fcb,
                                                    float* __restrict__ out) {
  __shared__ float sc[64], sh[64];
  __shared__ float pl[4][64];
  int tid = threadIdx.x;
  if (tid < 64) {
    double S = 0.0, Q = 0.0;
#pragma unroll
    for (int k = 0; k < 8; ++k) {
      S += sums[k * 128 + tid];
      Q += sums[k * 128 + 64 + tid];
    }
    double mu = S / (double)NN;
    double var = Q / (double)NN - mu * mu;
    float rstd = (float)(1.0 / sqrt(var + (double)BN_EPS));
    float scv = gamma[tid] * rstd;
    sc[tid] = scv;
    sh[tid] = beta[tid] - (float)mu * scv;
  }
  __syncthreads();
  int w = tid >> 6;
  int c = tid & 63;
  int g = blockIdx.x * 4 + w;
  float p = 0.f;
  if (g < GG) {
    int s = gstart[g], e = gstart[g + 1];
    float scv = sc[c], shv = sh[c], acc = 0.f;
    for (int i = s; i < e; ++i)
      acc += fmaxf(fmaf(h[(size_t)i * 64 + c], scv, shv), 0.f);
    p = acc / fmaxf((float)(e - s), 1.0f);
  }
  pl[w][c] = p;
  __syncthreads();
  if (tid < 4 * CC) {
    int gw = tid / CC, j = tid % CC;
    int gg = blockIdx.x * 4 + gw;
    if (gg < GG) {
      float acc = 0.f;
#pragma unroll
      for (int k = 0; k < 64; ++k) acc = fmaf(pl[gw][k], fcW[k * CC + j], acc);
      out[gg * CC + j] = acc + fcb[j];
    }
  }
}

extern "C" void kernel_launch(void* const* d_in, const int* in_sizes, int n_in,
                              void* d_out, int out_size, void* d_ws, size_t ws_size,
                              hipStream_t stream) {
  const float* x = (const float*)d_in[0];
  const int* eidx = (const int*)d_in[1];
  const int* batch = (const int*)d_in[2];
  const float* W[3] = {(const float*)d_in[3], (const float*)d_in[7], (const float*)d_in[11]};
  const float* gam[3] = {(const float*)d_in[5], (const float*)d_in[9], (const float*)d_in[13]};
  const float* bet[3] = {(const float*)d_in[6], (const float*)d_in[10], (const float*)d_in[14]};
  const float* fcW = (const float*)d_in[15];
  const float* fcb = (const float*)d_in[16];
  float* out = (float*)d_out;

  char* ws = (char*)d_ws;
  size_t off = 0;
  auto alloc = [&](size_t b) -> void* {
    void* p = ws + off;
    off = (off + b + 255) & ~(size_t)255;
    return p;
  };
  int* icnt_fill = (int*)alloc((size_t)2 * NN * 4);  // icnt | fill, one memset
  int* icnt = icnt_fill;
  int* fill = icnt_fill + NN;
  float* dinv = (float*)alloc((size_t)NN * 4);
  int* pre = (int*)alloc((size_t)NN * 4);
  int* bsum = (int*)alloc((size_t)NB_SCAN * 4);
  int* rowptr = (int*)alloc((size_t)(NN + 1) * 4);
  int* gstart = (int*)alloc((size_t)(GG + 1) * 4);
  unsigned short* ep = (unsigned short*)alloc((size_t)(EE + 4 * NN) * 2);  // padded CSR
  float* bufA = (float*)alloc((size_t)NN * 64 * 4);
  __half* bufB = (__half*)alloc((size_t)NN * 64 * 2);
  double* sums24 = (double*)alloc((size_t)3 * 1024 * 8);  // per-layer 8-bank stats

  const int* src = eidx;       // edge_index[0]
  const int* dst = eidx + EE;  // edge_index[1]

  // --- preprocessing ---
  hipMemsetAsync(icnt_fill, 0, (size_t)2 * NN * 4, stream);
  k_cb<<<NB_CNT + NB_BND, 256, 0, stream>>>(dst, icnt, batch, gstart);
  k_scan1<<<NB_SCAN, 256, 0, stream>>>(icnt, pre, bsum, dinv);
  k_scan2<<<1, 64, 0, stream>>>(bsum, rowptr, sums24);
  k_scan3<<<(NN + 255) / 256, 256, 0, stream>>>(pre, bsum, rowptr);

  // --- CSR fill + layer-0 GEMM (one dispatch), then layers ---
  k_fill_gemm0<<<NB_GEMM + NB_CNT, 256, 0, stream>>>(src, dst, dinv, rowptr, fill,
                                                     ep, x, W[0], bufB);
  k_gather_stats<<<(NN + 31) / 32, 256, 0, stream>>>(rowptr, icnt, ep, dinv, bufB, bufA,
                                                     sums24 + 0 * 1024);
  for (int l = 1; l < 3; ++l) {
    k_gemm64f<<<NB_GEMM, 256, 0, stream>>>(bufA, sums24 + (l - 1) * 1024, gam[l - 1],
                                           bet[l - 1], W[l], dinv, bufB);
    k_gather_stats<<<(NN + 31) / 32, 256, 0, stream>>>(rowptr, icnt, ep, dinv, bufB, bufA,
                                                       sums24 + l * 1024);
  }

  // --- pool (inlined BN of layer 2) + FC, one dispatch ---
  k_pool_final<<<(GG + 3) / 4, 256, 0, stream>>>(gstart, bufA, sums24 + 2 * 1024, gam[2],
                                                 bet[2], fcW, fcb, out);
}

// Round 11
// 332.103 us; speedup vs baseline: 3.1355x; 1.0866x over previous
//
#include <hip/hip_runtime.h>
#include <hip/hip_fp16.h>
#include <math.h>

#define NN 50000
#define EE 800000
#define GG 500
#define CC 6
#define BN_EPS 1e-5f
#define NB_SCAN 49     // ceil(50000/1024)
#define NB_CNT 3125    // ceil(800000/256)
#define NB_BND 196     // ceil(50000/256)
#define NB_GEMM 1563   // ceil(50000/32)
#define NBKT 98        // buckets of 512 nodes (dst>>9)
#define NB_PART 100    // partition blocks, 8000 edges each

// ---------------- count (edges) + graph bounds (nodes), one dispatch ----------------
__global__ __launch_bounds__(256) void k_cb(const int* __restrict__ dst,
                                            int* __restrict__ icnt,
                                            const int* __restrict__ batch,
                                            int* __restrict__ gstart) {
  int b = blockIdx.x;
  if (b < NB_CNT) {
    int e = b * 256 + threadIdx.x;
    if (e < EE) atomicAdd(&icnt[dst[e]], 1);
  } else {
    int i = (b - NB_CNT) * 256 + threadIdx.x;
    if (i >= NN) return;
    int bb = batch[i];
    if (i == 0) {
      for (int g = 0; g <= bb; ++g) gstart[g] = 0;
    } else {
      int pb = batch[i - 1];
      for (int g = pb + 1; g <= bb; ++g) gstart[g] = i;
    }
    if (i == NN - 1) {
      for (int g = bb + 1; g <= GG; ++g) gstart[g] = NN;
    }
  }
}

// ---------------- scan phase 1 over CEIL4(deg); also dinv + raw per-512-bucket sums ----------------
__global__ __launch_bounds__(256) void k_scan1(const int* __restrict__ icnt,
                                               int* __restrict__ pre,
                                               int* __restrict__ bsum,
                                               float* __restrict__ dinv,
                                               int* __restrict__ braw) {
  __shared__ int ls[256];
  __shared__ int lr[256];
  int base = blockIdx.x * 1024;
  int t = threadIdx.x;
  int v[4], s = 0, sraw = 0;
#pragma unroll
  for (int j = 0; j < 4; ++j) {
    int idx = base + t * 4 + j;
    int raw = (idx < NN) ? icnt[idx] : 0;
    if (idx < NN) dinv[idx] = rsqrtf((float)(raw + 1));  // +1 self-loop
    sraw += raw;
    v[j] = (raw + 3) & ~3;  // padded length (row starts 4-aligned)
    s += v[j];
  }
  ls[t] = s;
  lr[t] = sraw;
  __syncthreads();
  for (int ofs = 1; ofs < 256; ofs <<= 1) {
    int y = (t >= ofs) ? ls[t - ofs] : 0;
    __syncthreads();
    ls[t] += y;
    __syncthreads();
  }
  int excl = ls[t] - s;
#pragma unroll
  for (int j = 0; j < 4; ++j) {
    int idx = base + t * 4 + j;
    if (idx < NN) pre[idx] = excl;
    excl += v[j];
  }
  if (t == 255) bsum[blockIdx.x] = ls[255];
  // raw sums per 512-node half (threads 0..127 / 128..255)
  for (int ofs = 64; ofs >= 1; ofs >>= 1) {
    __syncthreads();
    if ((t & 127) < ofs) lr[t] += lr[t + ofs];
  }
  __syncthreads();
  if (t == 0) braw[2 * blockIdx.x] = lr[0];
  if (t == 128 && 2 * blockIdx.x + 1 < NBKT) braw[2 * blockIdx.x + 1] = lr[128];
}

// phase 2: serial scan of 49 block sums; zero 3 per-layer BN stat regions.
__global__ void k_scan2(int* __restrict__ bsum, int* __restrict__ rowptr,
                        double* __restrict__ sums24) {
  int t = threadIdx.x;  // 64 threads
  for (int k = t; k < 3 * 1024; k += 64) sums24[k] = 0.0;
  if (t == 0) {
    int run = 0;
    for (int b = 0; b < NB_SCAN; ++b) {
      int x = bsum[b];
      bsum[b] = run;
      run += x;
    }
    rowptr[NN] = run;
  }
}

// phase 3: rowptr; also init bucket write cursors gcur[b] = rowptr[b*512]
__global__ __launch_bounds__(256) void k_scan3(const int* __restrict__ pre,
                                               const int* __restrict__ bsum,
                                               int* __restrict__ rowptr,
                                               int* __restrict__ gcur) {
  int i = blockIdx.x * 256 + threadIdx.x;
  if (i < NN) {
    int v = pre[i] + bsum[i >> 10];
    rowptr[i] = v;
    if ((i & 511) == 0) gcur[i >> 9] = v;
  }
}

// ---------------- shared GEMM tile body ----------------
// out[n,:] = dinv[n] * f(A[n]) @ W  (half2 lanes); LAYER0: A=f32, no BN. else A=f16 + BN+ReLU.
template <bool LAYER0>
__device__ __forceinline__ void gemm_tile(int blockId,
                                          const void* __restrict__ Aptr,
                                          const double* __restrict__ sums,
                                          const float* __restrict__ gamma,
                                          const float* __restrict__ beta,
                                          const float* __restrict__ W,
                                          const float* __restrict__ dinv,
                                          __half* __restrict__ out) {
  __shared__ float Ws[64][64];
  __shared__ float As[32][64];
  __shared__ float sc[64], sh[64];
  int tid = threadIdx.x;
  if (!LAYER0 && tid < 64) {
    double S = 0.0, Q = 0.0;
#pragma unroll
    for (int k = 0; k < 8; ++k) {
      S += sums[k * 128 + tid];
      Q += sums[k * 128 + 64 + tid];
    }
    double mu = S / (double)NN;
    double var = Q / (double)NN - mu * mu;
    float rstd = (float)(1.0 / sqrt(var + (double)BN_EPS));
    float scv = gamma[tid] * rstd;
    sc[tid] = scv;
    sh[tid] = beta[tid] - (float)mu * scv;
  }
  const float4* W4 = (const float4*)W;
  float4* Ws4 = (float4*)&Ws[0][0];
#pragma unroll
  for (int i = 0; i < 4; ++i) Ws4[tid + 256 * i] = W4[tid + 256 * i];
  if (!LAYER0) __syncthreads();  // sc/sh ready
  int base = blockId * 32;
  int remain = NN - base;
  float4* As4 = (float4*)&As[0][0];
  if (LAYER0) {
    const float4* A4 = (const float4*)((const float*)Aptr + (size_t)base * 64);
#pragma unroll
    for (int i = 0; i < 2; ++i) {
      int idx = tid + 256 * i;
      if ((idx >> 4) < remain) As4[idx] = A4[idx];
    }
  } else {
    // fp16 input: one uint4 = 8 halves per thread covers the 32x64 tile
    const uint4* A8 = (const uint4*)((const __half*)Aptr + (size_t)base * 64);
    int r = tid >> 3;
    if (r < remain) {
      uint4 u = A8[tid];
      int c0 = (tid & 7) * 8;
      float f[8];
      __half2 h;
      h = *(__half2*)&u.x; f[0] = __low2float(h); f[1] = __high2float(h);
      h = *(__half2*)&u.y; f[2] = __low2float(h); f[3] = __high2float(h);
      h = *(__half2*)&u.z; f[4] = __low2float(h); f[5] = __high2float(h);
      h = *(__half2*)&u.w; f[6] = __low2float(h); f[7] = __high2float(h);
#pragma unroll
      for (int j = 0; j < 8; ++j)
        f[j] = fmaxf(fmaf(f[j], sc[c0 + j], sh[c0 + j]), 0.f);
      float4 lo = {f[0], f[1], f[2], f[3]}, hi = {f[4], f[5], f[6], f[7]};
      As4[(r << 4) + (tid & 7) * 2 + 0] = lo;
      As4[(r << 4) + (tid & 7) * 2 + 1] = hi;
    }
  }
  __syncthreads();
  int c2 = tid & 31;
  int r0 = (tid >> 5) * 4;
  float a00 = 0.f, a01 = 0.f, a10 = 0.f, a11 = 0.f;
  float a20 = 0.f, a21 = 0.f, a30 = 0.f, a31 = 0.f;
#pragma unroll
  for (int k = 0; k < 64; k += 4) {
    float4 v0 = *(const float4*)&As[r0 + 0][k];
    float4 v1 = *(const float4*)&As[r0 + 1][k];
    float4 v2 = *(const float4*)&As[r0 + 2][k];
    float4 v3 = *(const float4*)&As[r0 + 3][k];
#pragma unroll
    for (int kk = 0; kk < 4; ++kk) {
      float2 wv = *(const float2*)&Ws[k + kk][c2 * 2];
      float e0 = (kk == 0) ? v0.x : (kk == 1) ? v0.y : (kk == 2) ? v0.z : v0.w;
      float e1 = (kk == 0) ? v1.x : (kk == 1) ? v1.y : (kk == 2) ? v1.z : v1.w;
      float e2 = (kk == 0) ? v2.x : (kk == 1) ? v2.y : (kk == 2) ? v2.z : v2.w;
      float e3 = (kk == 0) ? v3.x : (kk == 1) ? v3.y : (kk == 2) ? v3.z : v3.w;
      a00 = fmaf(e0, wv.x, a00); a01 = fmaf(e0, wv.y, a01);
      a10 = fmaf(e1, wv.x, a10); a11 = fmaf(e1, wv.y, a11);
      a20 = fmaf(e2, wv.x, a20); a21 = fmaf(e2, wv.y, a21);
      a30 = fmaf(e3, wv.x, a30); a31 = fmaf(e3, wv.y, a31);
    }
  }
  int n = base + r0;
  if (n + 0 < NN) { float dv = dinv[n + 0]; ((__half2*)(out + (size_t)(n + 0) * 64))[c2] = __floats2half2_rn(a00 * dv, a01 * dv); }
  if (n + 1 < NN) { float dv = dinv[n + 1]; ((__half2*)(out + (size_t)(n + 1) * 64))[c2] = __floats2half2_rn(a10 * dv, a11 * dv); }
  if (n + 2 < NN) { float dv = dinv[n + 2]; ((__half2*)(out + (size_t)(n + 2) * 64))[c2] = __floats2half2_rn(a20 * dv, a21 * dv); }
  if (n + 3 < NN) { float dv = dinv[n + 3]; ((__half2*)(out + (size_t)(n + 3) * 64))[c2] = __floats2half2_rn(a30 * dv, a31 * dv); }
}

// ---------------- edge partition by dst>>9 (LDS-binned) + layer-0 GEMM, one dispatch ----------------
__global__ __launch_bounds__(256) void k_part_gemm0(const int* __restrict__ src,
                                                    const int* __restrict__ dst,
                                                    int* __restrict__ gcur,
                                                    unsigned int* __restrict__ part,
                                                    const float* __restrict__ x,
                                                    const float* __restrict__ W0,
                                                    const float* __restrict__ dinv,
                                                    __half* __restrict__ outB) {
  if (blockIdx.x >= NB_GEMM) {
    __shared__ int lcnt[NBKT], lofs[NBKT], lcur[NBKT];
    int tid = threadIdx.x;
    int cb = (blockIdx.x - NB_GEMM) * 8000;
    if (tid < NBKT) lcnt[tid] = 0;
    __syncthreads();
    for (int it = 0; it < 32; ++it) {
      int o = it * 256 + tid;
      if (o < 8000) atomicAdd(&lcnt[dst[cb + o] >> 9], 1);
    }
    __syncthreads();
    if (tid < NBKT) {
      lofs[tid] = atomicAdd(&gcur[tid], lcnt[tid]);
      lcur[tid] = 0;
    }
    __syncthreads();
    for (int it = 0; it < 32; ++it) {
      int o = it * 256 + tid;
      if (o < 8000) {
        int d = dst[cb + o];
        int bkt = d >> 9;
        int pos = lofs[bkt] + atomicAdd(&lcur[bkt], 1);
        part[pos] = ((unsigned)(d & 511) << 16) | (unsigned)src[cb + o];
      }
    }
    return;
  }
  gemm_tile<true>(blockIdx.x, x, nullptr, nullptr, nullptr, W0, dinv, outB);
}

// ---------------- CSR fill from partition: one block per bucket (XCD-local writes) ----------------
__global__ __launch_bounds__(512) void k_fill2(const int* __restrict__ rowptr,
                                               const int* __restrict__ braw,
                                               const unsigned int* __restrict__ part,
                                               unsigned short* __restrict__ ep) {
  __shared__ int lrp[512];
  __shared__ int lfill[512];
  int b = blockIdx.x;
  int tid = threadIdx.x;
  int nbase = b << 9;
  lrp[tid] = (nbase + tid < NN) ? rowptr[nbase + tid] : 0;
  lfill[tid] = 0;
  __syncthreads();
  int start = lrp[0];
  int cnt = braw[b];
  for (int i = tid; i < cnt; i += 512) {
    unsigned p = part[start + i];
    int dloc = p >> 16;
    int pos = lrp[dloc] + atomicAdd(&lfill[dloc], 1);
    ep[pos] = (unsigned short)(p & 0xFFFF);
  }
}

// ---------------- gather-aggregate (weight-free, fp16 in/out) + fused BN stats ----------------
// wave = 4 concurrent nodes (16 lanes each, ushort4 = 4 channels/lane) x 2 sequential.
__global__ __launch_bounds__(256) void k_gather_stats(const int* __restrict__ rowptr,
                                                      const int* __restrict__ icnt,
                                                      const unsigned short* __restrict__ ep,
                                                      const float* __restrict__ dinv,
                                                      const __half* __restrict__ t,
                                                      __half* __restrict__ outp,
                                                      double* __restrict__ sums8) {
  int w = threadIdx.x >> 6;
  int lane = threadIdx.x & 63;
  int q = lane >> 4;
  int cl = lane & 15;
  int nodeBase = blockIdx.x * 32 + w * 8;
  float4 s = {0.f, 0.f, 0.f, 0.f}, sq = {0.f, 0.f, 0.f, 0.f};
  for (int j = 0; j < 2; ++j) {
    int d = nodeBase + j * 4 + q;
    if (d < NN) {
      ushort4 u = ((const ushort4*)(t + (size_t)d * 64))[cl];
      __half2 hl = *(__half2*)&u.x, hh = *(__half2*)&u.z;
      float2 fl = __half22float2(hl), fh = __half22float2(hh);
      float4 acc = {fl.x, fl.y, fh.x, fh.y};  // self t'[d]
      int e0 = rowptr[d], cnt = icnt[d];
      int k = 0;
      for (; k + 3 < cnt; k += 4) {
        ushort4 qe = *(const ushort4*)&ep[e0 + k];
#pragma unroll
        for (int m = 0; m < 4; ++m) {
          unsigned sidx = (m == 0) ? qe.x : (m == 1) ? qe.y : (m == 2) ? qe.z : qe.w;
          ushort4 r = ((const ushort4*)(t + (size_t)sidx * 64))[cl];
          __half2 rl = *(__half2*)&r.x, rh = *(__half2*)&r.z;
          float2 a = __half22float2(rl), bb = __half22float2(rh);
          acc.x += a.x; acc.y += a.y; acc.z += bb.x; acc.w += bb.y;
        }
      }
      for (; k < cnt; ++k) {
        unsigned sidx = ep[e0 + k];
        ushort4 r = ((const ushort4*)(t + (size_t)sidx * 64))[cl];
        __half2 rl = *(__half2*)&r.x, rh = *(__half2*)&r.z;
        float2 a = __half22float2(rl), bb = __half22float2(rh);
        acc.x += a.x; acc.y += a.y; acc.z += bb.x; acc.w += bb.y;
      }
      float dv = dinv[d];
      acc.x *= dv; acc.y *= dv; acc.z *= dv; acc.w *= dv;
      __half2 o01 = __floats2half2_rn(acc.x, acc.y);
      __half2 o23 = __floats2half2_rn(acc.z, acc.w);
      uint2 ov;
      ov.x = *(unsigned*)&o01;
      ov.y = *(unsigned*)&o23;
      ((uint2*)(outp + (size_t)d * 64))[cl] = ov;
      s.x += acc.x; s.y += acc.y; s.z += acc.z; s.w += acc.w;
      sq.x = fmaf(acc.x, acc.x, sq.x); sq.y = fmaf(acc.y, acc.y, sq.y);
      sq.z = fmaf(acc.z, acc.z, sq.z); sq.w = fmaf(acc.w, acc.w, sq.w);
    }
  }
  __shared__ float ls[4][4][16][4], lq[4][4][16][4];
  *(float4*)&ls[w][q][cl][0] = s;
  *(float4*)&lq[w][q][cl][0] = sq;
  __syncthreads();
  if (threadIdx.x < 64) {
    int cc = threadIdx.x >> 2, comp = threadIdx.x & 3;
    float S = 0.f, Q = 0.f;
#pragma unroll
    for (int ww = 0; ww < 4; ++ww)
#pragma unroll
      for (int qq = 0; qq < 4; ++qq) {
        S += ls[ww][qq][cc][comp];
        Q += lq[ww][qq][cc][comp];
      }
    double* bank = sums8 + (size_t)(blockIdx.x & 7) * 128;
    atomicAdd(&bank[threadIdx.x], (double)S);
    atomicAdd(&bank[64 + threadIdx.x], (double)Q);
  }
}

// ---------------- tiled GEMM (fp16 in) with inlined BN-finalize + fused BN+ReLU ----------------
__global__ __launch_bounds__(256) void k_gemm64f(const __half* __restrict__ A,
                                                 const double* __restrict__ sums,
                                                 const float* __restrict__ gamma,
                                                 const float* __restrict__ beta,
                                                 const float* __restrict__ W,
                                                 const float* __restrict__ dinv,
                                                 __half* __restrict__ out) {
  gemm_tile<false>(blockIdx.x, A, sums, gamma, beta, W, dinv, out);
}

// ---------------- segmented mean-pool (inlined BN, fp16 in) + final FC ----------------
__global__ __launch_bounds__(256) void k_pool_final(const int* __restrict__ gstart,
                                                    const __half* __restrict__ h,
                                                    const double* __restrict__ sums,
                                                    const float* __restrict__ gamma,
                                                    const float* __restrict__ beta,
                                                    const float* __restrict__ fcW,
                                                    const float* __restrict__ fcb,
                                                    float* __restrict__ out) {
  __shared__ float sc[64], sh[64];
  __shared__ float pl[4][64];
  int tid = threadIdx.x;
  if (tid < 64) {
    double S = 0.0, Q = 0.0;
#pragma unroll
    for (int k = 0; k < 8; ++k) {
      S += sums[k * 128 + tid];
      Q += sums[k * 128 + 64 + tid];
    }
    double mu = S / (double)NN;
    double var = Q / (double)NN - mu * mu;
    float rstd = (float)(1.0 / sqrt(var + (double)BN_EPS));
    float scv = gamma[tid] * rstd;
    sc[tid] = scv;
    sh[tid] = beta[tid] - (float)mu * scv;
  }
  __syncthreads();
  int w = tid >> 6;
  int c = tid & 63;
  int g = blockIdx.x * 4 + w;
  float p = 0.f;
  if (g < GG) {
    int s = gstart[g], e = gstart[g + 1];
    float scv = sc[c], shv = sh[c], acc = 0.f;
    for (int i = s; i < e; ++i)
      acc += fmaxf(fmaf(__half2float(h[(size_t)i * 64 + c]), scv, shv), 0.f);
    p = acc / fmaxf((float)(e - s), 1.0f);
  }
  pl[w][c] = p;
  __syncthreads();
  if (tid < 4 * CC) {
    int gw = tid / CC, j = tid % CC;
    int gg = blockIdx.x * 4 + gw;
    if (gg < GG) {
      float acc = 0.f;
#pragma unroll
      for (int k = 0; k < 64; ++k) acc = fmaf(pl[gw][k], fcW[k * CC + j], acc);
      out[gg * CC + j] = acc + fcb[j];
    }
  }
}

extern "C" void kernel_launch(void* const* d_in, const int* in_sizes, int n_in,
                              void* d_out, int out_size, void* d_ws, size_t ws_size,
                              hipStream_t stream) {
  const float* x = (const float*)d_in[0];
  const int* eidx = (const int*)d_in[1];
  const int* batch = (const int*)d_in[2];
  const float* W[3] = {(const float*)d_in[3], (const float*)d_in[7], (const float*)d_in[11]};
  const float* gam[3] = {(const float*)d_in[5], (const float*)d_in[9], (const float*)d_in[13]};
  const float* bet[3] = {(const float*)d_in[6], (const float*)d_in[10], (const float*)d_in[14]};
  const float* fcW = (const float*)d_in[15];
  const float* fcb = (const float*)d_in[16];
  float* out = (float*)d_out;

  char* ws = (char*)d_ws;
  size_t off = 0;
  auto alloc = [&](size_t b) -> void* {
    void* p = ws + off;
    off = (off + b + 255) & ~(size_t)255;
    return p;
  };
  int* icnt = (int*)alloc((size_t)NN * 4);
  float* dinv = (float*)alloc((size_t)NN * 4);
  int* pre = (int*)alloc((size_t)NN * 4);
  int* bsum = (int*)alloc((size_t)NB_SCAN * 4);
  int* braw = (int*)alloc((size_t)NBKT * 4);
  int* gcur = (int*)alloc((size_t)NBKT * 4);
  int* rowptr = (int*)alloc((size_t)(NN + 1) * 4);
  int* gstart = (int*)alloc((size_t)(GG + 1) * 4);
  unsigned int* part = (unsigned int*)alloc((size_t)(EE + 4 * NN) * 4);
  unsigned short* ep = (unsigned short*)alloc((size_t)(EE + 4 * NN) * 2);
  __half* bufA = (__half*)alloc((size_t)NN * 64 * 2);
  __half* bufB = (__half*)alloc((size_t)NN * 64 * 2);
  double* sums24 = (double*)alloc((size_t)3 * 1024 * 8);

  const int* src = eidx;       // edge_index[0]
  const int* dst = eidx + EE;  // edge_index[1]

  // --- preprocessing ---
  hipMemsetAsync(icnt, 0, (size_t)NN * 4, stream);
  k_cb<<<NB_CNT + NB_BND, 256, 0, stream>>>(dst, icnt, batch, gstart);
  k_scan1<<<NB_SCAN, 256, 0, stream>>>(icnt, pre, bsum, dinv, braw);
  k_scan2<<<1, 64, 0, stream>>>(bsum, rowptr, sums24);
  k_scan3<<<(NN + 255) / 256, 256, 0, stream>>>(pre, bsum, rowptr, gcur);

  // --- edge partition + layer-0 GEMM (one dispatch); bucket-local CSR fill ---
  k_part_gemm0<<<NB_GEMM + NB_PART, 256, 0, stream>>>(src, dst, gcur, part, x, W[0],
                                                      dinv, bufB);
  k_fill2<<<NBKT, 512, 0, stream>>>(rowptr, braw, part, ep);

  // --- 3 GCN layers ---
  k_gather_stats<<<(NN + 31) / 32, 256, 0, stream>>>(rowptr, icnt, ep, dinv, bufB, bufA,
                                                     sums24 + 0 * 1024);
  for (int l = 1; l < 3; ++l) {
    k_gemm64f<<<NB_GEMM, 256, 0, stream>>>(bufA, sums24 + (l - 1) * 1024, gam[l - 1],
                                           bet[l - 1], W[l], dinv, bufB);
    k_gather_stats<<<(NN + 31) / 32, 256, 0, stream>>>(rowptr, icnt, ep, dinv, bufB, bufA,
                                                       sums24 + l * 1024);
  }

  // --- pool (inlined BN of layer 2) + FC ---
  k_pool_final<<<(GG + 3) / 4, 256, 0, stream>>>(gstart, bufA, sums24 + 2 * 1024, gam[2],
                                                 bet[2], fcW, fcb, out);
}

// Round 12
// 324.316 us; speedup vs baseline: 3.2108x; 1.0240x over previous
//
#include <hip/hip_runtime.h>
#include <hip/hip_fp16.h>
#include <math.h>

#define NN 50000
#define EE 800000
#define GG 500
#define CC 6
#define BN_EPS 1e-5f
#define NB_SCAN 49     // ceil(50000/1024)
#define NB_CNT 3125    // ceil(800000/256)
#define NB_BND 196     // ceil(50000/256)
#define NB_GEMM 1563   // ceil(50000/32)
#define NBKT 98        // buckets of 512 nodes (dst>>9)
#define NB_PART 100    // partition blocks, 8000 edges each

// ---------------- count (edges) + graph bounds (nodes), one dispatch ----------------
__global__ __launch_bounds__(256) void k_cb(const int* __restrict__ dst,
                                            int* __restrict__ icnt,
                                            const int* __restrict__ batch,
                                            int* __restrict__ gstart) {
  int b = blockIdx.x;
  if (b < NB_CNT) {
    int e = b * 256 + threadIdx.x;
    if (e < EE) atomicAdd(&icnt[dst[e]], 1);
  } else {
    int i = (b - NB_CNT) * 256 + threadIdx.x;
    if (i >= NN) return;
    int bb = batch[i];
    if (i == 0) {
      for (int g = 0; g <= bb; ++g) gstart[g] = 0;
    } else {
      int pb = batch[i - 1];
      for (int g = pb + 1; g <= bb; ++g) gstart[g] = i;
    }
    if (i == NN - 1) {
      for (int g = bb + 1; g <= GG; ++g) gstart[g] = NN;
    }
  }
}

// ---------------- scan phase 1 over CEIL4(deg); also dinv + raw per-512-bucket sums ----------------
__global__ __launch_bounds__(256) void k_scan1(const int* __restrict__ icnt,
                                               int* __restrict__ pre,
                                               int* __restrict__ bsum,
                                               float* __restrict__ dinv,
                                               int* __restrict__ braw) {
  __shared__ int ls[256];
  __shared__ int lr[256];
  int base = blockIdx.x * 1024;
  int t = threadIdx.x;
  int v[4], s = 0, sraw = 0;
#pragma unroll
  for (int j = 0; j < 4; ++j) {
    int idx = base + t * 4 + j;
    int raw = (idx < NN) ? icnt[idx] : 0;
    if (idx < NN) dinv[idx] = rsqrtf((float)(raw + 1));  // +1 self-loop
    sraw += raw;
    v[j] = (raw + 3) & ~3;  // padded length (row starts 4-aligned)
    s += v[j];
  }
  ls[t] = s;
  lr[t] = sraw;
  __syncthreads();
  for (int ofs = 1; ofs < 256; ofs <<= 1) {
    int y = (t >= ofs) ? ls[t - ofs] : 0;
    __syncthreads();
    ls[t] += y;
    __syncthreads();
  }
  int excl = ls[t] - s;
#pragma unroll
  for (int j = 0; j < 4; ++j) {
    int idx = base + t * 4 + j;
    if (idx < NN) pre[idx] = excl;
    excl += v[j];
  }
  if (t == 255) bsum[blockIdx.x] = ls[255];
  // raw sums per 512-node half (threads 0..127 / 128..255)
  for (int ofs = 64; ofs >= 1; ofs >>= 1) {
    __syncthreads();
    if ((t & 127) < ofs) lr[t] += lr[t + ofs];
  }
  __syncthreads();
  if (t == 0) braw[2 * blockIdx.x] = lr[0];
  if (t == 128 && 2 * blockIdx.x + 1 < NBKT) braw[2 * blockIdx.x + 1] = lr[128];
}

// phase 2: serial scan of 49 block sums; zero 3 per-layer BN stat regions.
__global__ void k_scan2(int* __restrict__ bsum, int* __restrict__ rowptr,
                        double* __restrict__ sums24) {
  int t = threadIdx.x;  // 64 threads
  for (int k = t; k < 3 * 1024; k += 64) sums24[k] = 0.0;
  if (t == 0) {
    int run = 0;
    for (int b = 0; b < NB_SCAN; ++b) {
      int x = bsum[b];
      bsum[b] = run;
      run += x;
    }
    rowptr[NN] = run;
  }
}

// phase 3: rowptr; also init bucket write cursors gcur[b] = rowptr[b*512]
__global__ __launch_bounds__(256) void k_scan3(const int* __restrict__ pre,
                                               const int* __restrict__ bsum,
                                               int* __restrict__ rowptr,
                                               int* __restrict__ gcur) {
  int i = blockIdx.x * 256 + threadIdx.x;
  if (i < NN) {
    int v = pre[i] + bsum[i >> 10];
    rowptr[i] = v;
    if ((i & 511) == 0) gcur[i >> 9] = v;
  }
}

// ---------------- shared GEMM tile body ----------------
// out[n,:] = dinv[n] * f(A[n]) @ W  (half2 lanes); LAYER0: A=f32, no BN. else A=f16 + BN+ReLU.
template <bool LAYER0>
__device__ __forceinline__ void gemm_tile(int blockId,
                                          const void* __restrict__ Aptr,
                                          const double* __restrict__ sums,
                                          const float* __restrict__ gamma,
                                          const float* __restrict__ beta,
                                          const float* __restrict__ W,
                                          const float* __restrict__ dinv,
                                          __half* __restrict__ out) {
  __shared__ float Ws[64][64];
  __shared__ float As[32][64];
  __shared__ float sc[64], sh[64];
  int tid = threadIdx.x;
  if (!LAYER0 && tid < 64) {
    double S = 0.0, Q = 0.0;
#pragma unroll
    for (int k = 0; k < 8; ++k) {
      S += sums[k * 128 + tid];
      Q += sums[k * 128 + 64 + tid];
    }
    double mu = S / (double)NN;
    double var = Q / (double)NN - mu * mu;
    float rstd = (float)(1.0 / sqrt(var + (double)BN_EPS));
    float scv = gamma[tid] * rstd;
    sc[tid] = scv;
    sh[tid] = beta[tid] - (float)mu * scv;
  }
  const float4* W4 = (const float4*)W;
  float4* Ws4 = (float4*)&Ws[0][0];
#pragma unroll
  for (int i = 0; i < 4; ++i) Ws4[tid + 256 * i] = W4[tid + 256 * i];
  if (!LAYER0) __syncthreads();  // sc/sh ready
  int base = blockId * 32;
  int remain = NN - base;
  float4* As4 = (float4*)&As[0][0];
  if (LAYER0) {
    const float4* A4 = (const float4*)((const float*)Aptr + (size_t)base * 64);
#pragma unroll
    for (int i = 0; i < 2; ++i) {
      int idx = tid + 256 * i;
      if ((idx >> 4) < remain) As4[idx] = A4[idx];
    }
  } else {
    // fp16 input: one uint4 = 8 halves per thread covers the 32x64 tile
    const uint4* A8 = (const uint4*)((const __half*)Aptr + (size_t)base * 64);
    int r = tid >> 3;
    if (r < remain) {
      uint4 u = A8[tid];
      int c0 = (tid & 7) * 8;
      float f[8];
      __half2 h;
      h = *(__half2*)&u.x; f[0] = __low2float(h); f[1] = __high2float(h);
      h = *(__half2*)&u.y; f[2] = __low2float(h); f[3] = __high2float(h);
      h = *(__half2*)&u.z; f[4] = __low2float(h); f[5] = __high2float(h);
      h = *(__half2*)&u.w; f[6] = __low2float(h); f[7] = __high2float(h);
#pragma unroll
      for (int j = 0; j < 8; ++j)
        f[j] = fmaxf(fmaf(f[j], sc[c0 + j], sh[c0 + j]), 0.f);
      float4 lo = {f[0], f[1], f[2], f[3]}, hi = {f[4], f[5], f[6], f[7]};
      As4[(r << 4) + (tid & 7) * 2 + 0] = lo;
      As4[(r << 4) + (tid & 7) * 2 + 1] = hi;
    }
  }
  __syncthreads();
  int c2 = tid & 31;
  int r0 = (tid >> 5) * 4;
  float a00 = 0.f, a01 = 0.f, a10 = 0.f, a11 = 0.f;
  float a20 = 0.f, a21 = 0.f, a30 = 0.f, a31 = 0.f;
#pragma unroll
  for (int k = 0; k < 64; k += 4) {
    float4 v0 = *(const float4*)&As[r0 + 0][k];
    float4 v1 = *(const float4*)&As[r0 + 1][k];
    float4 v2 = *(const float4*)&As[r0 + 2][k];
    float4 v3 = *(const float4*)&As[r0 + 3][k];
#pragma unroll
    for (int kk = 0; kk < 4; ++kk) {
      float2 wv = *(const float2*)&Ws[k + kk][c2 * 2];
      float e0 = (kk == 0) ? v0.x : (kk == 1) ? v0.y : (kk == 2) ? v0.z : v0.w;
      float e1 = (kk == 0) ? v1.x : (kk == 1) ? v1.y : (kk == 2) ? v1.z : v1.w;
      float e2 = (kk == 0) ? v2.x : (kk == 1) ? v2.y : (kk == 2) ? v2.z : v2.w;
      float e3 = (kk == 0) ? v3.x : (kk == 1) ? v3.y : (kk == 2) ? v3.z : v3.w;
      a00 = fmaf(e0, wv.x, a00); a01 = fmaf(e0, wv.y, a01);
      a10 = fmaf(e1, wv.x, a10); a11 = fmaf(e1, wv.y, a11);
      a20 = fmaf(e2, wv.x, a20); a21 = fmaf(e2, wv.y, a21);
      a30 = fmaf(e3, wv.x, a30); a31 = fmaf(e3, wv.y, a31);
    }
  }
  int n = base + r0;
  if (n + 0 < NN) { float dv = dinv[n + 0]; ((__half2*)(out + (size_t)(n + 0) * 64))[c2] = __floats2half2_rn(a00 * dv, a01 * dv); }
  if (n + 1 < NN) { float dv = dinv[n + 1]; ((__half2*)(out + (size_t)(n + 1) * 64))[c2] = __floats2half2_rn(a10 * dv, a11 * dv); }
  if (n + 2 < NN) { float dv = dinv[n + 2]; ((__half2*)(out + (size_t)(n + 2) * 64))[c2] = __floats2half2_rn(a20 * dv, a21 * dv); }
  if (n + 3 < NN) { float dv = dinv[n + 3]; ((__half2*)(out + (size_t)(n + 3) * 64))[c2] = __floats2half2_rn(a30 * dv, a31 * dv); }
}

// ---------------- edge partition by dst>>9 (LDS-binned) + layer-0 GEMM, one dispatch ----------------
__global__ __launch_bounds__(256) void k_part_gemm0(const int* __restrict__ src,
                                                    const int* __restrict__ dst,
                                                    int* __restrict__ gcur,
                                                    unsigned int* __restrict__ part,
                                                    const float* __restrict__ x,
                                                    const float* __restrict__ W0,
                                                    const float* __restrict__ dinv,
                                                    __half* __restrict__ outB) {
  if (blockIdx.x >= NB_GEMM) {
    __shared__ int lcnt[NBKT], lofs[NBKT], lcur[NBKT];
    int tid = threadIdx.x;
    int cb = (blockIdx.x - NB_GEMM) * 8000;
    if (tid < NBKT) lcnt[tid] = 0;
    __syncthreads();
    for (int it = 0; it < 32; ++it) {
      int o = it * 256 + tid;
      if (o < 8000) atomicAdd(&lcnt[dst[cb + o] >> 9], 1);
    }
    __syncthreads();
    if (tid < NBKT) {
      lofs[tid] = atomicAdd(&gcur[tid], lcnt[tid]);
      lcur[tid] = 0;
    }
    __syncthreads();
    for (int it = 0; it < 32; ++it) {
      int o = it * 256 + tid;
      if (o < 8000) {
        int d = dst[cb + o];
        int bkt = d >> 9;
        int pos = lofs[bkt] + atomicAdd(&lcur[bkt], 1);
        part[pos] = ((unsigned)(d & 511) << 16) | (unsigned)src[cb + o];
      }
    }
    return;
  }
  gemm_tile<true>(blockIdx.x, x, nullptr, nullptr, nullptr, W0, dinv, outB);
}

// ---------------- CSR fill from partition: one block per bucket (XCD-local writes) ----------------
__global__ __launch_bounds__(512) void k_fill2(const int* __restrict__ rowptr,
                                               const int* __restrict__ braw,
                                               const unsigned int* __restrict__ part,
                                               unsigned short* __restrict__ ep) {
  __shared__ int lrp[512];
  __shared__ int lfill[512];
  int b = blockIdx.x;
  int tid = threadIdx.x;
  int nbase = b << 9;
  lrp[tid] = (nbase + tid < NN) ? rowptr[nbase + tid] : 0;
  lfill[tid] = 0;
  __syncthreads();
  int start = lrp[0];
  int cnt = braw[b];
  for (int i = tid; i < cnt; i += 512) {
    unsigned p = part[start + i];
    int dloc = p >> 16;
    int pos = lrp[dloc] + atomicAdd(&lfill[dloc], 1);
    ep[pos] = (unsigned short)(p & 0xFFFF);
  }
}

// ---------------- gather-aggregate: 1 node per 8-lane group, uint4 (8ch) per lane ----------------
// 256 thr = 4 waves x 8 groups = 32 nodes/block. 8 concurrent nodes/wave x 4-edge unroll
// = 32 row-loads in flight/wave. Lane li covers channels li*8..li*8+7.
__global__ __launch_bounds__(256) void k_gather_stats(const int* __restrict__ rowptr,
                                                      const int* __restrict__ icnt,
                                                      const unsigned short* __restrict__ ep,
                                                      const float* __restrict__ dinv,
                                                      const __half* __restrict__ t,
                                                      __half* __restrict__ outp,
                                                      double* __restrict__ sums8) {
  int w = threadIdx.x >> 6;
  int lane = threadIdx.x & 63;
  int g = lane >> 3;   // group in wave
  int li = lane & 7;   // lane in group -> channel block
  int d = blockIdx.x * 32 + w * 8 + g;
  float acc[8] = {0.f, 0.f, 0.f, 0.f, 0.f, 0.f, 0.f, 0.f};
  if (d < NN) {
    uint4 u = ((const uint4*)(t + (size_t)d * 64))[li];  // self t'[d]
    {
      __half2* hp = (__half2*)&u;
#pragma unroll
      for (int j = 0; j < 4; ++j) {
        float2 f = __half22float2(hp[j]);
        acc[2 * j] += f.x;
        acc[2 * j + 1] += f.y;
      }
    }
    int e0 = rowptr[d], cnt = icnt[d];
    int k = 0;
    for (; k + 3 < cnt; k += 4) {
      ushort4 qe = *(const ushort4*)&ep[e0 + k];
      uint4 r0 = ((const uint4*)(t + (size_t)qe.x * 64))[li];
      uint4 r1 = ((const uint4*)(t + (size_t)qe.y * 64))[li];
      uint4 r2 = ((const uint4*)(t + (size_t)qe.z * 64))[li];
      uint4 r3 = ((const uint4*)(t + (size_t)qe.w * 64))[li];
      __half2* h0 = (__half2*)&r0;
      __half2* h1 = (__half2*)&r1;
      __half2* h2 = (__half2*)&r2;
      __half2* h3 = (__half2*)&r3;
#pragma unroll
      for (int j = 0; j < 4; ++j) {
        float2 f0 = __half22float2(h0[j]);
        float2 f1 = __half22float2(h1[j]);
        float2 f2 = __half22float2(h2[j]);
        float2 f3 = __half22float2(h3[j]);
        acc[2 * j] += (f0.x + f1.x) + (f2.x + f3.x);
        acc[2 * j + 1] += (f0.y + f1.y) + (f2.y + f3.y);
      }
    }
    for (; k < cnt; ++k) {
      uint4 r = ((const uint4*)(t + (size_t)ep[e0 + k] * 64))[li];
      __half2* hp = (__half2*)&r;
#pragma unroll
      for (int j = 0; j < 4; ++j) {
        float2 f = __half22float2(hp[j]);
        acc[2 * j] += f.x;
        acc[2 * j + 1] += f.y;
      }
    }
    float dv = dinv[d];
#pragma unroll
    for (int j = 0; j < 8; ++j) acc[j] *= dv;
    __half2 o0 = __floats2half2_rn(acc[0], acc[1]);
    __half2 o1 = __floats2half2_rn(acc[2], acc[3]);
    __half2 o2 = __floats2half2_rn(acc[4], acc[5]);
    __half2 o3 = __floats2half2_rn(acc[6], acc[7]);
    uint4 ov;
    ov.x = *(unsigned*)&o0;
    ov.y = *(unsigned*)&o1;
    ov.z = *(unsigned*)&o2;
    ov.w = *(unsigned*)&o3;
    ((uint4*)(outp + (size_t)d * 64))[li] = ov;
  }
  // stats: per-lane acc is the node's contribution for its 8 channels
  __shared__ float ls[4][8][8][8], lq[4][8][8][8];
#pragma unroll
  for (int j = 0; j < 8; ++j) {
    ls[w][g][li][j] = acc[j];
    lq[w][g][li][j] = acc[j] * acc[j];
  }
  __syncthreads();
  if (threadIdx.x < 64) {
    int c = threadIdx.x;
    int lsel = c >> 3, comp = c & 7;
    float S = 0.f, Q = 0.f;
#pragma unroll
    for (int ww = 0; ww < 4; ++ww)
#pragma unroll
      for (int gg = 0; gg < 8; ++gg) {
        S += ls[ww][gg][lsel][comp];
        Q += lq[ww][gg][lsel][comp];
      }
    double* bank = sums8 + (size_t)(blockIdx.x & 7) * 128;
    atomicAdd(&bank[c], (double)S);
    atomicAdd(&bank[64 + c], (double)Q);
  }
}

// ---------------- tiled GEMM (fp16 in) with inlined BN-finalize + fused BN+ReLU ----------------
__global__ __launch_bounds__(256) void k_gemm64f(const __half* __restrict__ A,
                                                 const double* __restrict__ sums,
                                                 const float* __restrict__ gamma,
                                                 const float* __restrict__ beta,
                                                 const float* __restrict__ W,
                                                 const float* __restrict__ dinv,
                                                 __half* __restrict__ out) {
  gemm_tile<false>(blockIdx.x, A, sums, gamma, beta, W, dinv, out);
}

// ---------------- segmented mean-pool (inlined BN, fp16 in) + final FC ----------------
__global__ __launch_bounds__(256) void k_pool_final(const int* __restrict__ gstart,
                                                    const __half* __restrict__ h,
                                                    const double* __restrict__ sums,
                                                    const float* __restrict__ gamma,
                                                    const float* __restrict__ beta,
                                                    const float* __restrict__ fcW,
                                                    const float* __restrict__ fcb,
                                                    float* __restrict__ out) {
  __shared__ float sc[64], sh[64];
  __shared__ float pl[4][64];
  int tid = threadIdx.x;
  if (tid < 64) {
    double S = 0.0, Q = 0.0;
#pragma unroll
    for (int k = 0; k < 8; ++k) {
      S += sums[k * 128 + tid];
      Q += sums[k * 128 + 64 + tid];
    }
    double mu = S / (double)NN;
    double var = Q / (double)NN - mu * mu;
    float rstd = (float)(1.0 / sqrt(var + (double)BN_EPS));
    float scv = gamma[tid] * rstd;
    sc[tid] = scv;
    sh[tid] = beta[tid] - (float)mu * scv;
  }
  __syncthreads();
  int w = tid >> 6;
  int c = tid & 63;
  int g = blockIdx.x * 4 + w;
  float p = 0.f;
  if (g < GG) {
    int s = gstart[g], e = gstart[g + 1];
    float scv = sc[c], shv = sh[c], acc = 0.f;
    for (int i = s; i < e; ++i)
      acc += fmaxf(fmaf(__half2float(h[(size_t)i * 64 + c]), scv, shv), 0.f);
    p = acc / fmaxf((float)(e - s), 1.0f);
  }
  pl[w][c] = p;
  __syncthreads();
  if (tid < 4 * CC) {
    int gw = tid / CC, j = tid % CC;
    int gg = blockIdx.x * 4 + gw;
    if (gg < GG) {
      float acc = 0.f;
#pragma unroll
      for (int k = 0; k < 64; ++k) acc = fmaf(pl[gw][k], fcW[k * CC + j], acc);
      out[gg * CC + j] = acc + fcb[j];
    }
  }
}

extern "C" void kernel_launch(void* const* d_in, const int* in_sizes, int n_in,
                              void* d_out, int out_size, void* d_ws, size_t ws_size,
                              hipStream_t stream) {
  const float* x = (const float*)d_in[0];
  const int* eidx = (const int*)d_in[1];
  const int* batch = (const int*)d_in[2];
  const float* W[3] = {(const float*)d_in[3], (const float*)d_in[7], (const float*)d_in[11]};
  const float* gam[3] = {(const float*)d_in[5], (const float*)d_in[9], (const float*)d_in[13]};
  const float* bet[3] = {(const float*)d_in[6], (const float*)d_in[10], (const float*)d_in[14]};
  const float* fcW = (const float*)d_in[15];
  const float* fcb = (const float*)d_in[16];
  float* out = (float*)d_out;

  char* ws = (char*)d_ws;
  size_t off = 0;
  auto alloc = [&](size_t b) -> void* {
    void* p = ws + off;
    off = (off + b + 255) & ~(size_t)255;
    return p;
  };
  int* icnt = (int*)alloc((size_t)NN * 4);
  float* dinv = (float*)alloc((size_t)NN * 4);
  int* pre = (int*)alloc((size_t)NN * 4);
  int* bsum = (int*)alloc((size_t)NB_SCAN * 4);
  int* braw = (int*)alloc((size_t)NBKT * 4);
  int* gcur = (int*)alloc((size_t)NBKT * 4);
  int* rowptr = (int*)alloc((size_t)(NN + 1) * 4);
  int* gstart = (int*)alloc((size_t)(GG + 1) * 4);
  unsigned int* part = (unsigned int*)alloc((size_t)(EE + 4 * NN) * 4);
  unsigned short* ep = (unsigned short*)alloc((size_t)(EE + 4 * NN) * 2);
  __half* bufA = (__half*)alloc((size_t)NN * 64 * 2);
  __half* bufB = (__half*)alloc((size_t)NN * 64 * 2);
  double* sums24 = (double*)alloc((size_t)3 * 1024 * 8);

  const int* src = eidx;       // edge_index[0]
  const int* dst = eidx + EE;  // edge_index[1]

  // --- preprocessing ---
  hipMemsetAsync(icnt, 0, (size_t)NN * 4, stream);
  k_cb<<<NB_CNT + NB_BND, 256, 0, stream>>>(dst, icnt, batch, gstart);
  k_scan1<<<NB_SCAN, 256, 0, stream>>>(icnt, pre, bsum, dinv, braw);
  k_scan2<<<1, 64, 0, stream>>>(bsum, rowptr, sums24);
  k_scan3<<<(NN + 255) / 256, 256, 0, stream>>>(pre, bsum, rowptr, gcur);

  // --- edge partition + layer-0 GEMM (one dispatch); bucket-local CSR fill ---
  k_part_gemm0<<<NB_GEMM + NB_PART, 256, 0, stream>>>(src, dst, gcur, part, x, W[0],
                                                      dinv, bufB);
  k_fill2<<<NBKT, 512, 0, stream>>>(rowptr, braw, part, ep);

  // --- 3 GCN layers ---
  k_gather_stats<<<(NN + 31) / 32, 256, 0, stream>>>(rowptr, icnt, ep, dinv, bufB, bufA,
                                                     sums24 + 0 * 1024);
  for (int l = 1; l < 3; ++l) {
    k_gemm64f<<<NB_GEMM, 256, 0, stream>>>(bufA, sums24 + (l - 1) * 1024, gam[l - 1],
                                           bet[l - 1], W[l], dinv, bufB);
    k_gather_stats<<<(NN + 31) / 32, 256, 0, stream>>>(rowptr, icnt, ep, dinv, bufB, bufA,
                                                       sums24 + l * 1024);
  }

  // --- pool (inlined BN of layer 2) + FC ---
  k_pool_final<<<(GG + 3) / 4, 256, 0, stream>>>(gstart, bufA, sums24 + 2 * 1024, gam[2],
                                                 bet[2], fcW, fcb, out);
}

// Round 15
// 282.916 us; speedup vs baseline: 3.6806x; 1.1463x over previous
//
#include <hip/hip_runtime.h>
#include <hip/hip_fp16.h>
#include <math.h>

#define NN 50000
#define EE 800000
#define GG 500
#define CC 6
#define BN_EPS 1e-5f
#define NB_SCAN 49     // ceil(50000/1024)
#define NB_CNT 3125    // ceil(800000/256)
#define NB_BND 196     // ceil(50000/256)
#define NB_GEMM 782    // ceil(50000/64)  -- 64-row MFMA tiles
#define NBKT 98        // buckets of 512 nodes (dst>>9)
#define NB_PART 100    // partition blocks, 8000 edges each

typedef _Float16 f16x8 __attribute__((ext_vector_type(8)));
typedef float f32x4 __attribute__((ext_vector_type(4)));

// ---------------- count (edges) + graph bounds (nodes), one dispatch ----------------
__global__ __launch_bounds__(256) void k_cb(const int* __restrict__ dst,
                                            int* __restrict__ icnt,
                                            const int* __restrict__ batch,
                                            int* __restrict__ gstart) {
  int b = blockIdx.x;
  if (b < NB_CNT) {
    int e = b * 256 + threadIdx.x;
    if (e < EE) atomicAdd(&icnt[dst[e]], 1);
  } else {
    int i = (b - NB_CNT) * 256 + threadIdx.x;
    if (i >= NN) return;
    int bb = batch[i];
    if (i == 0) {
      for (int g = 0; g <= bb; ++g) gstart[g] = 0;
    } else {
      int pb = batch[i - 1];
      for (int g = pb + 1; g <= bb; ++g) gstart[g] = i;
    }
    if (i == NN - 1) {
      for (int g = bb + 1; g <= GG; ++g) gstart[g] = NN;
    }
  }
}

// ---------------- scan phase 1 over CEIL4(deg); also dinv + raw per-512-bucket sums ----------------
__global__ __launch_bounds__(256) void k_scan1(const int* __restrict__ icnt,
                                               int* __restrict__ pre,
                                               int* __restrict__ bsum,
                                               float* __restrict__ dinv,
                                               int* __restrict__ braw) {
  __shared__ int ls[256];
  __shared__ int lr[256];
  int base = blockIdx.x * 1024;
  int t = threadIdx.x;
  int v[4], s = 0, sraw = 0;
#pragma unroll
  for (int j = 0; j < 4; ++j) {
    int idx = base + t * 4 + j;
    int raw = (idx < NN) ? icnt[idx] : 0;
    if (idx < NN) dinv[idx] = rsqrtf((float)(raw + 1));  // +1 self-loop
    sraw += raw;
    v[j] = (raw + 3) & ~3;  // padded length (row starts 4-aligned)
    s += v[j];
  }
  ls[t] = s;
  lr[t] = sraw;
  __syncthreads();
  for (int ofs = 1; ofs < 256; ofs <<= 1) {
    int y = (t >= ofs) ? ls[t - ofs] : 0;
    __syncthreads();
    ls[t] += y;
    __syncthreads();
  }
  int excl = ls[t] - s;
#pragma unroll
  for (int j = 0; j < 4; ++j) {
    int idx = base + t * 4 + j;
    if (idx < NN) pre[idx] = excl;
    excl += v[j];
  }
  if (t == 255) bsum[blockIdx.x] = ls[255];
  // raw sums per 512-node half (threads 0..127 / 128..255)
  for (int ofs = 64; ofs >= 1; ofs >>= 1) {
    __syncthreads();
    if ((t & 127) < ofs) lr[t] += lr[t + ofs];
  }
  __syncthreads();
  if (t == 0) braw[2 * blockIdx.x] = lr[0];
  if (t == 128 && 2 * blockIdx.x + 1 < NBKT) braw[2 * blockIdx.x + 1] = lr[128];
}

// phase 2: serial scan of 49 block sums; zero 3 per-layer BN stat regions.
__global__ void k_scan2(int* __restrict__ bsum, int* __restrict__ rowptr,
                        double* __restrict__ sums24) {
  int t = threadIdx.x;  // 64 threads
  for (int k = t; k < 3 * 1024; k += 64) sums24[k] = 0.0;
  if (t == 0) {
    int run = 0;
    for (int b = 0; b < NB_SCAN; ++b) {
      int x = bsum[b];
      bsum[b] = run;
      run += x;
    }
    rowptr[NN] = run;
  }
}

// phase 3: rowptr; also init bucket write cursors gcur[b] = rowptr[b*512]
__global__ __launch_bounds__(256) void k_scan3(const int* __restrict__ pre,
                                               const int* __restrict__ bsum,
                                               int* __restrict__ rowptr,
                                               int* __restrict__ gcur) {
  int i = blockIdx.x * 256 + threadIdx.x;
  if (i < NN) {
    int v = pre[i] + bsum[i >> 10];
    rowptr[i] = v;
    if ((i & 511) == 0) gcur[i >> 9] = v;
  }
}

// ---------------- MFMA GEMM tile body (64 rows/block, 4 waves, fp16 inputs) ----------------
// out[n,:] = dinv[n] * f(A[n]) @ W  (fp16); LAYER0: A=f32 raw. else A=f16 + BN+ReLU.
// LDS XOR-swizzle (byte ^= (row&7)<<4) keeps stride-128B ds_read_b128 conflict-free.
template <bool LAYER0>
__device__ __forceinline__ void gemm_tile(int blockId,
                                          const void* __restrict__ Aptr,
                                          const double* __restrict__ sums,
                                          const float* __restrict__ gamma,
                                          const float* __restrict__ beta,
                                          const float* __restrict__ W,
                                          const float* __restrict__ dinv,
                                          __half* __restrict__ out) {
  __shared__ __align__(16) unsigned char AhB[64 * 128];  // A tile fp16 (swizzled)
  __shared__ __align__(16) unsigned char WtB[64 * 128];  // W^T fp16 (swizzled)
  __shared__ float sc[64], sh[64];
  int tid = threadIdx.x;
  if (!LAYER0 && tid < 64) {
    double S = 0.0, Q = 0.0;
#pragma unroll
    for (int k = 0; k < 8; ++k) {
      S += sums[k * 128 + tid];
      Q += sums[k * 128 + 64 + tid];
    }
    double mu = S / (double)NN;
    double var = Q / (double)NN - mu * mu;
    float rstd = (float)(1.0 / sqrt(var + (double)BN_EPS));
    float scv = gamma[tid] * rstd;
    sc[tid] = scv;
    sh[tid] = beta[tid] - (float)mu * scv;
  }
  // stage W^T as fp16: Wt[c][k] = W[k][c]
#pragma unroll
  for (int i = 0; i < 16; ++i) {
    int idx = tid + 256 * i;
    int k = idx >> 6, c = idx & 63;
    *(__half*)&WtB[c * 128 + ((k * 2) ^ ((c & 7) << 4))] = __float2half(W[idx]);
  }
  if (!LAYER0) __syncthreads();  // sc/sh ready before A staging
  int base = blockId * 64;
  if (LAYER0) {
    const float4* A4 = (const float4*)((const float*)Aptr + (size_t)base * 64);
#pragma unroll
    for (int i = 0; i < 4; ++i) {
      int idx = tid + 256 * i;
      int row = idx >> 4, q = idx & 15;
      float4 v = (base + row < NN) ? A4[idx] : float4{0.f, 0.f, 0.f, 0.f};
      __half2 p0 = __floats2half2_rn(v.x, v.y);
      __half2 p1 = __floats2half2_rn(v.z, v.w);
      uint2 u;
      u.x = *(unsigned*)&p0;
      u.y = *(unsigned*)&p1;
      *(uint2*)&AhB[row * 128 + ((q * 8) ^ ((row & 7) << 4))] = u;
    }
  } else {
    const uint4* A8 = (const uint4*)((const __half*)Aptr + (size_t)base * 64);
#pragma unroll
    for (int i = 0; i < 2; ++i) {
      int idx = tid + 256 * i;
      int row = idx >> 3, chunk = idx & 7;
      uint4 u = (base + row < NN) ? A8[idx] : uint4{0u, 0u, 0u, 0u};
      __half2* hp = (__half2*)&u;
      int c0 = chunk * 8;
      float f[8];
#pragma unroll
      for (int j = 0; j < 4; ++j) {
        float2 fv = __half22float2(hp[j]);
        f[2 * j] = fv.x;
        f[2 * j + 1] = fv.y;
      }
#pragma unroll
      for (int j = 0; j < 8; ++j)
        f[j] = fmaxf(fmaf(f[j], sc[c0 + j], sh[c0 + j]), 0.f);
      __half2 q0 = __floats2half2_rn(f[0], f[1]);
      __half2 q1 = __floats2half2_rn(f[2], f[3]);
      __half2 q2 = __floats2half2_rn(f[4], f[5]);
      __half2 q3 = __floats2half2_rn(f[6], f[7]);
      uint4 o;
      o.x = *(unsigned*)&q0;
      o.y = *(unsigned*)&q1;
      o.z = *(unsigned*)&q2;
      o.w = *(unsigned*)&q3;
      *(uint4*)&AhB[row * 128 + ((chunk * 16) ^ ((row & 7) << 4))] = o;
    }
  }
  __syncthreads();
  int lane = tid & 63;
  int w = tid >> 6;
  int r0 = w * 16;
  int lrow = lane & 15;
  int kg = lane >> 4;
  int s = (lrow & 7) << 4;
  // A fragments: rows r0+lrow, k-chunks kg*8 within each K=32 tile
  f16x8 a0 = *(f16x8*)&AhB[(r0 + lrow) * 128 + ((kg * 16) ^ s)];
  f16x8 a1 = *(f16x8*)&AhB[(r0 + lrow) * 128 + ((64 + kg * 16) ^ s)];
  f32x4 acc[4];
#pragma unroll
  for (int ct = 0; ct < 4; ++ct) {
    acc[ct] = (f32x4){0.f, 0.f, 0.f, 0.f};
    f16x8 b0 = *(f16x8*)&WtB[(ct * 16 + lrow) * 128 + ((kg * 16) ^ s)];
    f16x8 b1 = *(f16x8*)&WtB[(ct * 16 + lrow) * 128 + ((64 + kg * 16) ^ s)];
    acc[ct] = __builtin_amdgcn_mfma_f32_16x16x32_f16(a0, b0, acc[ct], 0, 0, 0);
    acc[ct] = __builtin_amdgcn_mfma_f32_16x16x32_f16(a1, b1, acc[ct], 0, 0, 0);
  }
  __syncthreads();  // A-frag reads done; reuse AhB as output staging (linear)
#pragma unroll
  for (int reg = 0; reg < 4; ++reg) {
    int row = r0 + kg * 4 + reg;
    float dv = dinv[base + row < NN ? base + row : NN - 1];
#pragma unroll
    for (int ct = 0; ct < 4; ++ct)
      *(__half*)&AhB[row * 128 + (ct * 16 + lrow) * 2] =
          __float2half(acc[ct][reg] * dv);
  }
  __syncthreads();
#pragma unroll
  for (int i = 0; i < 2; ++i) {
    int idx = tid + 256 * i;
    int row = idx >> 3, chunk = idx & 7;
    int n = base + row;
    if (n < NN)
      ((uint4*)(out + (size_t)n * 64))[chunk] = *(uint4*)&AhB[row * 128 + chunk * 16];
  }
}

// ---------------- edge partition by dst>>9 (LDS-binned) + layer-0 GEMM, one dispatch ----------------
__global__ __launch_bounds__(256) void k_part_gemm0(const int* __restrict__ src,
                                                    const int* __restrict__ dst,
                                                    int* __restrict__ gcur,
                                                    unsigned int* __restrict__ part,
                                                    const float* __restrict__ x,
                                                    const float* __restrict__ W0,
                                                    const float* __restrict__ dinv,
                                                    __half* __restrict__ outB) {
  if (blockIdx.x >= NB_GEMM) {
    __shared__ int lcnt[NBKT], lofs[NBKT], lcur[NBKT];
    int tid = threadIdx.x;
    int cb = (blockIdx.x - NB_GEMM) * 8000;
    if (tid < NBKT) lcnt[tid] = 0;
    __syncthreads();
    for (int it = 0; it < 32; ++it) {
      int o = it * 256 + tid;
      if (o < 8000) atomicAdd(&lcnt[dst[cb + o] >> 9], 1);
    }
    __syncthreads();
    if (tid < NBKT) {
      lofs[tid] = atomicAdd(&gcur[tid], lcnt[tid]);
      lcur[tid] = 0;
    }
    __syncthreads();
    for (int it = 0; it < 32; ++it) {
      int o = it * 256 + tid;
      if (o < 8000) {
        int d = dst[cb + o];
        int bkt = d >> 9;
        int pos = lofs[bkt] + atomicAdd(&lcur[bkt], 1);
        part[pos] = ((unsigned)(d & 511) << 16) | (unsigned)src[cb + o];
      }
    }
    return;
  }
  gemm_tile<true>(blockIdx.x, x, nullptr, nullptr, nullptr, W0, dinv, outB);
}

// ---------------- CSR fill from partition: one block per bucket (XCD-local writes) ----------------
__global__ __launch_bounds__(512) void k_fill2(const int* __restrict__ rowptr,
                                               const int* __restrict__ braw,
                                               const unsigned int* __restrict__ part,
                                               unsigned short* __restrict__ ep) {
  __shared__ int lrp[512];
  __shared__ int lfill[512];
  int b = blockIdx.x;
  int tid = threadIdx.x;
  int nbase = b << 9;
  lrp[tid] = (nbase + tid < NN) ? rowptr[nbase + tid] : 0;
  lfill[tid] = 0;
  __syncthreads();
  int start = lrp[0];
  int cnt = braw[b];
  for (int i = tid; i < cnt; i += 512) {
    unsigned p = part[start + i];
    int dloc = p >> 16;
    int pos = lrp[dloc] + atomicAdd(&lfill[dloc], 1);
    ep[pos] = (unsigned short)(p & 0xFFFF);
  }
}

// ---------------- gather-aggregate: 1 node per 8-lane group, uint4 (8ch) per lane ----------------
__global__ __launch_bounds__(256) void k_gather_stats(const int* __restrict__ rowptr,
                                                      const int* __restrict__ icnt,
                                                      const unsigned short* __restrict__ ep,
                                                      const float* __restrict__ dinv,
                                                      const __half* __restrict__ t,
                                                      __half* __restrict__ outp,
                                                      double* __restrict__ sums8) {
  int w = threadIdx.x >> 6;
  int lane = threadIdx.x & 63;
  int g = lane >> 3;   // group in wave
  int li = lane & 7;   // lane in group -> channel block
  int d = blockIdx.x * 32 + w * 8 + g;
  float acc[8] = {0.f, 0.f, 0.f, 0.f, 0.f, 0.f, 0.f, 0.f};
  if (d < NN) {
    uint4 u = ((const uint4*)(t + (size_t)d * 64))[li];  // self t'[d]
    {
      __half2* hp = (__half2*)&u;
#pragma unroll
      for (int j = 0; j < 4; ++j) {
        float2 f = __half22float2(hp[j]);
        acc[2 * j] += f.x;
        acc[2 * j + 1] += f.y;
      }
    }
    int e0 = rowptr[d], cnt = icnt[d];
    int k = 0;
    for (; k + 3 < cnt; k += 4) {
      ushort4 qe = *(const ushort4*)&ep[e0 + k];
      uint4 r0 = ((const uint4*)(t + (size_t)qe.x * 64))[li];
      uint4 r1 = ((const uint4*)(t + (size_t)qe.y * 64))[li];
      uint4 r2 = ((const uint4*)(t + (size_t)qe.z * 64))[li];
      uint4 r3 = ((const uint4*)(t + (size_t)qe.w * 64))[li];
      __half2* h0 = (__half2*)&r0;
      __half2* h1 = (__half2*)&r1;
      __half2* h2 = (__half2*)&r2;
      __half2* h3 = (__half2*)&r3;
#pragma unroll
      for (int j = 0; j < 4; ++j) {
        float2 f0 = __half22float2(h0[j]);
        float2 f1 = __half22float2(h1[j]);
        float2 f2 = __half22float2(h2[j]);
        float2 f3 = __half22float2(h3[j]);
        acc[2 * j] += (f0.x + f1.x) + (f2.x + f3.x);
        acc[2 * j + 1] += (f0.y + f1.y) + (f2.y + f3.y);
      }
    }
    for (; k < cnt; ++k) {
      uint4 r = ((const uint4*)(t + (size_t)ep[e0 + k] * 64))[li];
      __half2* hp = (__half2*)&r;
#pragma unroll
      for (int j = 0; j < 4; ++j) {
        float2 f = __half22float2(hp[j]);
        acc[2 * j] += f.x;
        acc[2 * j + 1] += f.y;
      }
    }
    float dv = dinv[d];
#pragma unroll
    for (int j = 0; j < 8; ++j) acc[j] *= dv;
    __half2 o0 = __floats2half2_rn(acc[0], acc[1]);
    __half2 o1 = __floats2half2_rn(acc[2], acc[3]);
    __half2 o2 = __floats2half2_rn(acc[4], acc[5]);
    __half2 o3 = __floats2half2_rn(acc[6], acc[7]);
    uint4 ov;
    ov.x = *(unsigned*)&o0;
    ov.y = *(unsigned*)&o1;
    ov.z = *(unsigned*)&o2;
    ov.w = *(unsigned*)&o3;
    ((uint4*)(outp + (size_t)d * 64))[li] = ov;
  }
  // stats: per-lane acc is the node's contribution for its 8 channels
  __shared__ float ls[4][8][8][8], lq[4][8][8][8];
#pragma unroll
  for (int j = 0; j < 8; ++j) {
    ls[w][g][li][j] = acc[j];
    lq[w][g][li][j] = acc[j] * acc[j];
  }
  __syncthreads();
  if (threadIdx.x < 64) {
    int c = threadIdx.x;
    int lsel = c >> 3, comp = c & 7;
    float S = 0.f, Q = 0.f;
#pragma unroll
    for (int ww = 0; ww < 4; ++ww)
#pragma unroll
      for (int gg = 0; gg < 8; ++gg) {
        S += ls[ww][gg][lsel][comp];
        Q += lq[ww][gg][lsel][comp];
      }
    double* bank = sums8 + (size_t)(blockIdx.x & 7) * 128;
    atomicAdd(&bank[c], (double)S);
    atomicAdd(&bank[64 + c], (double)Q);
  }
}

// ---------------- MFMA GEMM (fp16 in) with inlined BN-finalize + fused BN+ReLU ----------------
__global__ __launch_bounds__(256) void k_gemm64f(const __half* __restrict__ A,
                                                 const double* __restrict__ sums,
                                                 const float* __restrict__ gamma,
                                                 const float* __restrict__ beta,
                                                 const float* __restrict__ W,
                                                 const float* __restrict__ dinv,
                                                 __half* __restrict__ out) {
  gemm_tile<false>(blockIdx.x, A, sums, gamma, beta, W, dinv, out);
}

// ---------------- segmented mean-pool (inlined BN, fp16 in) + final FC ----------------
__global__ __launch_bounds__(256) void k_pool_final(const int* __restrict__ gstart,
                                                    const __half* __restrict__ h,
                                                    const double* __restrict__ sums,
                                                    const float* __restrict__ gamma,
                                                    const float* __restrict__ beta,
                                                    const float* __restrict__ fcW,
                                                    const float* __restrict__ fcb,
                                                    float* __restrict__ out) {
  __shared__ float sc[64], sh[64];
  __shared__ float pl[4][64];
  int tid = threadIdx.x;
  if (tid < 64) {
    double S = 0.0, Q = 0.0;
#pragma unroll
    for (int k = 0; k < 8; ++k) {
      S += sums[k * 128 + tid];
      Q += sums[k * 128 + 64 + tid];
    }
    double mu = S / (double)NN;
    double var = Q / (double)NN - mu * mu;
    float rstd = (float)(1.0 / sqrt(var + (double)BN_EPS));
    float scv = gamma[tid] * rstd;
    sc[tid] = scv;
    sh[tid] = beta[tid] - (float)mu * scv;
  }
  __syncthreads();
  int w = tid >> 6;
  int c = tid & 63;
  int g = blockIdx.x * 4 + w;
  float p = 0.f;
  if (g < GG) {
    int s = gstart[g], e = gstart[g + 1];
    float scv = sc[c], shv = sh[c], acc = 0.f;
    for (int i = s; i < e; ++i)
      acc += fmaxf(fmaf(__half2float(h[(size_t)i * 64 + c]), scv, shv), 0.f);
    p = acc / fmaxf((float)(e - s), 1.0f);
  }
  pl[w][c] = p;
  __syncthreads();
  if (tid < 4 * CC) {
    int gw = tid / CC, j = tid % CC;
    int gg = blockIdx.x * 4 + gw;
    if (gg < GG) {
      float acc = 0.f;
#pragma unroll
      for (int k = 0; k < 64; ++k) acc = fmaf(pl[gw][k], fcW[k * CC + j], acc);
      out[gg * CC + j] = acc + fcb[j];
    }
  }
}

extern "C" void kernel_launch(void* const* d_in, const int* in_sizes, int n_in,
                              void* d_out, int out_size, void* d_ws, size_t ws_size,
                              hipStream_t stream) {
  const float* x = (const float*)d_in[0];
  const int* eidx = (const int*)d_in[1];
  const int* batch = (const int*)d_in[2];
  const float* W[3] = {(const float*)d_in[3], (const float*)d_in[7], (const float*)d_in[11]};
  const float* gam[3] = {(const float*)d_in[5], (const float*)d_in[9], (const float*)d_in[13]};
  const float* bet[3] = {(const float*)d_in[6], (const float*)d_in[10], (const float*)d_in[14]};
  const float* fcW = (const float*)d_in[15];
  const float* fcb = (const float*)d_in[16];
  float* out = (float*)d_out;

  char* ws = (char*)d_ws;
  size_t off = 0;
  auto alloc = [&](size_t b) -> void* {
    void* p = ws + off;
    off = (off + b + 255) & ~(size_t)255;
    return p;
  };
  int* icnt = (int*)alloc((size_t)NN * 4);
  float* dinv = (float*)alloc((size_t)NN * 4);
  int* pre = (int*)alloc((size_t)NN * 4);
  int* bsum = (int*)alloc((size_t)NB_SCAN * 4);
  int* braw = (int*)alloc((size_t)NBKT * 4);
  int* gcur = (int*)alloc((size_t)NBKT * 4);
  int* rowptr = (int*)alloc((size_t)(NN + 1) * 4);
  int* gstart = (int*)alloc((size_t)(GG + 1) * 4);
  unsigned int* part = (unsigned int*)alloc((size_t)(EE + 4 * NN) * 4);
  unsigned short* ep = (unsigned short*)alloc((size_t)(EE + 4 * NN) * 2);
  __half* bufA = (__half*)alloc((size_t)NN * 64 * 2);
  __half* bufB = (__half*)alloc((size_t)NN * 64 * 2);
  double* sums24 = (double*)alloc((size_t)3 * 1024 * 8);

  const int* src = eidx;       // edge_index[0]
  const int* dst = eidx + EE;  // edge_index[1]

  // --- preprocessing ---
  hipMemsetAsync(icnt, 0, (size_t)NN * 4, stream);
  k_cb<<<NB_CNT + NB_BND, 256, 0, stream>>>(dst, icnt, batch, gstart);
  k_scan1<<<NB_SCAN, 256, 0, stream>>>(icnt, pre, bsum, dinv, braw);
  k_scan2<<<1, 64, 0, stream>>>(bsum, rowptr, sums24);
  k_scan3<<<(NN + 255) / 256, 256, 0, stream>>>(pre, bsum, rowptr, gcur);

  // --- edge partition + layer-0 MFMA GEMM (one dispatch); bucket-local CSR fill ---
  k_part_gemm0<<<NB_GEMM + NB_PART, 256, 0, stream>>>(src, dst, gcur, part, x, W[0],
                                                      dinv, bufB);
  k_fill2<<<NBKT, 512, 0, stream>>>(rowptr, braw, part, ep);

  // --- 3 GCN layers ---
  k_gather_stats<<<(NN + 31) / 32, 256, 0, stream>>>(rowptr, icnt, ep, dinv, bufB, bufA,
                                                     sums24 + 0 * 1024);
  for (int l = 1; l < 3; ++l) {
    k_gemm64f<<<NB_GEMM, 256, 0, stream>>>(bufA, sums24 + (l - 1) * 1024, gam[l - 1],
                                           bet[l - 1], W[l], dinv, bufB);
    k_gather_stats<<<(NN + 31) / 32, 256, 0, stream>>>(rowptr, icnt, ep, dinv, bufB, bufA,
                                                       sums24 + l * 1024);
  }

  // --- pool (inlined BN of layer 2) + FC ---
  k_pool_final<<<(GG + 3) / 4, 256, 0, stream>>>(gstart, bufA, sums24 + 2 * 1024, gam[2],
                                                 bet[2], fcW, fcb, out);
}

// Round 16
// 276.500 us; speedup vs baseline: 3.7660x; 1.0232x over previous
//
#include <hip/hip_runtime.h>
#include <hip/hip_fp16.h>
#include <math.h>

#define NN 50000
#define EE 800000
#define GG 500
#define CC 6
#define BN_EPS 1e-5f
#define NB_SCAN 49     // ceil(50000/1024)
#define NB_CNT 3125    // ceil(800000/256)
#define NB_BND 196     // ceil(50000/256)
#define NB_GEMM 782    // ceil(50000/64)  -- 64-row MFMA tiles
#define NBKT 98        // buckets of 512 nodes (dst>>9)
#define NB_PART 400    // partition blocks, 2000 edges each

typedef _Float16 f16x8 __attribute__((ext_vector_type(8)));
typedef float f32x4 __attribute__((ext_vector_type(4)));

// ---------------- count (edges) + graph bounds (nodes), one dispatch ----------------
__global__ __launch_bounds__(256) void k_cb(const int* __restrict__ dst,
                                            int* __restrict__ icnt,
                                            const int* __restrict__ batch,
                                            int* __restrict__ gstart) {
  int b = blockIdx.x;
  if (b < NB_CNT) {
    int e = b * 256 + threadIdx.x;
    if (e < EE) atomicAdd(&icnt[dst[e]], 1);
  } else {
    int i = (b - NB_CNT) * 256 + threadIdx.x;
    if (i >= NN) return;
    int bb = batch[i];
    if (i == 0) {
      for (int g = 0; g <= bb; ++g) gstart[g] = 0;
    } else {
      int pb = batch[i - 1];
      for (int g = pb + 1; g <= bb; ++g) gstart[g] = i;
    }
    if (i == NN - 1) {
      for (int g = bb + 1; g <= GG; ++g) gstart[g] = NN;
    }
  }
}

// ---------------- scan phase 1 over CEIL4(deg); also dinv + raw per-512-bucket sums ----------------
__global__ __launch_bounds__(256) void k_scan1(const int* __restrict__ icnt,
                                               int* __restrict__ pre,
                                               int* __restrict__ bsum,
                                               float* __restrict__ dinv,
                                               int* __restrict__ braw) {
  __shared__ int ls[256];
  __shared__ int lr[256];
  int base = blockIdx.x * 1024;
  int t = threadIdx.x;
  int v[4], s = 0, sraw = 0;
#pragma unroll
  for (int j = 0; j < 4; ++j) {
    int idx = base + t * 4 + j;
    int raw = (idx < NN) ? icnt[idx] : 0;
    if (idx < NN) dinv[idx] = rsqrtf((float)(raw + 1));  // +1 self-loop
    sraw += raw;
    v[j] = (raw + 3) & ~3;  // padded length (row starts 4-aligned)
    s += v[j];
  }
  ls[t] = s;
  lr[t] = sraw;
  __syncthreads();
  for (int ofs = 1; ofs < 256; ofs <<= 1) {
    int y = (t >= ofs) ? ls[t - ofs] : 0;
    __syncthreads();
    ls[t] += y;
    __syncthreads();
  }
  int excl = ls[t] - s;
#pragma unroll
  for (int j = 0; j < 4; ++j) {
    int idx = base + t * 4 + j;
    if (idx < NN) pre[idx] = excl;
    excl += v[j];
  }
  if (t == 255) bsum[blockIdx.x] = ls[255];
  // raw sums per 512-node half (threads 0..127 / 128..255)
  for (int ofs = 64; ofs >= 1; ofs >>= 1) {
    __syncthreads();
    if ((t & 127) < ofs) lr[t] += lr[t + ofs];
  }
  __syncthreads();
  if (t == 0) braw[2 * blockIdx.x] = lr[0];
  if (t == 128 && 2 * blockIdx.x + 1 < NBKT) braw[2 * blockIdx.x + 1] = lr[128];
}

// phase 2: serial scan of 49 block sums; zero 3 per-layer BN stat regions.
__global__ void k_scan2(int* __restrict__ bsum, int* __restrict__ rowptr,
                        double* __restrict__ sums24) {
  int t = threadIdx.x;  // 64 threads
  for (int k = t; k < 3 * 1024; k += 64) sums24[k] = 0.0;
  if (t == 0) {
    int run = 0;
    for (int b = 0; b < NB_SCAN; ++b) {
      int x = bsum[b];
      bsum[b] = run;
      run += x;
    }
    rowptr[NN] = run;
  }
}

// phase 3: rowptr; also init bucket write cursors gcur[b] = rowptr[b*512]
__global__ __launch_bounds__(256) void k_scan3(const int* __restrict__ pre,
                                               const int* __restrict__ bsum,
                                               int* __restrict__ rowptr,
                                               int* __restrict__ gcur) {
  int i = blockIdx.x * 256 + threadIdx.x;
  if (i < NN) {
    int v = pre[i] + bsum[i >> 10];
    rowptr[i] = v;
    if ((i & 511) == 0) gcur[i >> 9] = v;
  }
}

// ---------------- MFMA GEMM tile body (64 rows/block, 4 waves, fp16 inputs) ----------------
// out[n,:] = dinv[n] * f(A[n]) @ W  (fp16); LAYER0: A=f32 raw. else A=f16 + BN+ReLU.
// LDS XOR-swizzle (byte ^= (row&7)<<4) keeps stride-128B ds_read_b128 conflict-free.
template <bool LAYER0>
__device__ __forceinline__ void gemm_tile(int blockId,
                                          const void* __restrict__ Aptr,
                                          const double* __restrict__ sums,
                                          const float* __restrict__ gamma,
                                          const float* __restrict__ beta,
                                          const float* __restrict__ W,
                                          const float* __restrict__ dinv,
                                          __half* __restrict__ out) {
  __shared__ __align__(16) unsigned char AhB[64 * 128];  // A tile fp16 (swizzled)
  __shared__ __align__(16) unsigned char WtB[64 * 128];  // W^T fp16 (swizzled)
  __shared__ float sc[64], sh[64];
  int tid = threadIdx.x;
  if (!LAYER0 && tid < 64) {
    double S = 0.0, Q = 0.0;
#pragma unroll
    for (int k = 0; k < 8; ++k) {
      S += sums[k * 128 + tid];
      Q += sums[k * 128 + 64 + tid];
    }
    double mu = S / (double)NN;
    double var = Q / (double)NN - mu * mu;
    float rstd = (float)(1.0 / sqrt(var + (double)BN_EPS));
    float scv = gamma[tid] * rstd;
    sc[tid] = scv;
    sh[tid] = beta[tid] - (float)mu * scv;
  }
  // stage W^T as fp16: Wt[c][k] = W[k][c]
#pragma unroll
  for (int i = 0; i < 16; ++i) {
    int idx = tid + 256 * i;
    int k = idx >> 6, c = idx & 63;
    *(__half*)&WtB[c * 128 + ((k * 2) ^ ((c & 7) << 4))] = __float2half(W[idx]);
  }
  if (!LAYER0) __syncthreads();  // sc/sh ready before A staging
  int base = blockId * 64;
  if (LAYER0) {
    const float4* A4 = (const float4*)((const float*)Aptr + (size_t)base * 64);
#pragma unroll
    for (int i = 0; i < 4; ++i) {
      int idx = tid + 256 * i;
      int row = idx >> 4, q = idx & 15;
      float4 v = (base + row < NN) ? A4[idx] : float4{0.f, 0.f, 0.f, 0.f};
      __half2 p0 = __floats2half2_rn(v.x, v.y);
      __half2 p1 = __floats2half2_rn(v.z, v.w);
      uint2 u;
      u.x = *(unsigned*)&p0;
      u.y = *(unsigned*)&p1;
      *(uint2*)&AhB[row * 128 + ((q * 8) ^ ((row & 7) << 4))] = u;
    }
  } else {
    const uint4* A8 = (const uint4*)((const __half*)Aptr + (size_t)base * 64);
#pragma unroll
    for (int i = 0; i < 2; ++i) {
      int idx = tid + 256 * i;
      int row = idx >> 3, chunk = idx & 7;
      uint4 u = (base + row < NN) ? A8[idx] : uint4{0u, 0u, 0u, 0u};
      __half2* hp = (__half2*)&u;
      int c0 = chunk * 8;
      float f[8];
#pragma unroll
      for (int j = 0; j < 4; ++j) {
        float2 fv = __half22float2(hp[j]);
        f[2 * j] = fv.x;
        f[2 * j + 1] = fv.y;
      }
#pragma unroll
      for (int j = 0; j < 8; ++j)
        f[j] = fmaxf(fmaf(f[j], sc[c0 + j], sh[c0 + j]), 0.f);
      __half2 q0 = __floats2half2_rn(f[0], f[1]);
      __half2 q1 = __floats2half2_rn(f[2], f[3]);
      __half2 q2 = __floats2half2_rn(f[4], f[5]);
      __half2 q3 = __floats2half2_rn(f[6], f[7]);
      uint4 o;
      o.x = *(unsigned*)&q0;
      o.y = *(unsigned*)&q1;
      o.z = *(unsigned*)&q2;
      o.w = *(unsigned*)&q3;
      *(uint4*)&AhB[row * 128 + ((chunk * 16) ^ ((row & 7) << 4))] = o;
    }
  }
  __syncthreads();
  int lane = tid & 63;
  int w = tid >> 6;
  int r0 = w * 16;
  int lrow = lane & 15;
  int kg = lane >> 4;
  int s = (lrow & 7) << 4;
  // A fragments: rows r0+lrow, k-chunks kg*8 within each K=32 tile
  f16x8 a0 = *(f16x8*)&AhB[(r0 + lrow) * 128 + ((kg * 16) ^ s)];
  f16x8 a1 = *(f16x8*)&AhB[(r0 + lrow) * 128 + ((64 + kg * 16) ^ s)];
  f32x4 acc[4];
#pragma unroll
  for (int ct = 0; ct < 4; ++ct) {
    acc[ct] = (f32x4){0.f, 0.f, 0.f, 0.f};
    f16x8 b0 = *(f16x8*)&WtB[(ct * 16 + lrow) * 128 + ((kg * 16) ^ s)];
    f16x8 b1 = *(f16x8*)&WtB[(ct * 16 + lrow) * 128 + ((64 + kg * 16) ^ s)];
    acc[ct] = __builtin_amdgcn_mfma_f32_16x16x32_f16(a0, b0, acc[ct], 0, 0, 0);
    acc[ct] = __builtin_amdgcn_mfma_f32_16x16x32_f16(a1, b1, acc[ct], 0, 0, 0);
  }
  __syncthreads();  // A-frag reads done; reuse AhB as output staging (linear)
#pragma unroll
  for (int reg = 0; reg < 4; ++reg) {
    int row = r0 + kg * 4 + reg;
    float dv = dinv[base + row < NN ? base + row : NN - 1];
#pragma unroll
    for (int ct = 0; ct < 4; ++ct)
      *(__half*)&AhB[row * 128 + (ct * 16 + lrow) * 2] =
          __float2half(acc[ct][reg] * dv);
  }
  __syncthreads();
#pragma unroll
  for (int i = 0; i < 2; ++i) {
    int idx = tid + 256 * i;
    int row = idx >> 3, chunk = idx & 7;
    int n = base + row;
    if (n < NN)
      ((uint4*)(out + (size_t)n * 64))[chunk] = *(uint4*)&AhB[row * 128 + chunk * 16];
  }
}

// ---------------- edge partition by dst>>9 (LDS-binned) + layer-0 GEMM, one dispatch ----------------
__global__ __launch_bounds__(256) void k_part_gemm0(const int* __restrict__ src,
                                                    const int* __restrict__ dst,
                                                    int* __restrict__ gcur,
                                                    unsigned int* __restrict__ part,
                                                    const float* __restrict__ x,
                                                    const float* __restrict__ W0,
                                                    const float* __restrict__ dinv,
                                                    __half* __restrict__ outB) {
  if (blockIdx.x >= NB_GEMM) {
    __shared__ int lcnt[NBKT], lofs[NBKT], lcur[NBKT];
    int tid = threadIdx.x;
    int cb = (blockIdx.x - NB_GEMM) * 2000;
    if (tid < NBKT) lcnt[tid] = 0;
    __syncthreads();
    for (int it = 0; it < 8; ++it) {
      int o = it * 256 + tid;
      if (o < 2000) atomicAdd(&lcnt[dst[cb + o] >> 9], 1);
    }
    __syncthreads();
    if (tid < NBKT) {
      lofs[tid] = atomicAdd(&gcur[tid], lcnt[tid]);
      lcur[tid] = 0;
    }
    __syncthreads();
    for (int it = 0; it < 8; ++it) {
      int o = it * 256 + tid;
      if (o < 2000) {
        int d = dst[cb + o];
        int bkt = d >> 9;
        int pos = lofs[bkt] + atomicAdd(&lcur[bkt], 1);
        part[pos] = ((unsigned)(d & 511) << 16) | (unsigned)src[cb + o];
      }
    }
    return;
  }
  gemm_tile<true>(blockIdx.x, x, nullptr, nullptr, nullptr, W0, dinv, outB);
}

// ---------------- CSR fill from partition: one block per bucket (XCD-local writes) ----------------
__global__ __launch_bounds__(512) void k_fill2(const int* __restrict__ rowptr,
                                               const int* __restrict__ braw,
                                               const unsigned int* __restrict__ part,
                                               unsigned short* __restrict__ ep) {
  __shared__ int lrp[512];
  __shared__ int lfill[512];
  int b = blockIdx.x;
  int tid = threadIdx.x;
  int nbase = b << 9;
  lrp[tid] = (nbase + tid < NN) ? rowptr[nbase + tid] : 0;
  lfill[tid] = 0;
  __syncthreads();
  int start = lrp[0];
  int cnt = braw[b];
  for (int i = tid; i < cnt; i += 512) {
    unsigned p = part[start + i];
    int dloc = p >> 16;
    int pos = lrp[dloc] + atomicAdd(&lfill[dloc], 1);
    ep[pos] = (unsigned short)(p & 0xFFFF);
  }
}

// ---------------- gather-aggregate: 1 node per 8-lane group, uint4 (8ch) per lane ----------------
// 8-deep edge unroll: 64 row-loads in flight per wave (latency-bound kernel).
__global__ __launch_bounds__(256) void k_gather_stats(const int* __restrict__ rowptr,
                                                      const int* __restrict__ icnt,
                                                      const unsigned short* __restrict__ ep,
                                                      const float* __restrict__ dinv,
                                                      const __half* __restrict__ t,
                                                      __half* __restrict__ outp,
                                                      double* __restrict__ sums8) {
  int w = threadIdx.x >> 6;
  int lane = threadIdx.x & 63;
  int g = lane >> 3;   // group in wave
  int li = lane & 7;   // lane in group -> channel block
  int d = blockIdx.x * 32 + w * 8 + g;
  float acc[8] = {0.f, 0.f, 0.f, 0.f, 0.f, 0.f, 0.f, 0.f};
  if (d < NN) {
    uint4 u = ((const uint4*)(t + (size_t)d * 64))[li];  // self t'[d]
    {
      __half2* hp = (__half2*)&u;
#pragma unroll
      for (int j = 0; j < 4; ++j) {
        float2 f = __half22float2(hp[j]);
        acc[2 * j] += f.x;
        acc[2 * j + 1] += f.y;
      }
    }
    int e0 = rowptr[d], cnt = icnt[d];
    int k = 0;
    for (; k + 7 < cnt; k += 8) {
      ushort4 qa = *(const ushort4*)&ep[e0 + k];
      ushort4 qb = *(const ushort4*)&ep[e0 + k + 4];
      uint4 r0 = ((const uint4*)(t + (size_t)qa.x * 64))[li];
      uint4 r1 = ((const uint4*)(t + (size_t)qa.y * 64))[li];
      uint4 r2 = ((const uint4*)(t + (size_t)qa.z * 64))[li];
      uint4 r3 = ((const uint4*)(t + (size_t)qa.w * 64))[li];
      uint4 r4 = ((const uint4*)(t + (size_t)qb.x * 64))[li];
      uint4 r5 = ((const uint4*)(t + (size_t)qb.y * 64))[li];
      uint4 r6 = ((const uint4*)(t + (size_t)qb.z * 64))[li];
      uint4 r7 = ((const uint4*)(t + (size_t)qb.w * 64))[li];
      uint4* rr[8] = {&r0, &r1, &r2, &r3, &r4, &r5, &r6, &r7};
#pragma unroll
      for (int m = 0; m < 8; ++m) {
        __half2* hp = (__half2*)rr[m];
#pragma unroll
        for (int j = 0; j < 4; ++j) {
          float2 f = __half22float2(hp[j]);
          acc[2 * j] += f.x;
          acc[2 * j + 1] += f.y;
        }
      }
    }
    for (; k + 3 < cnt; k += 4) {
      ushort4 qe = *(const ushort4*)&ep[e0 + k];
      uint4 r0 = ((const uint4*)(t + (size_t)qe.x * 64))[li];
      uint4 r1 = ((const uint4*)(t + (size_t)qe.y * 64))[li];
      uint4 r2 = ((const uint4*)(t + (size_t)qe.z * 64))[li];
      uint4 r3 = ((const uint4*)(t + (size_t)qe.w * 64))[li];
      uint4* rr[4] = {&r0, &r1, &r2, &r3};
#pragma unroll
      for (int m = 0; m < 4; ++m) {
        __half2* hp = (__half2*)rr[m];
#pragma unroll
        for (int j = 0; j < 4; ++j) {
          float2 f = __half22float2(hp[j]);
          acc[2 * j] += f.x;
          acc[2 * j + 1] += f.y;
        }
      }
    }
    for (; k < cnt; ++k) {
      uint4 r = ((const uint4*)(t + (size_t)ep[e0 + k] * 64))[li];
      __half2* hp = (__half2*)&r;
#pragma unroll
      for (int j = 0; j < 4; ++j) {
        float2 f = __half22float2(hp[j]);
        acc[2 * j] += f.x;
        acc[2 * j + 1] += f.y;
      }
    }
    float dv = dinv[d];
#pragma unroll
    for (int j = 0; j < 8; ++j) acc[j] *= dv;
    __half2 o0 = __floats2half2_rn(acc[0], acc[1]);
    __half2 o1 = __floats2half2_rn(acc[2], acc[3]);
    __half2 o2 = __floats2half2_rn(acc[4], acc[5]);
    __half2 o3 = __floats2half2_rn(acc[6], acc[7]);
    uint4 ov;
    ov.x = *(unsigned*)&o0;
    ov.y = *(unsigned*)&o1;
    ov.z = *(unsigned*)&o2;
    ov.w = *(unsigned*)&o3;
    ((uint4*)(outp + (size_t)d * 64))[li] = ov;
  }
  // stats: per-lane acc is the node's contribution for its 8 channels
  __shared__ float ls[4][8][8][8], lq[4][8][8][8];
#pragma unroll
  for (int j = 0; j < 8; ++j) {
    ls[w][g][li][j] = acc[j];
    lq[w][g][li][j] = acc[j] * acc[j];
  }
  __syncthreads();
  if (threadIdx.x < 64) {
    int c = threadIdx.x;
    int lsel = c >> 3, comp = c & 7;
    float S = 0.f, Q = 0.f;
#pragma unroll
    for (int ww = 0; ww < 4; ++ww)
#pragma unroll
      for (int gg = 0; gg < 8; ++gg) {
        S += ls[ww][gg][lsel][comp];
        Q += lq[ww][gg][lsel][comp];
      }
    double* bank = sums8 + (size_t)(blockIdx.x & 7) * 128;
    atomicAdd(&bank[c], (double)S);
    atomicAdd(&bank[64 + c], (double)Q);
  }
}

// ---------------- MFMA GEMM (fp16 in) with inlined BN-finalize + fused BN+ReLU ----------------
__global__ __launch_bounds__(256) void k_gemm64f(const __half* __restrict__ A,
                                                 const double* __restrict__ sums,
                                                 const float* __restrict__ gamma,
                                                 const float* __restrict__ beta,
                                                 const float* __restrict__ W,
                                                 const float* __restrict__ dinv,
                                                 __half* __restrict__ out) {
  gemm_tile<false>(blockIdx.x, A, sums, gamma, beta, W, dinv, out);
}

// ---------------- segmented mean-pool (inlined BN, fp16 in) + final FC ----------------
__global__ __launch_bounds__(256) void k_pool_final(const int* __restrict__ gstart,
                                                    const __half* __restrict__ h,
                                                    const double* __restrict__ sums,
                                                    const float* __restrict__ gamma,
                                                    const float* __restrict__ beta,
                                                    const float* __restrict__ fcW,
                                                    const float* __restrict__ fcb,
                                                    float* __restrict__ out) {
  __shared__ float sc[64], sh[64];
  __shared__ float pl[4][64];
  int tid = threadIdx.x;
  if (tid < 64) {
    double S = 0.0, Q = 0.0;
#pragma unroll
    for (int k = 0; k < 8; ++k) {
      S += sums[k * 128 + tid];
      Q += sums[k * 128 + 64 + tid];
    }
    double mu = S / (double)NN;
    double var = Q / (double)NN - mu * mu;
    float rstd = (float)(1.0 / sqrt(var + (double)BN_EPS));
    float scv = gamma[tid] * rstd;
    sc[tid] = scv;
    sh[tid] = beta[tid] - (float)mu * scv;
  }
  __syncthreads();
  int w = tid >> 6;
  int c = tid & 63;
  int g = blockIdx.x * 4 + w;
  float p = 0.f;
  if (g < GG) {
    int s = gstart[g], e = gstart[g + 1];
    float scv = sc[c], shv = sh[c], acc = 0.f;
    for (int i = s; i < e; ++i)
      acc += fmaxf(fmaf(__half2float(h[(size_t)i * 64 + c]), scv, shv), 0.f);
    p = acc / fmaxf((float)(e - s), 1.0f);
  }
  pl[w][c] = p;
  __syncthreads();
  if (tid < 4 * CC) {
    int gw = tid / CC, j = tid % CC;
    int gg = blockIdx.x * 4 + gw;
    if (gg < GG) {
      float acc = 0.f;
#pragma unroll
      for (int k = 0; k < 64; ++k) acc = fmaf(pl[gw][k], fcW[k * CC + j], acc);
      out[gg * CC + j] = acc + fcb[j];
    }
  }
}

extern "C" void kernel_launch(void* const* d_in, const int* in_sizes, int n_in,
                              void* d_out, int out_size, void* d_ws, size_t ws_size,
                              hipStream_t stream) {
  const float* x = (const float*)d_in[0];
  const int* eidx = (const int*)d_in[1];
  const int* batch = (const int*)d_in[2];
  const float* W[3] = {(const float*)d_in[3], (const float*)d_in[7], (const float*)d_in[11]};
  const float* gam[3] = {(const float*)d_in[5], (const float*)d_in[9], (const float*)d_in[13]};
  const float* bet[3] = {(const float*)d_in[6], (const float*)d_in[10], (const float*)d_in[14]};
  const float* fcW = (const float*)d_in[15];
  const float* fcb = (const float*)d_in[16];
  float* out = (float*)d_out;

  char* ws = (char*)d_ws;
  size_t off = 0;
  auto alloc = [&](size_t b) -> void* {
    void* p = ws + off;
    off = (off + b + 255) & ~(size_t)255;
    return p;
  };
  int* icnt = (int*)alloc((size_t)NN * 4);
  float* dinv = (float*)alloc((size_t)NN * 4);
  int* pre = (int*)alloc((size_t)NN * 4);
  int* bsum = (int*)alloc((size_t)NB_SCAN * 4);
  int* braw = (int*)alloc((size_t)NBKT * 4);
  int* gcur = (int*)alloc((size_t)NBKT * 4);
  int* rowptr = (int*)alloc((size_t)(NN + 1) * 4);
  int* gstart = (int*)alloc((size_t)(GG + 1) * 4);
  unsigned int* part = (unsigned int*)alloc((size_t)(EE + 4 * NN) * 4);
  unsigned short* ep = (unsigned short*)alloc((size_t)(EE + 4 * NN) * 2);
  __half* bufA = (__half*)alloc((size_t)NN * 64 * 2);
  __half* bufB = (__half*)alloc((size_t)NN * 64 * 2);
  double* sums24 = (double*)alloc((size_t)3 * 1024 * 8);

  const int* src = eidx;       // edge_index[0]
  const int* dst = eidx + EE;  // edge_index[1]

  // --- preprocessing ---
  hipMemsetAsync(icnt, 0, (size_t)NN * 4, stream);
  k_cb<<<NB_CNT + NB_BND, 256, 0, stream>>>(dst, icnt, batch, gstart);
  k_scan1<<<NB_SCAN, 256, 0, stream>>>(icnt, pre, bsum, dinv, braw);
  k_scan2<<<1, 64, 0, stream>>>(bsum, rowptr, sums24);
  k_scan3<<<(NN + 255) / 256, 256, 0, stream>>>(pre, bsum, rowptr, gcur);

  // --- edge partition + layer-0 MFMA GEMM (one dispatch); bucket-local CSR fill ---
  k_part_gemm0<<<NB_GEMM + NB_PART, 256, 0, stream>>>(src, dst, gcur, part, x, W[0],
                                                      dinv, bufB);
  k_fill2<<<NBKT, 512, 0, stream>>>(rowptr, braw, part, ep);

  // --- 3 GCN layers ---
  k_gather_stats<<<(NN + 31) / 32, 256, 0, stream>>>(rowptr, icnt, ep, dinv, bufB, bufA,
                                                     sums24 + 0 * 1024);
  for (int l = 1; l < 3; ++l) {
    k_gemm64f<<<NB_GEMM, 256, 0, stream>>>(bufA, sums24 + (l - 1) * 1024, gam[l - 1],
                                           bet[l - 1], W[l], dinv, bufB);
    k_gather_stats<<<(NN + 31) / 32, 256, 0, stream>>>(rowptr, icnt, ep, dinv, bufB, bufA,
                                                       sums24 + l * 1024);
  }

  // --- pool (inlined BN of layer 2) + FC ---
  k_pool_final<<<(GG + 3) / 4, 256, 0, stream>>>(gstart, bufA, sums24 + 2 * 1024, gam[2],
                                                 bet[2], fcW, fcb, out);
}

// Round 17
// 239.000 us; speedup vs baseline: 4.3569x; 1.1569x over previous
//
#include <hip/hip_runtime.h>
#include <hip/hip_fp16.h>
#include <math.h>

#define NN 50000
#define EE 800000
#define GG 500
#define CC 6
#define BN_EPS 1e-5f
#define NB_BND 196     // ceil(50000/256)
#define NB_GEMM 782    // ceil(50000/64)  -- 64-row MFMA tiles
#define NBKT 98        // buckets of 512 nodes (dst>>9)
#define NB_PART 400    // partition blocks, 2000 edges each
#define PCAP 12288     // per-bucket partition capacity (uints); avg 8163, +45 sigma
#define EPCAP 14336    // per-bucket ep capacity (ushorts); max padded ~10.5K

typedef _Float16 f16x8 __attribute__((ext_vector_type(8)));
typedef float f32x4 __attribute__((ext_vector_type(4)));

// ---------------- graph bounds + gcur init + stat zeroing, one small dispatch ----------------
__global__ __launch_bounds__(256) void k_bounds(const int* __restrict__ batch,
                                                int* __restrict__ gstart,
                                                int* __restrict__ gcur,
                                                double* __restrict__ sums24) {
  if (blockIdx.x == 0) {
    if (threadIdx.x < NBKT) gcur[threadIdx.x] = threadIdx.x * PCAP;
    for (int k = threadIdx.x; k < 3 * 1024; k += 256) sums24[k] = 0.0;
  }
  int i = blockIdx.x * 256 + threadIdx.x;
  if (i >= NN) return;
  int bb = batch[i];
  if (i == 0) {
    for (int g = 0; g <= bb; ++g) gstart[g] = 0;
  } else {
    int pb = batch[i - 1];
    for (int g = pb + 1; g <= bb; ++g) gstart[g] = i;
  }
  if (i == NN - 1) {
    for (int g = bb + 1; g <= GG; ++g) gstart[g] = NN;
  }
}

// ---------------- MFMA GEMM tile body (64 rows/block, 4 waves, fp16 inputs) ----------------
// LAYER0: A=f32 raw, NO dinv prescale (applied later in k_fill2b). else: A=f16 + BN+ReLU + dinv.
template <bool LAYER0>
__device__ __forceinline__ void gemm_tile(int blockId,
                                          const void* __restrict__ Aptr,
                                          const double* __restrict__ sums,
                                          const float* __restrict__ gamma,
                                          const float* __restrict__ beta,
                                          const float* __restrict__ W,
                                          const float* __restrict__ dinv,
                                          __half* __restrict__ out) {
  __shared__ __align__(16) unsigned char AhB[64 * 128];  // A tile fp16 (swizzled)
  __shared__ __align__(16) unsigned char WtB[64 * 128];  // W^T fp16 (swizzled)
  __shared__ float sc[64], sh[64];
  int tid = threadIdx.x;
  if (!LAYER0 && tid < 64) {
    double S = 0.0, Q = 0.0;
#pragma unroll
    for (int k = 0; k < 8; ++k) {
      S += sums[k * 128 + tid];
      Q += sums[k * 128 + 64 + tid];
    }
    double mu = S / (double)NN;
    double var = Q / (double)NN - mu * mu;
    float rstd = (float)(1.0 / sqrt(var + (double)BN_EPS));
    float scv = gamma[tid] * rstd;
    sc[tid] = scv;
    sh[tid] = beta[tid] - (float)mu * scv;
  }
  // stage W^T as fp16: Wt[c][k] = W[k][c]
#pragma unroll
  for (int i = 0; i < 16; ++i) {
    int idx = tid + 256 * i;
    int k = idx >> 6, c = idx & 63;
    *(__half*)&WtB[c * 128 + ((k * 2) ^ ((c & 7) << 4))] = __float2half(W[idx]);
  }
  if (!LAYER0) __syncthreads();  // sc/sh ready before A staging
  int base = blockId * 64;
  if (LAYER0) {
    const float4* A4 = (const float4*)((const float*)Aptr + (size_t)base * 64);
#pragma unroll
    for (int i = 0; i < 4; ++i) {
      int idx = tid + 256 * i;
      int row = idx >> 4, q = idx & 15;
      float4 v = (base + row < NN) ? A4[idx] : float4{0.f, 0.f, 0.f, 0.f};
      __half2 p0 = __floats2half2_rn(v.x, v.y);
      __half2 p1 = __floats2half2_rn(v.z, v.w);
      uint2 u;
      u.x = *(unsigned*)&p0;
      u.y = *(unsigned*)&p1;
      *(uint2*)&AhB[row * 128 + ((q * 8) ^ ((row & 7) << 4))] = u;
    }
  } else {
    const uint4* A8 = (const uint4*)((const __half*)Aptr + (size_t)base * 64);
#pragma unroll
    for (int i = 0; i < 2; ++i) {
      int idx = tid + 256 * i;
      int row = idx >> 3, chunk = idx & 7;
      uint4 u = (base + row < NN) ? A8[idx] : uint4{0u, 0u, 0u, 0u};
      __half2* hp = (__half2*)&u;
      int c0 = chunk * 8;
      float f[8];
#pragma unroll
      for (int j = 0; j < 4; ++j) {
        float2 fv = __half22float2(hp[j]);
        f[2 * j] = fv.x;
        f[2 * j + 1] = fv.y;
      }
#pragma unroll
      for (int j = 0; j < 8; ++j)
        f[j] = fmaxf(fmaf(f[j], sc[c0 + j], sh[c0 + j]), 0.f);
      __half2 q0 = __floats2half2_rn(f[0], f[1]);
      __half2 q1 = __floats2half2_rn(f[2], f[3]);
      __half2 q2 = __floats2half2_rn(f[4], f[5]);
      __half2 q3 = __floats2half2_rn(f[6], f[7]);
      uint4 o;
      o.x = *(unsigned*)&q0;
      o.y = *(unsigned*)&q1;
      o.z = *(unsigned*)&q2;
      o.w = *(unsigned*)&q3;
      *(uint4*)&AhB[row * 128 + ((chunk * 16) ^ ((row & 7) << 4))] = o;
    }
  }
  __syncthreads();
  int lane = tid & 63;
  int w = tid >> 6;
  int r0 = w * 16;
  int lrow = lane & 15;
  int kg = lane >> 4;
  int s = (lrow & 7) << 4;
  f16x8 a0 = *(f16x8*)&AhB[(r0 + lrow) * 128 + ((kg * 16) ^ s)];
  f16x8 a1 = *(f16x8*)&AhB[(r0 + lrow) * 128 + ((64 + kg * 16) ^ s)];
  f32x4 acc[4];
#pragma unroll
  for (int ct = 0; ct < 4; ++ct) {
    acc[ct] = (f32x4){0.f, 0.f, 0.f, 0.f};
    f16x8 b0 = *(f16x8*)&WtB[(ct * 16 + lrow) * 128 + ((kg * 16) ^ s)];
    f16x8 b1 = *(f16x8*)&WtB[(ct * 16 + lrow) * 128 + ((64 + kg * 16) ^ s)];
    acc[ct] = __builtin_amdgcn_mfma_f32_16x16x32_f16(a0, b0, acc[ct], 0, 0, 0);
    acc[ct] = __builtin_amdgcn_mfma_f32_16x16x32_f16(a1, b1, acc[ct], 0, 0, 0);
  }
  __syncthreads();  // A-frag reads done; reuse AhB as output staging (linear)
#pragma unroll
  for (int reg = 0; reg < 4; ++reg) {
    int row = r0 + kg * 4 + reg;
    int n = base + row;
    float dv = 1.0f;
    if (!LAYER0) dv = dinv[n < NN ? n : NN - 1];
#pragma unroll
    for (int ct = 0; ct < 4; ++ct)
      *(__half*)&AhB[row * 128 + (ct * 16 + lrow) * 2] =
          __float2half(acc[ct][reg] * dv);
  }
  __syncthreads();
#pragma unroll
  for (int i = 0; i < 2; ++i) {
    int idx = tid + 256 * i;
    int row = idx >> 3, chunk = idx & 7;
    int n = base + row;
    if (n < NN)
      ((uint4*)(out + (size_t)n * 64))[chunk] = *(uint4*)&AhB[row * 128 + chunk * 16];
  }
}

// ---------------- edge partition by dst>>9 (fixed-capacity buckets) + layer-0 GEMM ----------------
__global__ __launch_bounds__(256) void k_part_gemm0(const int* __restrict__ src,
                                                    const int* __restrict__ dst,
                                                    int* __restrict__ gcur,
                                                    unsigned int* __restrict__ part,
                                                    const float* __restrict__ x,
                                                    const float* __restrict__ W0,
                                                    __half* __restrict__ outB) {
  if (blockIdx.x >= NB_GEMM) {
    __shared__ int lcnt[NBKT], lofs[NBKT], lcur[NBKT];
    int tid = threadIdx.x;
    int cb = (blockIdx.x - NB_GEMM) * 2000;
    if (tid < NBKT) lcnt[tid] = 0;
    __syncthreads();
    for (int it = 0; it < 8; ++it) {
      int o = it * 256 + tid;
      if (o < 2000) atomicAdd(&lcnt[dst[cb + o] >> 9], 1);
    }
    __syncthreads();
    if (tid < NBKT) {
      lofs[tid] = atomicAdd(&gcur[tid], lcnt[tid]);
      lcur[tid] = 0;
    }
    __syncthreads();
    for (int it = 0; it < 8; ++it) {
      int o = it * 256 + tid;
      if (o < 2000) {
        int d = dst[cb + o];
        int bkt = d >> 9;
        int pos = lofs[bkt] + atomicAdd(&lcur[bkt], 1);
        part[pos] = ((unsigned)(d & 511) << 16) | (unsigned)src[cb + o];
      }
    }
    return;
  }
  gemm_tile<true>(blockIdx.x, x, nullptr, nullptr, nullptr, W0, nullptr, outB);
}

// ---------------- fill2b: per-bucket counts, prefix, rowptr/icnt/dinv, ep scatter, bufB scale ----
__global__ __launch_bounds__(512) void k_fill2b(const int* __restrict__ gcur,
                                                const unsigned int* __restrict__ part,
                                                unsigned short* __restrict__ ep,
                                                int* __restrict__ rowptr,
                                                int* __restrict__ icnt,
                                                float* __restrict__ dinv,
                                                __half* __restrict__ bufB) {
  __shared__ int lcnt[512];
  __shared__ int lpre[512];
  __shared__ int lfill[512];
  __shared__ float ldinv[512];
  int b = blockIdx.x;
  int tid = threadIdx.x;
  int nbase = b << 9;
  int cnt_b = gcur[b] - b * PCAP;
  const unsigned int* ps = part + (size_t)b * PCAP;
  lcnt[tid] = 0;
  __syncthreads();
  for (int i = tid; i < cnt_b; i += 512) atomicAdd(&lcnt[ps[i] >> 16], 1);
  __syncthreads();
  int myc = lcnt[tid];
  int pad = (myc + 3) & ~3;
  lpre[tid] = pad;
  __syncthreads();
  for (int ofs = 1; ofs < 512; ofs <<= 1) {
    int y = (tid >= ofs) ? lpre[tid - ofs] : 0;
    __syncthreads();
    lpre[tid] += y;
    __syncthreads();
  }
  int excl = lpre[tid] - pad;  // exclusive padded prefix (4-aligned)
  float dv = rsqrtf((float)(myc + 1));
  int node = nbase + tid;
  if (node < NN) {
    rowptr[node] = b * EPCAP + excl;
    icnt[node] = myc;
    dinv[node] = dv;
  }
  ldinv[tid] = dv;
  lfill[tid] = 0;
  __syncthreads();
  lpre[tid] = excl;
  __syncthreads();
  for (int i = tid; i < cnt_b; i += 512) {
    unsigned p = ps[i];
    int dloc = p >> 16;
    int pos = lpre[dloc] + atomicAdd(&lfill[dloc], 1);
    ep[(size_t)b * EPCAP + pos] = (unsigned short)(p & 0xFFFF);
  }
  // prescale layer-0 GEMM rows for this bucket's nodes by dinv
  __syncthreads();
  int maxrow = NN - nbase;
  if (maxrow > 512) maxrow = 512;
  uint4* B4 = (uint4*)(bufB + (size_t)nbase * 64);
  for (int i = tid; i < maxrow * 8; i += 512) {
    float dvr = ldinv[i >> 3];
    uint4 u = B4[i];
    __half2* hp = (__half2*)&u;
#pragma unroll
    for (int j = 0; j < 4; ++j) {
      float2 f = __half22float2(hp[j]);
      hp[j] = __floats2half2_rn(f.x * dvr, f.y * dvr);
    }
    B4[i] = u;
  }
}

// ---------------- gather-aggregate: 1 node per 8-lane group, uint4 (8ch) per lane ----------------
__global__ __launch_bounds__(256) void k_gather_stats(const int* __restrict__ rowptr,
                                                      const int* __restrict__ icnt,
                                                      const unsigned short* __restrict__ ep,
                                                      const float* __restrict__ dinv,
                                                      const __half* __restrict__ t,
                                                      __half* __restrict__ outp,
                                                      double* __restrict__ sums8) {
  int w = threadIdx.x >> 6;
  int lane = threadIdx.x & 63;
  int g = lane >> 3;   // group in wave
  int li = lane & 7;   // lane in group -> channel block
  int d = blockIdx.x * 32 + w * 8 + g;
  float acc[8] = {0.f, 0.f, 0.f, 0.f, 0.f, 0.f, 0.f, 0.f};
  if (d < NN) {
    uint4 u = ((const uint4*)(t + (size_t)d * 64))[li];  // self t'[d]
    {
      __half2* hp = (__half2*)&u;
#pragma unroll
      for (int j = 0; j < 4; ++j) {
        float2 f = __half22float2(hp[j]);
        acc[2 * j] += f.x;
        acc[2 * j + 1] += f.y;
      }
    }
    int e0 = rowptr[d], cnt = icnt[d];
    int k = 0;
    for (; k + 7 < cnt; k += 8) {
      ushort4 qa = *(const ushort4*)&ep[e0 + k];
      ushort4 qb = *(const ushort4*)&ep[e0 + k + 4];
      uint4 r0 = ((const uint4*)(t + (size_t)qa.x * 64))[li];
      uint4 r1 = ((const uint4*)(t + (size_t)qa.y * 64))[li];
      uint4 r2 = ((const uint4*)(t + (size_t)qa.z * 64))[li];
      uint4 r3 = ((const uint4*)(t + (size_t)qa.w * 64))[li];
      uint4 r4 = ((const uint4*)(t + (size_t)qb.x * 64))[li];
      uint4 r5 = ((const uint4*)(t + (size_t)qb.y * 64))[li];
      uint4 r6 = ((const uint4*)(t + (size_t)qb.z * 64))[li];
      uint4 r7 = ((const uint4*)(t + (size_t)qb.w * 64))[li];
      uint4* rr[8] = {&r0, &r1, &r2, &r3, &r4, &r5, &r6, &r7};
#pragma unroll
      for (int m = 0; m < 8; ++m) {
        __half2* hp = (__half2*)rr[m];
#pragma unroll
        for (int j = 0; j < 4; ++j) {
          float2 f = __half22float2(hp[j]);
          acc[2 * j] += f.x;
          acc[2 * j + 1] += f.y;
        }
      }
    }
    for (; k + 3 < cnt; k += 4) {
      ushort4 qe = *(const ushort4*)&ep[e0 + k];
      uint4 r0 = ((const uint4*)(t + (size_t)qe.x * 64))[li];
      uint4 r1 = ((const uint4*)(t + (size_t)qe.y * 64))[li];
      uint4 r2 = ((const uint4*)(t + (size_t)qe.z * 64))[li];
      uint4 r3 = ((const uint4*)(t + (size_t)qe.w * 64))[li];
      uint4* rr[4] = {&r0, &r1, &r2, &r3};
#pragma unroll
      for (int m = 0; m < 4; ++m) {
        __half2* hp = (__half2*)rr[m];
#pragma unroll
        for (int j = 0; j < 4; ++j) {
          float2 f = __half22float2(hp[j]);
          acc[2 * j] += f.x;
          acc[2 * j + 1] += f.y;
        }
      }
    }
    for (; k < cnt; ++k) {
      uint4 r = ((const uint4*)(t + (size_t)ep[e0 + k] * 64))[li];
      __half2* hp = (__half2*)&r;
#pragma unroll
      for (int j = 0; j < 4; ++j) {
        float2 f = __half22float2(hp[j]);
        acc[2 * j] += f.x;
        acc[2 * j + 1] += f.y;
      }
    }
    float dv = dinv[d];
#pragma unroll
    for (int j = 0; j < 8; ++j) acc[j] *= dv;
    __half2 o0 = __floats2half2_rn(acc[0], acc[1]);
    __half2 o1 = __floats2half2_rn(acc[2], acc[3]);
    __half2 o2 = __floats2half2_rn(acc[4], acc[5]);
    __half2 o3 = __floats2half2_rn(acc[6], acc[7]);
    uint4 ov;
    ov.x = *(unsigned*)&o0;
    ov.y = *(unsigned*)&o1;
    ov.z = *(unsigned*)&o2;
    ov.w = *(unsigned*)&o3;
    ((uint4*)(outp + (size_t)d * 64))[li] = ov;
  }
  // stats: per-lane acc is the node's contribution for its 8 channels
  __shared__ float ls[4][8][8][8], lq[4][8][8][8];
#pragma unroll
  for (int j = 0; j < 8; ++j) {
    ls[w][g][li][j] = acc[j];
    lq[w][g][li][j] = acc[j] * acc[j];
  }
  __syncthreads();
  if (threadIdx.x < 64) {
    int c = threadIdx.x;
    int lsel = c >> 3, comp = c & 7;
    float S = 0.f, Q = 0.f;
#pragma unroll
    for (int ww = 0; ww < 4; ++ww)
#pragma unroll
      for (int gg = 0; gg < 8; ++gg) {
        S += ls[ww][gg][lsel][comp];
        Q += lq[ww][gg][lsel][comp];
      }
    double* bank = sums8 + (size_t)(blockIdx.x & 7) * 128;
    atomicAdd(&bank[c], (double)S);
    atomicAdd(&bank[64 + c], (double)Q);
  }
}

// ---------------- MFMA GEMM (fp16 in) with inlined BN-finalize + fused BN+ReLU ----------------
__global__ __launch_bounds__(256) void k_gemm64f(const __half* __restrict__ A,
                                                 const double* __restrict__ sums,
                                                 const float* __restrict__ gamma,
                                                 const float* __restrict__ beta,
                                                 const float* __restrict__ W,
                                                 const float* __restrict__ dinv,
                                                 __half* __restrict__ out) {
  gemm_tile<false>(blockIdx.x, A, sums, gamma, beta, W, dinv, out);
}

// ---------------- segmented mean-pool (inlined BN, fp16 in) + final FC ----------------
__global__ __launch_bounds__(256) void k_pool_final(const int* __restrict__ gstart,
                                                    const __half* __restrict__ h,
                                                    const double* __restrict__ sums,
                                                    const float* __restrict__ gamma,
                                                    const float* __restrict__ beta,
                                                    const float* __restrict__ fcW,
                                                    const float* __restrict__ fcb,
                                                    float* __restrict__ out) {
  __shared__ float sc[64], sh[64];
  __shared__ float pl[4][64];
  int tid = threadIdx.x;
  if (tid < 64) {
    double S = 0.0, Q = 0.0;
#pragma unroll
    for (int k = 0; k < 8; ++k) {
      S += sums[k * 128 + tid];
      Q += sums[k * 128 + 64 + tid];
    }
    double mu = S / (double)NN;
    double var = Q / (double)NN - mu * mu;
    float rstd = (float)(1.0 / sqrt(var + (double)BN_EPS));
    float scv = gamma[tid] * rstd;
    sc[tid] = scv;
    sh[tid] = beta[tid] - (float)mu * scv;
  }
  __syncthreads();
  int w = tid >> 6;
  int c = tid & 63;
  int g = blockIdx.x * 4 + w;
  float p = 0.f;
  if (g < GG) {
    int s = gstart[g], e = gstart[g + 1];
    float scv = sc[c], shv = sh[c], acc = 0.f;
    for (int i = s; i < e; ++i)
      acc += fmaxf(fmaf(__half2float(h[(size_t)i * 64 + c]), scv, shv), 0.f);
    p = acc / fmaxf((float)(e - s), 1.0f);
  }
  pl[w][c] = p;
  __syncthreads();
  if (tid < 4 * CC) {
    int gw = tid / CC, j = tid % CC;
    int gg = blockIdx.x * 4 + gw;
    if (gg < GG) {
      float acc = 0.f;
#pragma unroll
      for (int k = 0; k < 64; ++k) acc = fmaf(pl[gw][k], fcW[k * CC + j], acc);
      out[gg * CC + j] = acc + fcb[j];
    }
  }
}

extern "C" void kernel_launch(void* const* d_in, const int* in_sizes, int n_in,
                              void* d_out, int out_size, void* d_ws, size_t ws_size,
                              hipStream_t stream) {
  const float* x = (const float*)d_in[0];
  const int* eidx = (const int*)d_in[1];
  const int* batch = (const int*)d_in[2];
  const float* W[3] = {(const float*)d_in[3], (const float*)d_in[7], (const float*)d_in[11]};
  const float* gam[3] = {(const float*)d_in[5], (const float*)d_in[9], (const float*)d_in[13]};
  const float* bet[3] = {(const float*)d_in[6], (const float*)d_in[10], (const float*)d_in[14]};
  const float* fcW = (const float*)d_in[15];
  const float* fcb = (const float*)d_in[16];
  float* out = (float*)d_out;

  char* ws = (char*)d_ws;
  size_t off = 0;
  auto alloc = [&](size_t b) -> void* {
    void* p = ws + off;
    off = (off + b + 255) & ~(size_t)255;
    return p;
  };
  int* icnt = (int*)alloc((size_t)NN * 4);
  float* dinv = (float*)alloc((size_t)NN * 4);
  int* gcur = (int*)alloc((size_t)NBKT * 4);
  int* rowptr = (int*)alloc((size_t)NN * 4);
  int* gstart = (int*)alloc((size_t)(GG + 1) * 4);
  unsigned int* part = (unsigned int*)alloc((size_t)NBKT * PCAP * 4);
  unsigned short* ep = (unsigned short*)alloc((size_t)NBKT * EPCAP * 2);
  __half* bufA = (__half*)alloc((size_t)NN * 64 * 2);
  __half* bufB = (__half*)alloc((size_t)NN * 64 * 2);
  double* sums24 = (double*)alloc((size_t)3 * 1024 * 8);

  const int* src = eidx;       // edge_index[0]
  const int* dst = eidx + EE;  // edge_index[1]

  // --- preprocessing: bounds + gcur/stat init; partition+gemm0; bucket-local CSR build ---
  k_bounds<<<NB_BND, 256, 0, stream>>>(batch, gstart, gcur, sums24);
  k_part_gemm0<<<NB_GEMM + NB_PART, 256, 0, stream>>>(src, dst, gcur, part, x, W[0], bufB);
  k_fill2b<<<NBKT, 512, 0, stream>>>(gcur, part, ep, rowptr, icnt, dinv, bufB);

  // --- 3 GCN layers ---
  k_gather_stats<<<(NN + 31) / 32, 256, 0, stream>>>(rowptr, icnt, ep, dinv, bufB, bufA,
                                                     sums24 + 0 * 1024);
  for (int l = 1; l < 3; ++l) {
    k_gemm64f<<<NB_GEMM, 256, 0, stream>>>(bufA, sums24 + (l - 1) * 1024, gam[l - 1],
                                           bet[l - 1], W[l], dinv, bufB);
    k_gather_stats<<<(NN + 31) / 32, 256, 0, stream>>>(rowptr, icnt, ep, dinv, bufB, bufA,
                                                       sums24 + l * 1024);
  }

  // --- pool (inlined BN of layer 2) + FC ---
  k_pool_final<<<(GG + 3) / 4, 256, 0, stream>>>(gstart, bufA, sums24 + 2 * 1024, gam[2],
                                                 bet[2], fcW, fcb, out);
}

// Round 18
// 234.454 us; speedup vs baseline: 4.4414x; 1.0194x over previous
//
#include <hip/hip_runtime.h>
#include <hip/hip_fp16.h>
#include <math.h>

#define NN 50000
#define EE 800000
#define GG 500
#define CC 6
#define BN_EPS 1e-5f
#define NB_BND 196     // ceil(50000/256)
#define NB_GEMM 782    // ceil(50000/64)  -- 64-row MFMA tiles
#define NBKT 196       // buckets of 256 nodes (dst>>8)
#define NB_PART 400    // partition blocks, 2000 edges each
#define PCAP 6144      // per-bucket partition capacity (uints); mean 4096, +32 sigma
#define EPCAP 7168     // per-bucket ep capacity (ushorts); max padded ~ mean+768+slack

typedef _Float16 f16x8 __attribute__((ext_vector_type(8)));
typedef float f32x4 __attribute__((ext_vector_type(4)));

// ---------------- graph bounds + gcur init + stat zeroing, one small dispatch ----------------
__global__ __launch_bounds__(256) void k_bounds(const int* __restrict__ batch,
                                                int* __restrict__ gstart,
                                                int* __restrict__ gcur,
                                                double* __restrict__ sums24) {
  if (blockIdx.x == 0) {
    if (threadIdx.x < NBKT) gcur[threadIdx.x] = threadIdx.x * PCAP;
    for (int k = threadIdx.x; k < 3 * 1024; k += 256) sums24[k] = 0.0;
  }
  int i = blockIdx.x * 256 + threadIdx.x;
  if (i >= NN) return;
  int bb = batch[i];
  if (i == 0) {
    for (int g = 0; g <= bb; ++g) gstart[g] = 0;
  } else {
    int pb = batch[i - 1];
    for (int g = pb + 1; g <= bb; ++g) gstart[g] = i;
  }
  if (i == NN - 1) {
    for (int g = bb + 1; g <= GG; ++g) gstart[g] = NN;
  }
}

// ---------------- MFMA GEMM tile body (64 rows/block, 4 waves, fp16 inputs) ----------------
// LAYER0: A=f32 raw, NO dinv prescale (applied later in k_fill2b). else: A=f16 + BN+ReLU + dinv.
template <bool LAYER0>
__device__ __forceinline__ void gemm_tile(int blockId,
                                          const void* __restrict__ Aptr,
                                          const double* __restrict__ sums,
                                          const float* __restrict__ gamma,
                                          const float* __restrict__ beta,
                                          const float* __restrict__ W,
                                          const float* __restrict__ dinv,
                                          __half* __restrict__ out) {
  __shared__ __align__(16) unsigned char AhB[64 * 128];  // A tile fp16 (swizzled)
  __shared__ __align__(16) unsigned char WtB[64 * 128];  // W^T fp16 (swizzled)
  __shared__ float sc[64], sh[64];
  int tid = threadIdx.x;
  if (!LAYER0 && tid < 64) {
    double S = 0.0, Q = 0.0;
#pragma unroll
    for (int k = 0; k < 8; ++k) {
      S += sums[k * 128 + tid];
      Q += sums[k * 128 + 64 + tid];
    }
    double mu = S / (double)NN;
    double var = Q / (double)NN - mu * mu;
    float rstd = (float)(1.0 / sqrt(var + (double)BN_EPS));
    float scv = gamma[tid] * rstd;
    sc[tid] = scv;
    sh[tid] = beta[tid] - (float)mu * scv;
  }
  // stage W^T as fp16: Wt[c][k] = W[k][c]
#pragma unroll
  for (int i = 0; i < 16; ++i) {
    int idx = tid + 256 * i;
    int k = idx >> 6, c = idx & 63;
    *(__half*)&WtB[c * 128 + ((k * 2) ^ ((c & 7) << 4))] = __float2half(W[idx]);
  }
  if (!LAYER0) __syncthreads();  // sc/sh ready before A staging
  int base = blockId * 64;
  if (LAYER0) {
    const float4* A4 = (const float4*)((const float*)Aptr + (size_t)base * 64);
#pragma unroll
    for (int i = 0; i < 4; ++i) {
      int idx = tid + 256 * i;
      int row = idx >> 4, q = idx & 15;
      float4 v = (base + row < NN) ? A4[idx] : float4{0.f, 0.f, 0.f, 0.f};
      __half2 p0 = __floats2half2_rn(v.x, v.y);
      __half2 p1 = __floats2half2_rn(v.z, v.w);
      uint2 u;
      u.x = *(unsigned*)&p0;
      u.y = *(unsigned*)&p1;
      *(uint2*)&AhB[row * 128 + ((q * 8) ^ ((row & 7) << 4))] = u;
    }
  } else {
    const uint4* A8 = (const uint4*)((const __half*)Aptr + (size_t)base * 64);
#pragma unroll
    for (int i = 0; i < 2; ++i) {
      int idx = tid + 256 * i;
      int row = idx >> 3, chunk = idx & 7;
      uint4 u = (base + row < NN) ? A8[idx] : uint4{0u, 0u, 0u, 0u};
      __half2* hp = (__half2*)&u;
      int c0 = chunk * 8;
      float f[8];
#pragma unroll
      for (int j = 0; j < 4; ++j) {
        float2 fv = __half22float2(hp[j]);
        f[2 * j] = fv.x;
        f[2 * j + 1] = fv.y;
      }
#pragma unroll
      for (int j = 0; j < 8; ++j)
        f[j] = fmaxf(fmaf(f[j], sc[c0 + j], sh[c0 + j]), 0.f);
      __half2 q0 = __floats2half2_rn(f[0], f[1]);
      __half2 q1 = __floats2half2_rn(f[2], f[3]);
      __half2 q2 = __floats2half2_rn(f[4], f[5]);
      __half2 q3 = __floats2half2_rn(f[6], f[7]);
      uint4 o;
      o.x = *(unsigned*)&q0;
      o.y = *(unsigned*)&q1;
      o.z = *(unsigned*)&q2;
      o.w = *(unsigned*)&q3;
      *(uint4*)&AhB[row * 128 + ((chunk * 16) ^ ((row & 7) << 4))] = o;
    }
  }
  __syncthreads();
  int lane = tid & 63;
  int w = tid >> 6;
  int r0 = w * 16;
  int lrow = lane & 15;
  int kg = lane >> 4;
  int s = (lrow & 7) << 4;
  f16x8 a0 = *(f16x8*)&AhB[(r0 + lrow) * 128 + ((kg * 16) ^ s)];
  f16x8 a1 = *(f16x8*)&AhB[(r0 + lrow) * 128 + ((64 + kg * 16) ^ s)];
  f32x4 acc[4];
#pragma unroll
  for (int ct = 0; ct < 4; ++ct) {
    acc[ct] = (f32x4){0.f, 0.f, 0.f, 0.f};
    f16x8 b0 = *(f16x8*)&WtB[(ct * 16 + lrow) * 128 + ((kg * 16) ^ s)];
    f16x8 b1 = *(f16x8*)&WtB[(ct * 16 + lrow) * 128 + ((64 + kg * 16) ^ s)];
    acc[ct] = __builtin_amdgcn_mfma_f32_16x16x32_f16(a0, b0, acc[ct], 0, 0, 0);
    acc[ct] = __builtin_amdgcn_mfma_f32_16x16x32_f16(a1, b1, acc[ct], 0, 0, 0);
  }
  __syncthreads();  // A-frag reads done; reuse AhB as output staging (linear)
#pragma unroll
  for (int reg = 0; reg < 4; ++reg) {
    int row = r0 + kg * 4 + reg;
    int n = base + row;
    float dv = 1.0f;
    if (!LAYER0) dv = dinv[n < NN ? n : NN - 1];
#pragma unroll
    for (int ct = 0; ct < 4; ++ct)
      *(__half*)&AhB[row * 128 + (ct * 16 + lrow) * 2] =
          __float2half(acc[ct][reg] * dv);
  }
  __syncthreads();
#pragma unroll
  for (int i = 0; i < 2; ++i) {
    int idx = tid + 256 * i;
    int row = idx >> 3, chunk = idx & 7;
    int n = base + row;
    if (n < NN)
      ((uint4*)(out + (size_t)n * 64))[chunk] = *(uint4*)&AhB[row * 128 + chunk * 16];
  }
}

// ---------------- edge partition by dst>>8 (single-read, regs-held) + layer-0 GEMM ----------------
__global__ __launch_bounds__(256) void k_part_gemm0(const int* __restrict__ src,
                                                    const int* __restrict__ dst,
                                                    int* __restrict__ gcur,
                                                    unsigned int* __restrict__ part,
                                                    const float* __restrict__ x,
                                                    const float* __restrict__ W0,
                                                    __half* __restrict__ outB) {
  if (blockIdx.x >= NB_GEMM) {
    __shared__ int lcnt[NBKT], lofs[NBKT], lcur[NBKT];
    int tid = threadIdx.x;
    int cb = (blockIdx.x - NB_GEMM) * 2000;
    int d[8], s[8];
#pragma unroll
    for (int it = 0; it < 8; ++it) {
      int o = it * 256 + tid;
      d[it] = (o < 2000) ? dst[cb + o] : -1;
      s[it] = (o < 2000) ? src[cb + o] : 0;
    }
    if (tid < NBKT) lcnt[tid] = 0;
    __syncthreads();
#pragma unroll
    for (int it = 0; it < 8; ++it)
      if (d[it] >= 0) atomicAdd(&lcnt[d[it] >> 8], 1);
    __syncthreads();
    if (tid < NBKT) {
      lofs[tid] = atomicAdd(&gcur[tid], lcnt[tid]);
      lcur[tid] = 0;
    }
    __syncthreads();
#pragma unroll
    for (int it = 0; it < 8; ++it) {
      if (d[it] >= 0) {
        int bkt = d[it] >> 8;
        int pos = lofs[bkt] + atomicAdd(&lcur[bkt], 1);
        part[pos] = ((unsigned)(d[it] & 255) << 16) | (unsigned)s[it];
      }
    }
    return;
  }
  gemm_tile<true>(blockIdx.x, x, nullptr, nullptr, nullptr, W0, nullptr, outB);
}

// ---------------- fill2b: per-bucket counts, prefix, rowptr/icnt/dinv, ep scatter, bufB scale ----
__global__ __launch_bounds__(256) void k_fill2b(const int* __restrict__ gcur,
                                                const unsigned int* __restrict__ part,
                                                unsigned short* __restrict__ ep,
                                                int* __restrict__ rowptr,
                                                int* __restrict__ icnt,
                                                float* __restrict__ dinv,
                                                __half* __restrict__ bufB) {
  __shared__ int lcnt[256];
  __shared__ int lpre[256];
  __shared__ int lfill[256];
  __shared__ float ldinv[256];
  int b = blockIdx.x;
  int tid = threadIdx.x;
  int nbase = b << 8;
  int cnt_b = gcur[b] - b * PCAP;
  const unsigned int* ps = part + (size_t)b * PCAP;
  lcnt[tid] = 0;
  __syncthreads();
  for (int i = tid; i < cnt_b; i += 256) atomicAdd(&lcnt[ps[i] >> 16], 1);
  __syncthreads();
  int myc = lcnt[tid];
  int pad = (myc + 3) & ~3;
  lpre[tid] = pad;
  __syncthreads();
  for (int ofs = 1; ofs < 256; ofs <<= 1) {
    int y = (tid >= ofs) ? lpre[tid - ofs] : 0;
    __syncthreads();
    lpre[tid] += y;
    __syncthreads();
  }
  int excl = lpre[tid] - pad;  // exclusive padded prefix (4-aligned)
  float dv = rsqrtf((float)(myc + 1));
  int node = nbase + tid;
  if (node < NN) {
    rowptr[node] = b * EPCAP + excl;
    icnt[node] = myc;
    dinv[node] = dv;
  }
  ldinv[tid] = dv;
  lfill[tid] = 0;
  __syncthreads();
  lpre[tid] = excl;
  __syncthreads();
  for (int i = tid; i < cnt_b; i += 256) {
    unsigned p = ps[i];
    int dloc = p >> 16;
    int pos = lpre[dloc] + atomicAdd(&lfill[dloc], 1);
    ep[(size_t)b * EPCAP + pos] = (unsigned short)(p & 0xFFFF);
  }
  // prescale layer-0 GEMM rows for this bucket's nodes by dinv
  __syncthreads();
  int maxrow = NN - nbase;
  if (maxrow > 256) maxrow = 256;
  uint4* B4 = (uint4*)(bufB + (size_t)nbase * 64);
  for (int i = tid; i < maxrow * 8; i += 256) {
    float dvr = ldinv[i >> 3];
    uint4 u = B4[i];
    __half2* hp = (__half2*)&u;
#pragma unroll
    for (int j = 0; j < 4; ++j) {
      float2 f = __half22float2(hp[j]);
      hp[j] = __floats2half2_rn(f.x * dvr, f.y * dvr);
    }
    B4[i] = u;
  }
}

// ---------------- gather-aggregate: 1 node per 8-lane group, uint4 (8ch) per lane ----------------
__global__ __launch_bounds__(256) void k_gather_stats(const int* __restrict__ rowptr,
                                                      const int* __restrict__ icnt,
                                                      const unsigned short* __restrict__ ep,
                                                      const float* __restrict__ dinv,
                                                      const __half* __restrict__ t,
                                                      __half* __restrict__ outp,
                                                      double* __restrict__ sums8) {
  int w = threadIdx.x >> 6;
  int lane = threadIdx.x & 63;
  int g = lane >> 3;   // group in wave
  int li = lane & 7;   // lane in group -> channel block
  int d = blockIdx.x * 32 + w * 8 + g;
  float acc[8] = {0.f, 0.f, 0.f, 0.f, 0.f, 0.f, 0.f, 0.f};
  if (d < NN) {
    uint4 u = ((const uint4*)(t + (size_t)d * 64))[li];  // self t'[d]
    {
      __half2* hp = (__half2*)&u;
#pragma unroll
      for (int j = 0; j < 4; ++j) {
        float2 f = __half22float2(hp[j]);
        acc[2 * j] += f.x;
        acc[2 * j + 1] += f.y;
      }
    }
    int e0 = rowptr[d], cnt = icnt[d];
    int k = 0;
    for (; k + 7 < cnt; k += 8) {
      ushort4 qa = *(const ushort4*)&ep[e0 + k];
      ushort4 qb = *(const ushort4*)&ep[e0 + k + 4];
      uint4 r0 = ((const uint4*)(t + (size_t)qa.x * 64))[li];
      uint4 r1 = ((const uint4*)(t + (size_t)qa.y * 64))[li];
      uint4 r2 = ((const uint4*)(t + (size_t)qa.z * 64))[li];
      uint4 r3 = ((const uint4*)(t + (size_t)qa.w * 64))[li];
      uint4 r4 = ((const uint4*)(t + (size_t)qb.x * 64))[li];
      uint4 r5 = ((const uint4*)(t + (size_t)qb.y * 64))[li];
      uint4 r6 = ((const uint4*)(t + (size_t)qb.z * 64))[li];
      uint4 r7 = ((const uint4*)(t + (size_t)qb.w * 64))[li];
      uint4* rr[8] = {&r0, &r1, &r2, &r3, &r4, &r5, &r6, &r7};
#pragma unroll
      for (int m = 0; m < 8; ++m) {
        __half2* hp = (__half2*)rr[m];
#pragma unroll
        for (int j = 0; j < 4; ++j) {
          float2 f = __half22float2(hp[j]);
          acc[2 * j] += f.x;
          acc[2 * j + 1] += f.y;
        }
      }
    }
    for (; k + 3 < cnt; k += 4) {
      ushort4 qe = *(const ushort4*)&ep[e0 + k];
      uint4 r0 = ((const uint4*)(t + (size_t)qe.x * 64))[li];
      uint4 r1 = ((const uint4*)(t + (size_t)qe.y * 64))[li];
      uint4 r2 = ((const uint4*)(t + (size_t)qe.z * 64))[li];
      uint4 r3 = ((const uint4*)(t + (size_t)qe.w * 64))[li];
      uint4* rr[4] = {&r0, &r1, &r2, &r3};
#pragma unroll
      for (int m = 0; m < 4; ++m) {
        __half2* hp = (__half2*)rr[m];
#pragma unroll
        for (int j = 0; j < 4; ++j) {
          float2 f = __half22float2(hp[j]);
          acc[2 * j] += f.x;
          acc[2 * j + 1] += f.y;
        }
      }
    }
    for (; k < cnt; ++k) {
      uint4 r = ((const uint4*)(t + (size_t)ep[e0 + k] * 64))[li];
      __half2* hp = (__half2*)&r;
#pragma unroll
      for (int j = 0; j < 4; ++j) {
        float2 f = __half22float2(hp[j]);
        acc[2 * j] += f.x;
        acc[2 * j + 1] += f.y;
      }
    }
    float dv = dinv[d];
#pragma unroll
    for (int j = 0; j < 8; ++j) acc[j] *= dv;
    __half2 o0 = __floats2half2_rn(acc[0], acc[1]);
    __half2 o1 = __floats2half2_rn(acc[2], acc[3]);
    __half2 o2 = __floats2half2_rn(acc[4], acc[5]);
    __half2 o3 = __floats2half2_rn(acc[6], acc[7]);
    uint4 ov;
    ov.x = *(unsigned*)&o0;
    ov.y = *(unsigned*)&o1;
    ov.z = *(unsigned*)&o2;
    ov.w = *(unsigned*)&o3;
    ((uint4*)(outp + (size_t)d * 64))[li] = ov;
  }
  // stats: per-lane acc is the node's contribution for its 8 channels
  __shared__ float ls[4][8][8][8], lq[4][8][8][8];
#pragma unroll
  for (int j = 0; j < 8; ++j) {
    ls[w][g][li][j] = acc[j];
    lq[w][g][li][j] = acc[j] * acc[j];
  }
  __syncthreads();
  if (threadIdx.x < 64) {
    int c = threadIdx.x;
    int lsel = c >> 3, comp = c & 7;
    float S = 0.f, Q = 0.f;
#pragma unroll
    for (int ww = 0; ww < 4; ++ww)
#pragma unroll
      for (int gg = 0; gg < 8; ++gg) {
        S += ls[ww][gg][lsel][comp];
        Q += lq[ww][gg][lsel][comp];
      }
    double* bank = sums8 + (size_t)(blockIdx.x & 7) * 128;
    atomicAdd(&bank[c], (double)S);
    atomicAdd(&bank[64 + c], (double)Q);
  }
}

// ---------------- MFMA GEMM (fp16 in) with inlined BN-finalize + fused BN+ReLU ----------------
__global__ __launch_bounds__(256) void k_gemm64f(const __half* __restrict__ A,
                                                 const double* __restrict__ sums,
                                                 const float* __restrict__ gamma,
                                                 const float* __restrict__ beta,
                                                 const float* __restrict__ W,
                                                 const float* __restrict__ dinv,
                                                 __half* __restrict__ out) {
  gemm_tile<false>(blockIdx.x, A, sums, gamma, beta, W, dinv, out);
}

// ---------------- segmented mean-pool (inlined BN, fp16 in) + final FC ----------------
__global__ __launch_bounds__(256) void k_pool_final(const int* __restrict__ gstart,
                                                    const __half* __restrict__ h,
                                                    const double* __restrict__ sums,
                                                    const float* __restrict__ gamma,
                                                    const float* __restrict__ beta,
                                                    const float* __restrict__ fcW,
                                                    const float* __restrict__ fcb,
                                                    float* __restrict__ out) {
  __shared__ float sc[64], sh[64];
  __shared__ float pl[4][64];
  int tid = threadIdx.x;
  if (tid < 64) {
    double S = 0.0, Q = 0.0;
#pragma unroll
    for (int k = 0; k < 8; ++k) {
      S += sums[k * 128 + tid];
      Q += sums[k * 128 + 64 + tid];
    }
    double mu = S / (double)NN;
    double var = Q / (double)NN - mu * mu;
    float rstd = (float)(1.0 / sqrt(var + (double)BN_EPS));
    float scv = gamma[tid] * rstd;
    sc[tid] = scv;
    sh[tid] = beta[tid] - (float)mu * scv;
  }
  __syncthreads();
  int w = tid >> 6;
  int c = tid & 63;
  int g = blockIdx.x * 4 + w;
  float p = 0.f;
  if (g < GG) {
    int s = gstart[g], e = gstart[g + 1];
    float scv = sc[c], shv = sh[c], acc = 0.f;
    for (int i = s; i < e; ++i)
      acc += fmaxf(fmaf(__half2float(h[(size_t)i * 64 + c]), scv, shv), 0.f);
    p = acc / fmaxf((float)(e - s), 1.0f);
  }
  pl[w][c] = p;
  __syncthreads();
  if (tid < 4 * CC) {
    int gw = tid / CC, j = tid % CC;
    int gg = blockIdx.x * 4 + gw;
    if (gg < GG) {
      float acc = 0.f;
#pragma unroll
      for (int k = 0; k < 64; ++k) acc = fmaf(pl[gw][k], fcW[k * CC + j], acc);
      out[gg * CC + j] = acc + fcb[j];
    }
  }
}

extern "C" void kernel_launch(void* const* d_in, const int* in_sizes, int n_in,
                              void* d_out, int out_size, void* d_ws, size_t ws_size,
                              hipStream_t stream) {
  const float* x = (const float*)d_in[0];
  const int* eidx = (const int*)d_in[1];
  const int* batch = (const int*)d_in[2];
  const float* W[3] = {(const float*)d_in[3], (const float*)d_in[7], (const float*)d_in[11]};
  const float* gam[3] = {(const float*)d_in[5], (const float*)d_in[9], (const float*)d_in[13]};
  const float* bet[3] = {(const float*)d_in[6], (const float*)d_in[10], (const float*)d_in[14]};
  const float* fcW = (const float*)d_in[15];
  const float* fcb = (const float*)d_in[16];
  float* out = (float*)d_out;

  char* ws = (char*)d_ws;
  size_t off = 0;
  auto alloc = [&](size_t b) -> void* {
    void* p = ws + off;
    off = (off + b + 255) & ~(size_t)255;
    return p;
  };
  int* icnt = (int*)alloc((size_t)NN * 4);
  float* dinv = (float*)alloc((size_t)NN * 4);
  int* gcur = (int*)alloc((size_t)NBKT * 4);
  int* rowptr = (int*)alloc((size_t)NN * 4);
  int* gstart = (int*)alloc((size_t)(GG + 1) * 4);
  unsigned int* part = (unsigned int*)alloc((size_t)NBKT * PCAP * 4);
  unsigned short* ep = (unsigned short*)alloc((size_t)NBKT * EPCAP * 2);
  __half* bufA = (__half*)alloc((size_t)NN * 64 * 2);
  __half* bufB = (__half*)alloc((size_t)NN * 64 * 2);
  double* sums24 = (double*)alloc((size_t)3 * 1024 * 8);

  const int* src = eidx;       // edge_index[0]
  const int* dst = eidx + EE;  // edge_index[1]

  // --- preprocessing: bounds + gcur/stat init; partition+gemm0; bucket-local CSR build ---
  k_bounds<<<NB_BND, 256, 0, stream>>>(batch, gstart, gcur, sums24);
  k_part_gemm0<<<NB_GEMM + NB_PART, 256, 0, stream>>>(src, dst, gcur, part, x, W[0], bufB);
  k_fill2b<<<NBKT, 256, 0, stream>>>(gcur, part, ep, rowptr, icnt, dinv, bufB);

  // --- 3 GCN layers ---
  k_gather_stats<<<(NN + 31) / 32, 256, 0, stream>>>(rowptr, icnt, ep, dinv, bufB, bufA,
                                                     sums24 + 0 * 1024);
  for (int l = 1; l < 3; ++l) {
    k_gemm64f<<<NB_GEMM, 256, 0, stream>>>(bufA, sums24 + (l - 1) * 1024, gam[l - 1],
                                           bet[l - 1], W[l], dinv, bufB);
    k_gather_stats<<<(NN + 31) / 32, 256, 0, stream>>>(rowptr, icnt, ep, dinv, bufB, bufA,
                                                       sums24 + l * 1024);
  }

  // --- pool (inlined BN of layer 2) + FC ---
  k_pool_final<<<(GG + 3) / 4, 256, 0, stream>>>(gstart, bufA, sums24 + 2 * 1024, gam[2],
                                                 bet[2], fcW, fcb, out);
}